// Round 2
// baseline (10622.476 us; speedup 1.0000x reference)
//
#include <hip/hip_runtime.h>
#include <hip/hip_bf16.h>

#define NW 4
#define NST 100
#define TT 128
#define II 256
#define HH 1024
#define H3 3072

typedef _Float16 h8 __attribute__((ext_vector_type(8)));
typedef float f4 __attribute__((ext_vector_type(4)));

__device__ __forceinline__ float sigf(float x) { return 1.0f / (1.0f + expf(-x)); }

// ---------------- device-scope multi-use barrier (regular launches, graph-safe) ----
// Entry __syncthreads drains every wave's stores (compiler emits vmcnt(0) before
// s_barrier); thread-0 release-fence publishes L2, arrive via device-scope atomic,
// spin on generation counter, acquire-fence invalidates L1/L2 before proceeding.
__device__ __forceinline__ void gbar(unsigned* cnt, unsigned* gen, unsigned nb) {
    __syncthreads();
    if (threadIdx.x == 0) {
        __threadfence();
        unsigned g = __hip_atomic_load(gen, __ATOMIC_RELAXED, __HIP_MEMORY_SCOPE_AGENT);
        unsigned a = __hip_atomic_fetch_add(cnt, 1u, __ATOMIC_ACQ_REL, __HIP_MEMORY_SCOPE_AGENT);
        if (a == nb - 1u) {
            __hip_atomic_store(cnt, 0u, __ATOMIC_RELAXED, __HIP_MEMORY_SCOPE_AGENT);
            __hip_atomic_fetch_add(gen, 1u, __ATOMIC_RELEASE, __HIP_MEMORY_SCOPE_AGENT);
        } else {
            while (__hip_atomic_load(gen, __ATOMIC_RELAXED, __HIP_MEMORY_SCOPE_AGENT) == g) {
                __builtin_amdgcn_s_sleep(8);
            }
        }
        __threadfence();
    }
    __syncthreads();
}

// ---------------- zero init ----------------
__global__ void zero_k(float* a, int n) {
    int i = blockIdx.x * 256 + threadIdx.x;
    if (i < n) a[i] = 0.0f;
}

// ---------------- weight concat + fp16 convert: Wc[w][3072][1280] = [Whh | Wih] ----
__global__ void convW_k(const float* __restrict__ Whh, const float* __restrict__ Wih,
                        _Float16* __restrict__ Wc) {
    int col = blockIdx.x * 256 + threadIdx.x;  // 0..1279
    int r = blockIdx.y;                        // 0..3071
    int w = blockIdx.z;
    float v = (col < HH) ? Whh[((size_t)w * H3 + r) * HH + col]
                         : Wih[((size_t)w * H3 + r) * II + (col - HH)];
    Wc[((size_t)w * H3 + r) * 1280 + col] = (_Float16)v;
}

// ---------------- weekly weights fp16 ----------------
__global__ void convWk_k(const float* __restrict__ src, _Float16* __restrict__ dst) {
    int col = blockIdx.x * 256 + threadIdx.x;  // 0..1023
    int r = blockIdx.y;                        // 0..3071
    dst[(size_t)r * HH + col] = (_Float16)src[(size_t)r * HH + col];
}

// ---------------- x -> fp16 padded transpose: xT[w][t][128][256] ----------------
__global__ void xcvt_k(const float* __restrict__ x0, const float* __restrict__ x1,
                       const float* __restrict__ x2, const float* __restrict__ x3,
                       _Float16* __restrict__ xT) {
    int idx = blockIdx.x * 256 + threadIdx.x;   // 2^21 total
    int k8 = idx & 31;
    int m  = (idx >> 5) & 127;
    int t  = (idx >> 12) & 127;
    int w  = idx >> 19;
    const float* xw = (w == 0) ? x0 : (w == 1) ? x1 : (w == 2) ? x2 : x3;
    h8 hv = {};
    if (m < NST) {
        const float* s = xw + ((size_t)m * TT + t) * II + k8 * 8;
        float4 fa = *(const float4*)s;
        float4 fb = *(const float4*)(s + 4);
        hv[0] = (_Float16)fa.x; hv[1] = (_Float16)fa.y;
        hv[2] = (_Float16)fa.z; hv[3] = (_Float16)fa.w;
        hv[4] = (_Float16)fb.x; hv[5] = (_Float16)fb.y;
        hv[6] = (_Float16)fb.z; hv[7] = (_Float16)fb.w;
    }
    *(h8*)&xT[(((size_t)w * TT + t) * 128 + m) * II + k8 * 8] = hv;
}

// ---------------- combined bias precompute: bc[w][{r,z,ni,nh}][1024] fp32 ----
__global__ void convB_k(const float* __restrict__ bih, const float* __restrict__ bhh,
                        float* __restrict__ bc) {
    int j = blockIdx.x * 256 + threadIdx.x;
    int w = blockIdx.y;
    const float* bi = bih + w * H3;
    const float* bh = bhh + w * H3;
    float* o = bc + w * 4096;
    o[j] = bi[j] + bh[j];
    o[1024 + j] = bi[1024 + j] + bh[1024 + j];
    o[2048 + j] = bi[2048 + j];
    o[3072 + j] = bh[2048 + j];
}

// ---------------- fused encoder GRU: entire 128-step recurrence in ONE kernel.
// Weights (48x1280 fp16 per block) resident in LDS, fp32 h master in registers,
// per-week 64-block device barrier per time step. ----------------
#define ENC_LDS_HALFS (40 * 48 * 40)
#define ENC_LDS_BYTES (ENC_LDS_HALFS * 2)

__global__ __launch_bounds__(256) void enc_fused_k(
    const _Float16* __restrict__ Wc, const float* __restrict__ bc,
    const _Float16* __restrict__ xT,
    _Float16* __restrict__ hhA, _Float16* __restrict__ hhB,
    _Float16* __restrict__ seq, unsigned* bar)
{
    extern __shared__ _Float16 Bs[];   // [40 chunks][48 rows][40 halfs] stride-40 pad

    int j0 = blockIdx.x * 16;
    int w  = blockIdx.y;
    const _Float16* Wcw = Wc + (size_t)w * H3 * 1280;
    const float* bcw = bc + w * 4096;
    _Float16* hA = hhA + (size_t)w * 128 * HH;
    _Float16* hB = hhB + (size_t)w * 128 * HH;

    int tid = threadIdx.x;
    int lane = tid & 63, wi = tid >> 6, quad = lane >> 4, l15 = lane & 15;

    // one-time weight staging: 192 threads, 16B each, 40 chunks
    if (tid < 192) {
        int brow = tid >> 2, bseg = tid & 3;
        const _Float16* bsrc =
            Wcw + (size_t)((brow >> 4) * 1024 + j0 + (brow & 15)) * 1280 + bseg * 8;
        #pragma unroll 8
        for (int c = 0; c < 40; c++) {
            uint4 v = *(const uint4*)(bsrc + c * 32);
            *(uint4*)&Bs[((size_t)c * 48 + brow) * 40 + bseg * 8] = v;
        }
    }
    __syncthreads();

    int j = j0 + l15;
    float br = bcw[j], bz = bcw[1024 + j], bni = bcw[2048 + j], bnh = bcw[3072 + j];
    int r0 = wi * 32 + l15, r1 = wi * 32 + 16 + l15;
    float hreg[2][4] = {};   // fp32 h master, block-private -> registers

    for (int t = 0; t < TT; t++) {
        const _Float16* hin = (t & 1) ? hB : hA;
        _Float16* hout = (t & 1) ? hA : hB;
        const _Float16* xt = xT + ((size_t)w * TT + t) * 128 * II;
        const _Float16* pA0h = hin + (size_t)r0 * HH + quad * 8;
        const _Float16* pA1h = hin + (size_t)r1 * HH + quad * 8;
        const _Float16* pA0x = xt + (size_t)r0 * II + quad * 8;
        const _Float16* pA1x = xt + (size_t)r1 * II + quad * 8;

        f4 aR[2] = {}, aZ[2] = {}, aNH[2] = {}, aNX[2] = {};
        h8 a0 = *(const h8*)pA0h;
        h8 a1 = *(const h8*)pA1h;
        #pragma unroll 4
        for (int c = 0; c < 40; c++) {
            // prefetch A chunk c+1 (global -> regs) while computing c
            h8 an0 = {}, an1 = {};
            if (c < 39) {
                int cn = c + 1;
                const _Float16* s0 = (cn < 32) ? pA0h + cn * 32 : pA0x + (cn - 32) * 32;
                const _Float16* s1 = (cn < 32) ? pA1h + cn * 32 : pA1x + (cn - 32) * 32;
                an0 = *(const h8*)s0;
                an1 = *(const h8*)s1;
            }
            const _Float16* bb = &Bs[(size_t)(c * 48) * 40];
            h8 bf0 = *(const h8*)&bb[l15 * 40 + quad * 8];
            h8 bf1 = *(const h8*)&bb[(16 + l15) * 40 + quad * 8];
            h8 bf2 = *(const h8*)&bb[(32 + l15) * 40 + quad * 8];
            aR[0] = __builtin_amdgcn_mfma_f32_16x16x32_f16(a0, bf0, aR[0], 0, 0, 0);
            aR[1] = __builtin_amdgcn_mfma_f32_16x16x32_f16(a1, bf0, aR[1], 0, 0, 0);
            aZ[0] = __builtin_amdgcn_mfma_f32_16x16x32_f16(a0, bf1, aZ[0], 0, 0, 0);
            aZ[1] = __builtin_amdgcn_mfma_f32_16x16x32_f16(a1, bf1, aZ[1], 0, 0, 0);
            if (c < 32) {
                aNH[0] = __builtin_amdgcn_mfma_f32_16x16x32_f16(a0, bf2, aNH[0], 0, 0, 0);
                aNH[1] = __builtin_amdgcn_mfma_f32_16x16x32_f16(a1, bf2, aNH[1], 0, 0, 0);
            } else {
                aNX[0] = __builtin_amdgcn_mfma_f32_16x16x32_f16(a0, bf2, aNX[0], 0, 0, 0);
                aNX[1] = __builtin_amdgcn_mfma_f32_16x16x32_f16(a1, bf2, aNX[1], 0, 0, 0);
            }
            a0 = an0; a1 = an1;
        }

        // ---- gate epilogue: C/D mapping col=lane&15, row=quad*4+reg ----
        #pragma unroll
        for (int mi = 0; mi < 2; mi++) {
            #pragma unroll
            for (int p = 0; p < 4; p++) {
                int row = wi * 32 + mi * 16 + quad * 4 + p;
                float r = sigf(aR[mi][p] + br);
                float z = sigf(aZ[mi][p] + bz);
                float n = tanhf(aNX[mi][p] + bni + r * (aNH[mi][p] + bnh));
                float hv = (1.f - z) * n + z * hreg[mi][p];
                hreg[mi][p] = hv;
                hout[(size_t)row * HH + j] = (_Float16)hv;
                if (row < NST)
                    seq[(((size_t)w * NST + row) * TT + t) * HH + j] = (_Float16)hv;
            }
        }
        // per-week barrier: 64 blocks of this week
        gbar(&bar[w], &bar[4 + w], 64);
    }
}

// ---------------- encoder time-attention (fp16 seq, vectorized) ----------------
__global__ __launch_bounds__(256) void att1_k(
    const _Float16* __restrict__ seq, const float* __restrict__ attW,
    const float* __restrict__ attb, float* __restrict__ wex)
{
    int d0 = blockIdx.x * 128;
    int n  = blockIdx.y;
    int w  = blockIdx.z;
    __shared__ _Float16 S[128][128];  // [t][d]
    __shared__ float PM[16][136];
    int tid = threadIdx.x;
    const _Float16* sp = seq + ((size_t)(w * NST + n) * TT) * HH + d0;
    for (int q = tid; q < 2048; q += 256) {
        int t = q >> 4, seg = q & 15;
        *(h8*)&S[t][seg * 8] = *(const h8*)(sp + (size_t)t * HH + seg * 8);
    }
    __syncthreads();
    int tx = tid & 15, ty = tid >> 4;
    const float* Wg = attW + (size_t)w * TT * TT;
    float acc[8][8];
    #pragma unroll
    for (int i = 0; i < 8; i++) {
        float b = attb[w * TT + ty * 8 + i];
        for (int j = 0; j < 8; j++) acc[i][j] = b;
    }
    for (int t = 0; t < 128; t++) {
        float wv[8], sv[8];
        #pragma unroll
        for (int i = 0; i < 8; i++) wv[i] = Wg[(ty * 8 + i) * TT + t];
        h8 s8 = *(const h8*)&S[t][tx * 8];
        #pragma unroll
        for (int j = 0; j < 8; j++) sv[j] = (float)s8[j];
        #pragma unroll
        for (int i = 0; i < 8; i++)
            #pragma unroll
            for (int j = 0; j < 8; j++) acc[i][j] += wv[i] * sv[j];
    }
    float cmax[8], csum[8];
    #pragma unroll
    for (int j = 0; j < 8; j++) {
        float m = acc[0][j];
        for (int i = 1; i < 8; i++) m = fmaxf(m, acc[i][j]);
        PM[ty][tx * 8 + j] = m;
    }
    __syncthreads();
    #pragma unroll
    for (int j = 0; j < 8; j++) {
        float m = -1e30f;
        for (int yy = 0; yy < 16; yy++) m = fmaxf(m, PM[yy][tx * 8 + j]);
        cmax[j] = m;
    }
    __syncthreads();
    #pragma unroll
    for (int j = 0; j < 8; j++) {
        float s = 0.f;
        for (int i = 0; i < 8; i++) { acc[i][j] = expf(acc[i][j] - cmax[j]); s += acc[i][j]; }
        PM[ty][tx * 8 + j] = s;
    }
    __syncthreads();
    #pragma unroll
    for (int j = 0; j < 8; j++) {
        float s = 0.f;
        for (int yy = 0; yy < 16; yy++) s += PM[yy][tx * 8 + j];
        csum[j] = s;
    }
    __syncthreads();
    #pragma unroll
    for (int i = 0; i < 8; i++) {
        h8 s8 = *(const h8*)&S[ty * 8 + i][tx * 8];
        #pragma unroll
        for (int j = 0; j < 8; j++) {
            if (i == 0) PM[ty][tx * 8 + j] = 0.f;
            PM[ty][tx * 8 + j] += acc[i][j] * (float)s8[j];
        }
    }
    __syncthreads();
    if (ty == 0) {
        #pragma unroll
        for (int j = 0; j < 8; j++) {
            float o = 0.f;
            for (int yy = 0; yy < 16; yy++) o += PM[yy][tx * 8 + j];
            wex[((size_t)w * NST + n) * HH + d0 + tx * 8 + j] = o / csum[j];
        }
    }
}

// ---------------- generic fp32 GEMM: C[m][n] = sum_k A[m][k]*B[n][k] (+bias, relu) ----
template <int RELU>
__global__ __launch_bounds__(256) void gemm_tn_k(
    const float* __restrict__ A, const float* __restrict__ B,
    const float* __restrict__ bias, float* __restrict__ C, int M, int N, int K)
{
    int n0 = blockIdx.x * 64, m0 = blockIdx.y * 64;
    __shared__ float As[16][64], Bs[16][64];
    int tid = threadIdx.x, tx = tid & 15, ty = tid >> 4;
    float acc[4][4] = {{0.f}};
    for (int k0 = 0; k0 < K; k0 += 16) {
        __syncthreads();
        for (int q = tid; q < 1024; q += 256) {
            int kk = q & 15, r = q >> 4;
            int m = m0 + r, nn = n0 + r;
            As[kk][r] = (m < M) ? A[(size_t)m * K + k0 + kk] : 0.f;
            Bs[kk][r] = (nn < N) ? B[(size_t)nn * K + k0 + kk] : 0.f;
        }
        __syncthreads();
        #pragma unroll
        for (int kk = 0; kk < 16; kk++) {
            float4 av = *(const float4*)&As[kk][ty * 4];
            float4 bv = *(const float4*)&Bs[kk][tx * 4];
            float a[4] = {av.x, av.y, av.z, av.w};
            float b[4] = {bv.x, bv.y, bv.z, bv.w};
            #pragma unroll
            for (int r = 0; r < 4; r++)
                #pragma unroll
                for (int c = 0; c < 4; c++) acc[r][c] += a[r] * b[c];
        }
    }
    #pragma unroll
    for (int r = 0; r < 4; r++) {
        int m = m0 + ty * 4 + r;
        if (m >= M) continue;
        #pragma unroll
        for (int c = 0; c < 4; c++) {
            int nn = n0 + tx * 4 + c;
            if (nn >= N) continue;
            float v = acc[r][c] + (bias ? bias[nn] : 0.f);
            if (RELU) v = fmaxf(v, 0.f);
            C[(size_t)m * N + nn] = v;
        }
    }
}

// ---------------- fused weekly GRU: entire 100-step recurrence in ONE kernel,
// weight fragments register-resident across steps, device barrier per step ------
__global__ __launch_bounds__(256) void wk_fused_k(
    const float* __restrict__ gxw, const _Float16* __restrict__ wkW,
    const float* __restrict__ bhh, float* __restrict__ hA,
    float* __restrict__ hB, float* __restrict__ we2, unsigned* bar)
{
    int wi = threadIdx.x >> 6, lane = threadIdx.x & 63;
    int j = blockIdx.x * 4 + wi;
    int k0 = lane * 16;
    float wf[3][16];
    #pragma unroll
    for (int g = 0; g < 3; g++) {
        h8 wa = *(const h8*)&wkW[(size_t)(g * HH + j) * HH + k0];
        h8 wb = *(const h8*)&wkW[(size_t)(g * HH + j) * HH + k0 + 8];
        #pragma unroll
        for (int i = 0; i < 8; i++) { wf[g][i] = (float)wa[i]; wf[g][8 + i] = (float)wb[i]; }
    }
    float b0 = bhh[j], b1 = bhh[HH + j], b2 = bhh[2 * HH + j];

    for (int t = 0; t < NST; t++) {
        const float* hin = (t & 1) ? hB : hA;
        float* hout = (t & 1) ? hA : hB;
        float acc[4][3] = {};
        #pragma unroll
        for (int b = 0; b < 4; b++) {
            float hv[16];
            #pragma unroll
            for (int s = 0; s < 4; s++) {
                float4 hq = *(const float4*)&hin[b * HH + k0 + s * 4];
                hv[s * 4] = hq.x; hv[s * 4 + 1] = hq.y;
                hv[s * 4 + 2] = hq.z; hv[s * 4 + 3] = hq.w;
            }
            #pragma unroll
            for (int g = 0; g < 3; g++)
                #pragma unroll
                for (int i = 0; i < 16; i++) acc[b][g] += wf[g][i] * hv[i];
        }
        #pragma unroll
        for (int b = 0; b < 4; b++)
            #pragma unroll
            for (int g = 0; g < 3; g++)
                for (int o = 32; o; o >>= 1) acc[b][g] += __shfl_down(acc[b][g], o);
        if (lane == 0) {
            for (int b = 0; b < 4; b++) {
                const float* gx = gxw + ((size_t)b * NST + t) * H3;
                float hr = acc[b][0] + b0;
                float hz = acc[b][1] + b1;
                float hn = acc[b][2] + b2;
                float r = sigf(gx[j] + hr);
                float z = sigf(gx[HH + j] + hz);
                float n = tanhf(gx[2 * HH + j] + r * hn);
                float hv = (1.f - z) * n + z * hin[b * HH + j];
                hout[b * HH + j] = hv;
                we2[((size_t)t * 4 + b) * HH + j] = hv;
            }
        }
        gbar(&bar[8], &bar[9], 256);
    }
}

// ---------------- weekly attention (T=4) ----------------
__global__ void wkatt_k(const float* __restrict__ we2, const float* __restrict__ W,
                        const float* __restrict__ bv, float* __restrict__ wav)
{
    int n = blockIdx.x;
    for (int d = threadIdx.x; d < HH; d += 256) {
        float v[4], l[4];
        #pragma unroll
        for (int tp = 0; tp < 4; tp++) v[tp] = we2[((size_t)n * 4 + tp) * HH + d];
        float mx = -1e30f;
        #pragma unroll
        for (int tp = 0; tp < 4; tp++) {
            float s = bv[tp];
            for (int t2 = 0; t2 < 4; t2++) s += v[t2] * W[tp * 4 + t2];
            l[tp] = s; mx = fmaxf(mx, s);
        }
        float se = 0.f, o = 0.f;
        #pragma unroll
        for (int tp = 0; tp < 4; tp++) {
            float e = expf(l[tp] - mx);
            se += e; o += e * v[tp];
        }
        wav[(size_t)n * HH + d] = o / se;
    }
}

// ---------------- pool attention (C=5, T=20) ----------------
__global__ void poolatt_k(const float* __restrict__ wav, const float* __restrict__ W,
                          const float* __restrict__ bv, float* __restrict__ cat1)
{
    int c = blockIdx.x;
    for (int d = threadIdx.x; d < HH; d += 256) {
        float v[20], l[20];
        for (int t2 = 0; t2 < 20; t2++) v[t2] = wav[((size_t)c * 20 + t2) * HH + d];
        float mx = -1e30f;
        for (int tp = 0; tp < 20; tp++) {
            float s = bv[tp];
            for (int t2 = 0; t2 < 20; t2++) s += v[t2] * W[tp * 20 + t2];
            l[tp] = s; mx = fmaxf(mx, s);
        }
        float se = 0.f, o = 0.f;
        for (int tp = 0; tp < 20; tp++) {
            float e = expf(l[tp] - mx);
            se += e; o += e * v[tp];
        }
        cat1[(size_t)c * HH + d] = o / se;
    }
}

// ---------------- GAT: per-node alpha dots ----------------
__global__ void gat_dots_k(const float* __restrict__ h, const float* __restrict__ as_,
                           const float* __restrict__ ad_, float* __restrict__ ss,
                           float* __restrict__ sd)
{
    int i = blockIdx.x, tid = threadIdx.x;
    float s1 = 0.f, s2 = 0.f;
    for (int k = tid; k < HH; k += 256) {
        float v = h[(size_t)i * HH + k];
        s1 += v * as_[k]; s2 += v * ad_[k];
    }
    __shared__ float r1[256], r2[256];
    r1[tid] = s1; r2[tid] = s2; __syncthreads();
    for (int s = 128; s; s >>= 1) {
        if (tid < s) { r1[tid] += r1[tid + s]; r2[tid] += r2[tid + s]; }
        __syncthreads();
    }
    if (tid == 0) { ss[i] = r1[0]; sd[i] = r2[0]; }
}

// ---------------- GAT aggregate: block per dst node ----------------
#define MAXE 256
__global__ __launch_bounds__(256) void gat_agg_k(
    const float* __restrict__ hmat, const int* __restrict__ esrc,
    const int* __restrict__ edst, int nedges, const float* __restrict__ ss,
    const float* __restrict__ sd, const float* __restrict__ bias, float* __restrict__ outp)
{
    int i = blockIdx.x, tid = threadIdx.x;
    __shared__ int cnt;
    __shared__ int msrc[MAXE];
    __shared__ float mw[MAXE];
    __shared__ float inv_s;
    if (tid == 0) {
        cnt = 1; msrc[0] = i;
        float e = ss[i] + sd[i];
        mw[0] = e > 0.f ? e : 0.2f * e;
    }
    __syncthreads();
    for (int e = tid; e < nedges; e += 256) {
        if (edst[e] == i) {
            int p = atomicAdd(&cnt, 1);
            if (p < MAXE) {
                int s = esrc[e];
                msrc[p] = s;
                float v = ss[s] + sd[i];
                mw[p] = v > 0.f ? v : 0.2f * v;
            }
        }
    }
    __syncthreads();
    int m = min(cnt, MAXE);
    if (tid == 0) {
        float mx = -1e30f;
        for (int p = 0; p < m; p++) mx = fmaxf(mx, mw[p]);
        float s = 0.f;
        for (int p = 0; p < m; p++) { float e = expf(mw[p] - mx); mw[p] = e; s += e; }
        inv_s = 1.0f / s;
    }
    __syncthreads();
    for (int d = tid; d < HH; d += 256) {
        float a = 0.f;
        for (int p = 0; p < m; p++) a += mw[p] * hmat[(size_t)msrc[p] * HH + d];
        outp[(size_t)i * HH + d] = a * inv_s + bias[d];
    }
}

// ---------------- concat [wav3, cat, inner] ----------------
__global__ void concat_k(const float* __restrict__ wav, const float* __restrict__ gc,
                         const float* __restrict__ gi, float* __restrict__ cc)
{
    int row = blockIdx.x;
    int c = row / 20;
    for (int k = threadIdx.x; k < H3; k += 256) {
        float v;
        if (k < HH) v = wav[(size_t)row * HH + k];
        else if (k < 2 * HH) v = gc[(size_t)c * HH + (k - HH)];
        else v = gi[(size_t)row * HH + (k - 2 * HH)];
        cc[(size_t)row * H3 + k] = v;
    }
}

// ---------------- reg/cls heads ----------------
__global__ void heads_k(const float* __restrict__ f, const float* __restrict__ regW,
                        const float* __restrict__ regb, const float* __restrict__ clsW,
                        const float* __restrict__ clsb, float* __restrict__ outp)
{
    int i = blockIdx.x, tid = threadIdx.x;
    float s1 = 0.f, s2 = 0.f;
    for (int k = tid; k < HH; k += 256) {
        float v = f[(size_t)i * HH + k];
        s1 += v * regW[k]; s2 += v * clsW[k];
    }
    __shared__ float r1[256], r2[256];
    r1[tid] = s1; r2[tid] = s2; __syncthreads();
    for (int s = 128; s; s >>= 1) {
        if (tid < s) { r1[tid] += r1[tid + s]; r2[tid] += r2[tid + s]; }
        __syncthreads();
    }
    if (tid == 0) {
        outp[i] = r1[0] + regb[0];
        outp[100 + i] = sigf(r2[0] + clsb[0]);
    }
}

extern "C" void kernel_launch(void* const* d_in, const int* in_sizes, int n_in,
                              void* d_out, int out_size, void* d_ws, size_t ws_size,
                              hipStream_t stream)
{
    (void)in_sizes; (void)n_in; (void)out_size; (void)ws_size;
    const float* x0 = (const float*)d_in[0];
    const float* x1 = (const float*)d_in[1];
    const float* x2 = (const float*)d_in[2];
    const float* x3 = (const float*)d_in[3];
    const int*   ie = (const int*)d_in[4];
    const int*   oe = (const int*)d_in[5];
    const float* enc_Wih = (const float*)d_in[6];
    const float* enc_Whh = (const float*)d_in[7];
    const float* enc_bih = (const float*)d_in[8];
    const float* enc_bhh = (const float*)d_in[9];
    const float* enc_attW = (const float*)d_in[10];
    const float* enc_attb = (const float*)d_in[11];
    const float* wk_Wih = (const float*)d_in[12];
    const float* wk_Whh = (const float*)d_in[13];
    const float* wk_bih = (const float*)d_in[14];
    const float* wk_bhh = (const float*)d_in[15];
    const float* wkatt_W = (const float*)d_in[16];
    const float* wkatt_b = (const float*)d_in[17];
    const float* pool_W = (const float*)d_in[18];
    const float* pool_b = (const float*)d_in[19];
    const float* ig_W = (const float*)d_in[20];
    const float* ig_as = (const float*)d_in[21];
    const float* ig_ad = (const float*)d_in[22];
    const float* ig_b = (const float*)d_in[23];
    const float* cg_W = (const float*)d_in[24];
    const float* cg_as = (const float*)d_in[25];
    const float* cg_ad = (const float*)d_in[26];
    const float* cg_b = (const float*)d_in[27];
    const float* fus_W = (const float*)d_in[28];
    const float* fus_b = (const float*)d_in[29];
    const float* reg_W = (const float*)d_in[30];
    const float* reg_b = (const float*)d_in[31];
    const float* cls_W = (const float*)d_in[32];
    const float* cls_b = (const float*)d_in[33];
    float* outp = (float*)d_out;

    // workspace carve-up
    char* p = (char*)d_ws;
    auto alloc = [&](size_t bytes) { char* r = p; p += (bytes + 255) & ~(size_t)255; return (void*)r; };
    unsigned* bar = (unsigned*)alloc(16 * 4);   // [0..3]=enc cnt, [4..7]=enc gen, [8]=wk cnt, [9]=wk gen
    _Float16* Wcat = (_Float16*)alloc((size_t)NW * H3 * 1280 * 2);
    float* bc = (float*)alloc((size_t)NW * 4 * HH * 4);
    _Float16* wkW = (_Float16*)alloc((size_t)H3 * HH * 2);
    _Float16* xT = (_Float16*)alloc((size_t)NW * TT * 128 * II * 2);
    _Float16* hhA = (_Float16*)alloc((size_t)NW * 128 * HH * 2);
    _Float16* hhB = (_Float16*)alloc((size_t)NW * 128 * HH * 2);
    _Float16* seq = (_Float16*)alloc((size_t)NW * NST * TT * HH * 2);
    float* wex = (float*)alloc((size_t)NW * NST * HH * 4);
    float* gxw = (float*)alloc((size_t)NW * NST * H3 * 4);
    float* hwA = (float*)alloc(4 * HH * 4);
    float* hwB = (float*)alloc(4 * HH * 4);
    float* we2 = (float*)alloc((size_t)NST * 4 * HH * 4);
    float* wav = (float*)alloc((size_t)NST * HH * 4);
    float* hi  = (float*)alloc((size_t)NST * HH * 4);
    float* si_s = (float*)alloc(128 * 4);
    float* si_d = (float*)alloc(128 * 4);
    float* gi  = (float*)alloc((size_t)NST * HH * 4);
    float* cat1 = (float*)alloc(5 * HH * 4);
    float* hc  = (float*)alloc(5 * HH * 4);
    float* sc_s = (float*)alloc(64 * 4);
    float* sc_d = (float*)alloc(64 * 4);
    float* gc  = (float*)alloc(5 * HH * 4);
    float* cc  = (float*)alloc((size_t)NST * H3 * 4);
    float* fbuf = (float*)alloc((size_t)NST * HH * 4);

    // allow >64KB dynamic LDS for the fused encoder (once)
    static bool attr_done = false;
    if (!attr_done) {
        hipFuncSetAttribute((const void*)enc_fused_k,
                            hipFuncAttributeMaxDynamicSharedMemorySize, ENC_LDS_BYTES);
        attr_done = true;
    }

    // one-time conversions + zero-init (barrier state re-zeroed every replay)
    zero_k<<<1, 256, 0, stream>>>((float*)bar, 16);
    convW_k<<<dim3(5, H3, NW), 256, 0, stream>>>(enc_Whh, enc_Wih, Wcat);
    convB_k<<<dim3(4, NW), 256, 0, stream>>>(enc_bih, enc_bhh, bc);
    convWk_k<<<dim3(4, H3), 256, 0, stream>>>(wk_Whh, wkW);
    xcvt_k<<<8192, 256, 0, stream>>>(x0, x1, x2, x3, xT);
    zero_k<<<(NW * 128 * HH / 2 + 255) / 256, 256, 0, stream>>>((float*)hhA, NW * 128 * HH / 2);
    zero_k<<<(4 * HH + 255) / 256, 256, 0, stream>>>(hwA, 4 * HH);

    // 4-week encoder GRU: single kernel, 128 internal steps, per-week device barrier
    enc_fused_k<<<dim3(64, NW), 256, ENC_LDS_BYTES, stream>>>(
        Wcat, bc, xT, hhA, hhB, seq, bar);

    // per-week time attention -> wex[w][n][d]
    att1_k<<<dim3(8, NST, NW), 256, 0, stream>>>(seq, enc_attW, enc_attb, wex);

    // weekly GRU input projection (bias folded in)
    gemm_tn_k<0><<<dim3(48, 7), 256, 0, stream>>>(wex, wk_Wih, wk_bih, gxw, 400, H3, HH);

    // weekly GRU recurrence: single kernel, 100 internal steps, device barrier
    wk_fused_k<<<256, 256, 0, stream>>>(gxw, wkW, wk_bhh, hwA, hwB, we2, bar);

    // weekly attention -> wav (100,1024)
    wkatt_k<<<NST, 256, 0, stream>>>(we2, wkatt_W, wkatt_b, wav);

    // inner GAT
    gemm_tn_k<0><<<dim3(16, 2), 256, 0, stream>>>(wav, ig_W, nullptr, hi, NST, HH, HH);
    gat_dots_k<<<NST, 256, 0, stream>>>(hi, ig_as, ig_ad, si_s, si_d);
    gat_agg_k<<<NST, 256, 0, stream>>>(hi, ie, ie + 2000, 2000, si_s, si_d, ig_b, gi);

    // category pooling attention + outer GAT
    poolatt_k<<<5, 256, 0, stream>>>(wav, pool_W, pool_b, cat1);
    gemm_tn_k<0><<<dim3(16, 1), 256, 0, stream>>>(cat1, cg_W, nullptr, hc, 5, HH, HH);
    gat_dots_k<<<5, 256, 0, stream>>>(hc, cg_as, cg_ad, sc_s, sc_d);
    gat_agg_k<<<5, 256, 0, stream>>>(hc, oe, oe + 25, 25, sc_s, sc_d, cg_b, gc);

    // fusion + heads
    concat_k<<<NST, 256, 0, stream>>>(wav, gc, gi, cc);
    gemm_tn_k<1><<<dim3(16, 2), 256, 0, stream>>>(cc, fus_W, fus_b, fbuf, NST, HH, H3);
    heads_k<<<NST, 256, 0, stream>>>(fbuf, reg_W, reg_b, cls_W, cls_b, outp);
}

// Round 3
// 8753.773 us; speedup vs baseline: 1.2135x; 1.2135x over previous
//
#include <hip/hip_runtime.h>
#include <hip/hip_bf16.h>

#define NW 4
#define NST 100
#define TT 128
#define II 256
#define HH 1024
#define H3 3072

typedef _Float16 h8 __attribute__((ext_vector_type(8)));
typedef float f4 __attribute__((ext_vector_type(4)));

__device__ __forceinline__ float sigf(float x) { return 1.0f / (1.0f + expf(-x)); }

// ---------------- zero init ----------------
__global__ void zero_k(float* a, int n) {
    int i = blockIdx.x * 256 + threadIdx.x;
    if (i < n) a[i] = 0.0f;
}

// ---------------- weight concat + fp16 convert: Wc[w][3072][1280] = [Whh | Wih] ----
__global__ void convW_k(const float* __restrict__ Whh, const float* __restrict__ Wih,
                        _Float16* __restrict__ Wc) {
    int col = blockIdx.x * 256 + threadIdx.x;  // 0..1279
    int r = blockIdx.y;                        // 0..3071
    int w = blockIdx.z;
    float v = (col < HH) ? Whh[((size_t)w * H3 + r) * HH + col]
                         : Wih[((size_t)w * H3 + r) * II + (col - HH)];
    Wc[((size_t)w * H3 + r) * 1280 + col] = (_Float16)v;
}

// ---------------- weekly weights fp16 ----------------
__global__ void convWk_k(const float* __restrict__ src, _Float16* __restrict__ dst) {
    int col = blockIdx.x * 256 + threadIdx.x;  // 0..1023
    int r = blockIdx.y;                        // 0..3071
    dst[(size_t)r * HH + col] = (_Float16)src[(size_t)r * HH + col];
}

// ---------------- x -> fp16 padded transpose: xT[w][t][128][256] ----------------
__global__ void xcvt_k(const float* __restrict__ x0, const float* __restrict__ x1,
                       const float* __restrict__ x2, const float* __restrict__ x3,
                       _Float16* __restrict__ xT) {
    int idx = blockIdx.x * 256 + threadIdx.x;   // 2^21 total
    int k8 = idx & 31;
    int m  = (idx >> 5) & 127;
    int t  = (idx >> 12) & 127;
    int w  = idx >> 19;
    const float* xw = (w == 0) ? x0 : (w == 1) ? x1 : (w == 2) ? x2 : x3;
    h8 hv = {};
    if (m < NST) {
        const float* s = xw + ((size_t)m * TT + t) * II + k8 * 8;
        float4 fa = *(const float4*)s;
        float4 fb = *(const float4*)(s + 4);
        hv[0] = (_Float16)fa.x; hv[1] = (_Float16)fa.y;
        hv[2] = (_Float16)fa.z; hv[3] = (_Float16)fa.w;
        hv[4] = (_Float16)fb.x; hv[5] = (_Float16)fb.y;
        hv[6] = (_Float16)fb.z; hv[7] = (_Float16)fb.w;
    }
    *(h8*)&xT[(((size_t)w * TT + t) * 128 + m) * II + k8 * 8] = hv;
}

// ---------------- combined bias precompute: bc[w][{r,z,ni,nh}][1024] fp32 ----
__global__ void convB_k(const float* __restrict__ bih, const float* __restrict__ bhh,
                        float* __restrict__ bc) {
    int j = blockIdx.x * 256 + threadIdx.x;
    int w = blockIdx.y;
    const float* bi = bih + w * H3;
    const float* bh = bhh + w * H3;
    float* o = bc + w * 4096;
    o[j] = bi[j] + bh[j];
    o[1024 + j] = bi[1024 + j] + bh[1024 + j];
    o[2048 + j] = bi[2048 + j];
    o[3072 + j] = bh[2048 + j];
}

// ---------------- fused encoder GRU: entire 128-step recurrence in ONE kernel.
// Weights (48x1280 fp16 per block) resident in LDS, fp32 h master in registers,
// contention-free flag-array barrier per time step (per-week, 64 blocks). ------
#define ENC_LDS_HALFS (40 * 48 * 40)
#define ENC_LDS_BYTES (ENC_LDS_HALFS * 2)

__global__ __launch_bounds__(256) void enc_fused_k(
    const _Float16* __restrict__ Wc, const float* __restrict__ bc,
    const _Float16* __restrict__ xT,
    _Float16* __restrict__ hhA, _Float16* __restrict__ hhB,
    _Float16* __restrict__ seq, unsigned* flags)
{
    extern __shared__ _Float16 Bs[];   // [40 chunks][48 rows][40 halfs] stride-40 pad

    int j0 = blockIdx.x * 16;
    int w  = blockIdx.y;
    const _Float16* Wcw = Wc + (size_t)w * H3 * 1280;
    const float* bcw = bc + w * 4096;
    _Float16* hA = hhA + (size_t)w * 128 * HH;
    _Float16* hB = hhB + (size_t)w * 128 * HH;
    unsigned* fw = flags + (size_t)w * 64 * 16;   // per-week flag group, 64B stride

    int tid = threadIdx.x;
    int lane = tid & 63, wi = tid >> 6, quad = lane >> 4, l15 = lane & 15;

    // one-time weight staging: 192 threads, 16B each, 40 chunks
    if (tid < 192) {
        int brow = tid >> 2, bseg = tid & 3;
        const _Float16* bsrc =
            Wcw + (size_t)((brow >> 4) * 1024 + j0 + (brow & 15)) * 1280 + bseg * 8;
        #pragma unroll 8
        for (int c = 0; c < 40; c++) {
            uint4 v = *(const uint4*)(bsrc + c * 32);
            *(uint4*)&Bs[((size_t)c * 48 + brow) * 40 + bseg * 8] = v;
        }
    }
    __syncthreads();

    int j = j0 + l15;
    float br = bcw[j], bz = bcw[1024 + j], bni = bcw[2048 + j], bnh = bcw[3072 + j];
    int r0 = wi * 32 + l15, r1 = wi * 32 + 16 + l15;
    float hreg[2][4] = {};   // fp32 h master, block-private -> registers

    for (int t = 0; t < TT; t++) {
        const _Float16* hin = (t & 1) ? hB : hA;
        _Float16* hout = (t & 1) ? hA : hB;
        const _Float16* xt = xT + ((size_t)w * TT + t) * 128 * II;
        const _Float16* pA0h = hin + (size_t)r0 * HH + quad * 8;
        const _Float16* pA1h = hin + (size_t)r1 * HH + quad * 8;
        const _Float16* pA0x = xt + (size_t)r0 * II + quad * 8;
        const _Float16* pA1x = xt + (size_t)r1 * II + quad * 8;

        f4 aR[2] = {}, aZ[2] = {}, aNH[2] = {}, aNX[2] = {};
        h8 a0 = *(const h8*)pA0h;
        h8 a1 = *(const h8*)pA1h;
        #pragma unroll 4
        for (int c = 0; c < 40; c++) {
            // prefetch A chunk c+1 (global -> regs) while computing c
            h8 an0 = {}, an1 = {};
            if (c < 39) {
                int cn = c + 1;
                const _Float16* s0 = (cn < 32) ? pA0h + cn * 32 : pA0x + (cn - 32) * 32;
                const _Float16* s1 = (cn < 32) ? pA1h + cn * 32 : pA1x + (cn - 32) * 32;
                an0 = *(const h8*)s0;
                an1 = *(const h8*)s1;
            }
            const _Float16* bb = &Bs[(size_t)(c * 48) * 40];
            h8 bf0 = *(const h8*)&bb[l15 * 40 + quad * 8];
            h8 bf1 = *(const h8*)&bb[(16 + l15) * 40 + quad * 8];
            h8 bf2 = *(const h8*)&bb[(32 + l15) * 40 + quad * 8];
            aR[0] = __builtin_amdgcn_mfma_f32_16x16x32_f16(a0, bf0, aR[0], 0, 0, 0);
            aR[1] = __builtin_amdgcn_mfma_f32_16x16x32_f16(a1, bf0, aR[1], 0, 0, 0);
            aZ[0] = __builtin_amdgcn_mfma_f32_16x16x32_f16(a0, bf1, aZ[0], 0, 0, 0);
            aZ[1] = __builtin_amdgcn_mfma_f32_16x16x32_f16(a1, bf1, aZ[1], 0, 0, 0);
            if (c < 32) {
                aNH[0] = __builtin_amdgcn_mfma_f32_16x16x32_f16(a0, bf2, aNH[0], 0, 0, 0);
                aNH[1] = __builtin_amdgcn_mfma_f32_16x16x32_f16(a1, bf2, aNH[1], 0, 0, 0);
            } else {
                aNX[0] = __builtin_amdgcn_mfma_f32_16x16x32_f16(a0, bf2, aNX[0], 0, 0, 0);
                aNX[1] = __builtin_amdgcn_mfma_f32_16x16x32_f16(a1, bf2, aNX[1], 0, 0, 0);
            }
            a0 = an0; a1 = an1;
        }

        // ---- gate epilogue: C/D mapping col=lane&15, row=quad*4+reg ----
        #pragma unroll
        for (int mi = 0; mi < 2; mi++) {
            #pragma unroll
            for (int p = 0; p < 4; p++) {
                int row = wi * 32 + mi * 16 + quad * 4 + p;
                float r = sigf(aR[mi][p] + br);
                float z = sigf(aZ[mi][p] + bz);
                float n = tanhf(aNX[mi][p] + bni + r * (aNH[mi][p] + bnh));
                float hv = (1.f - z) * n + z * hreg[mi][p];
                hreg[mi][p] = hv;
                hout[(size_t)row * HH + j] = (_Float16)hv;
                if (row < NST)
                    seq[(((size_t)w * NST + row) * TT + t) * HH + j] = (_Float16)hv;
            }
        }
        // ---- flag-array barrier (64 blocks of this week), skip after last step ----
        if (t < TT - 1) {
            __syncthreads();   // drains vmcnt: all h/seq stores issued
            if (tid == 0)
                __hip_atomic_store(&fw[blockIdx.x * 16], (unsigned)(t + 1),
                                   __ATOMIC_RELEASE, __HIP_MEMORY_SCOPE_AGENT);
            if (tid < 64) {
                while (__hip_atomic_load(&fw[tid * 16], __ATOMIC_RELAXED,
                                         __HIP_MEMORY_SCOPE_AGENT) <= (unsigned)t)
                    __builtin_amdgcn_s_sleep(1);
            }
            __syncthreads();
            __threadfence();   // acquire: invalidate stale cached h before next step
        }
    }
}

// ---------------- encoder time-attention (fp16 seq, vectorized) ----------------
__global__ __launch_bounds__(256) void att1_k(
    const _Float16* __restrict__ seq, const float* __restrict__ attW,
    const float* __restrict__ attb, float* __restrict__ wex)
{
    int d0 = blockIdx.x * 128;
    int n  = blockIdx.y;
    int w  = blockIdx.z;
    __shared__ _Float16 S[128][128];  // [t][d]
    __shared__ float PM[16][136];
    int tid = threadIdx.x;
    const _Float16* sp = seq + ((size_t)(w * NST + n) * TT) * HH + d0;
    for (int q = tid; q < 2048; q += 256) {
        int t = q >> 4, seg = q & 15;
        *(h8*)&S[t][seg * 8] = *(const h8*)(sp + (size_t)t * HH + seg * 8);
    }
    __syncthreads();
    int tx = tid & 15, ty = tid >> 4;
    const float* Wg = attW + (size_t)w * TT * TT;
    float acc[8][8];
    #pragma unroll
    for (int i = 0; i < 8; i++) {
        float b = attb[w * TT + ty * 8 + i];
        for (int j = 0; j < 8; j++) acc[i][j] = b;
    }
    for (int t = 0; t < 128; t++) {
        float wv[8], sv[8];
        #pragma unroll
        for (int i = 0; i < 8; i++) wv[i] = Wg[(ty * 8 + i) * TT + t];
        h8 s8 = *(const h8*)&S[t][tx * 8];
        #pragma unroll
        for (int j = 0; j < 8; j++) sv[j] = (float)s8[j];
        #pragma unroll
        for (int i = 0; i < 8; i++)
            #pragma unroll
            for (int j = 0; j < 8; j++) acc[i][j] += wv[i] * sv[j];
    }
    float cmax[8], csum[8];
    #pragma unroll
    for (int j = 0; j < 8; j++) {
        float m = acc[0][j];
        for (int i = 1; i < 8; i++) m = fmaxf(m, acc[i][j]);
        PM[ty][tx * 8 + j] = m;
    }
    __syncthreads();
    #pragma unroll
    for (int j = 0; j < 8; j++) {
        float m = -1e30f;
        for (int yy = 0; yy < 16; yy++) m = fmaxf(m, PM[yy][tx * 8 + j]);
        cmax[j] = m;
    }
    __syncthreads();
    #pragma unroll
    for (int j = 0; j < 8; j++) {
        float s = 0.f;
        for (int i = 0; i < 8; i++) { acc[i][j] = expf(acc[i][j] - cmax[j]); s += acc[i][j]; }
        PM[ty][tx * 8 + j] = s;
    }
    __syncthreads();
    #pragma unroll
    for (int j = 0; j < 8; j++) {
        float s = 0.f;
        for (int yy = 0; yy < 16; yy++) s += PM[yy][tx * 8 + j];
        csum[j] = s;
    }
    __syncthreads();
    #pragma unroll
    for (int i = 0; i < 8; i++) {
        h8 s8 = *(const h8*)&S[ty * 8 + i][tx * 8];
        #pragma unroll
        for (int j = 0; j < 8; j++) {
            if (i == 0) PM[ty][tx * 8 + j] = 0.f;
            PM[ty][tx * 8 + j] += acc[i][j] * (float)s8[j];
        }
    }
    __syncthreads();
    if (ty == 0) {
        #pragma unroll
        for (int j = 0; j < 8; j++) {
            float o = 0.f;
            for (int yy = 0; yy < 16; yy++) o += PM[yy][tx * 8 + j];
            wex[((size_t)w * NST + n) * HH + d0 + tx * 8 + j] = o / csum[j];
        }
    }
}

// ---------------- generic fp32 GEMM: C[m][n] = sum_k A[m][k]*B[n][k] (+bias, relu) ----
template <int RELU>
__global__ __launch_bounds__(256) void gemm_tn_k(
    const float* __restrict__ A, const float* __restrict__ B,
    const float* __restrict__ bias, float* __restrict__ C, int M, int N, int K)
{
    int n0 = blockIdx.x * 64, m0 = blockIdx.y * 64;
    __shared__ float As[16][64], Bs[16][64];
    int tid = threadIdx.x, tx = tid & 15, ty = tid >> 4;
    float acc[4][4] = {{0.f}};
    for (int k0 = 0; k0 < K; k0 += 16) {
        __syncthreads();
        for (int q = tid; q < 1024; q += 256) {
            int kk = q & 15, r = q >> 4;
            int m = m0 + r, nn = n0 + r;
            As[kk][r] = (m < M) ? A[(size_t)m * K + k0 + kk] : 0.f;
            Bs[kk][r] = (nn < N) ? B[(size_t)nn * K + k0 + kk] : 0.f;
        }
        __syncthreads();
        #pragma unroll
        for (int kk = 0; kk < 16; kk++) {
            float4 av = *(const float4*)&As[kk][ty * 4];
            float4 bv = *(const float4*)&Bs[kk][tx * 4];
            float a[4] = {av.x, av.y, av.z, av.w};
            float b[4] = {bv.x, bv.y, bv.z, bv.w};
            #pragma unroll
            for (int r = 0; r < 4; r++)
                #pragma unroll
                for (int c = 0; c < 4; c++) acc[r][c] += a[r] * b[c];
        }
    }
    #pragma unroll
    for (int r = 0; r < 4; r++) {
        int m = m0 + ty * 4 + r;
        if (m >= M) continue;
        #pragma unroll
        for (int c = 0; c < 4; c++) {
            int nn = n0 + tx * 4 + c;
            if (nn >= N) continue;
            float v = acc[r][c] + (bias ? bias[nn] : 0.f);
            if (RELU) v = fmaxf(v, 0.f);
            C[(size_t)m * N + nn] = v;
        }
    }
}

// ---------------- fused weekly GRU: entire 100-step recurrence in ONE kernel,
// weight fragments register-resident, flag-array barrier (256 blocks) ----------
__global__ __launch_bounds__(256) void wk_fused_k(
    const float* __restrict__ gxw, const _Float16* __restrict__ wkW,
    const float* __restrict__ bhh, float* __restrict__ hA,
    float* __restrict__ hB, float* __restrict__ we2, unsigned* flags)
{
    int tid = threadIdx.x;
    int wi = tid >> 6, lane = tid & 63;
    int j = blockIdx.x * 4 + wi;
    int k0 = lane * 16;
    float wf[3][16];
    #pragma unroll
    for (int g = 0; g < 3; g++) {
        h8 wa = *(const h8*)&wkW[(size_t)(g * HH + j) * HH + k0];
        h8 wb = *(const h8*)&wkW[(size_t)(g * HH + j) * HH + k0 + 8];
        #pragma unroll
        for (int i = 0; i < 8; i++) { wf[g][i] = (float)wa[i]; wf[g][8 + i] = (float)wb[i]; }
    }
    float b0 = bhh[j], b1 = bhh[HH + j], b2 = bhh[2 * HH + j];

    for (int t = 0; t < NST; t++) {
        const float* hin = (t & 1) ? hB : hA;
        float* hout = (t & 1) ? hA : hB;
        float acc[4][3] = {};
        #pragma unroll
        for (int b = 0; b < 4; b++) {
            float hv[16];
            #pragma unroll
            for (int s = 0; s < 4; s++) {
                float4 hq = *(const float4*)&hin[b * HH + k0 + s * 4];
                hv[s * 4] = hq.x; hv[s * 4 + 1] = hq.y;
                hv[s * 4 + 2] = hq.z; hv[s * 4 + 3] = hq.w;
            }
            #pragma unroll
            for (int g = 0; g < 3; g++)
                #pragma unroll
                for (int i = 0; i < 16; i++) acc[b][g] += wf[g][i] * hv[i];
        }
        #pragma unroll
        for (int b = 0; b < 4; b++)
            #pragma unroll
            for (int g = 0; g < 3; g++)
                for (int o = 32; o; o >>= 1) acc[b][g] += __shfl_down(acc[b][g], o);
        if (lane == 0) {
            for (int b = 0; b < 4; b++) {
                const float* gx = gxw + ((size_t)b * NST + t) * H3;
                float hr = acc[b][0] + b0;
                float hz = acc[b][1] + b1;
                float hn = acc[b][2] + b2;
                float r = sigf(gx[j] + hr);
                float z = sigf(gx[HH + j] + hz);
                float n = tanhf(gx[2 * HH + j] + r * hn);
                float hv = (1.f - z) * n + z * hin[b * HH + j];
                hout[b * HH + j] = hv;
                we2[((size_t)t * 4 + b) * HH + j] = hv;
            }
        }
        // ---- flag-array barrier across 256 blocks, skip after last step ----
        if (t < NST - 1) {
            __syncthreads();
            if (tid == 0)
                __hip_atomic_store(&flags[blockIdx.x * 16], (unsigned)(t + 1),
                                   __ATOMIC_RELEASE, __HIP_MEMORY_SCOPE_AGENT);
            while (__hip_atomic_load(&flags[tid * 16], __ATOMIC_RELAXED,
                                     __HIP_MEMORY_SCOPE_AGENT) <= (unsigned)t)
                __builtin_amdgcn_s_sleep(1);
            __syncthreads();
            __threadfence();
        }
    }
}

// ---------------- weekly attention (T=4) ----------------
__global__ void wkatt_k(const float* __restrict__ we2, const float* __restrict__ W,
                        const float* __restrict__ bv, float* __restrict__ wav)
{
    int n = blockIdx.x;
    for (int d = threadIdx.x; d < HH; d += 256) {
        float v[4], l[4];
        #pragma unroll
        for (int tp = 0; tp < 4; tp++) v[tp] = we2[((size_t)n * 4 + tp) * HH + d];
        float mx = -1e30f;
        #pragma unroll
        for (int tp = 0; tp < 4; tp++) {
            float s = bv[tp];
            for (int t2 = 0; t2 < 4; t2++) s += v[t2] * W[tp * 4 + t2];
            l[tp] = s; mx = fmaxf(mx, s);
        }
        float se = 0.f, o = 0.f;
        #pragma unroll
        for (int tp = 0; tp < 4; tp++) {
            float e = expf(l[tp] - mx);
            se += e; o += e * v[tp];
        }
        wav[(size_t)n * HH + d] = o / se;
    }
}

// ---------------- pool attention (C=5, T=20) ----------------
__global__ void poolatt_k(const float* __restrict__ wav, const float* __restrict__ W,
                          const float* __restrict__ bv, float* __restrict__ cat1)
{
    int c = blockIdx.x;
    for (int d = threadIdx.x; d < HH; d += 256) {
        float v[20], l[20];
        for (int t2 = 0; t2 < 20; t2++) v[t2] = wav[((size_t)c * 20 + t2) * HH + d];
        float mx = -1e30f;
        for (int tp = 0; tp < 20; tp++) {
            float s = bv[tp];
            for (int t2 = 0; t2 < 20; t2++) s += v[t2] * W[tp * 20 + t2];
            l[tp] = s; mx = fmaxf(mx, s);
        }
        float se = 0.f, o = 0.f;
        for (int tp = 0; tp < 20; tp++) {
            float e = expf(l[tp] - mx);
            se += e; o += e * v[tp];
        }
        cat1[(size_t)c * HH + d] = o / se;
    }
}

// ---------------- GAT: per-node alpha dots ----------------
__global__ void gat_dots_k(const float* __restrict__ h, const float* __restrict__ as_,
                           const float* __restrict__ ad_, float* __restrict__ ss,
                           float* __restrict__ sd)
{
    int i = blockIdx.x, tid = threadIdx.x;
    float s1 = 0.f, s2 = 0.f;
    for (int k = tid; k < HH; k += 256) {
        float v = h[(size_t)i * HH + k];
        s1 += v * as_[k]; s2 += v * ad_[k];
    }
    __shared__ float r1[256], r2[256];
    r1[tid] = s1; r2[tid] = s2; __syncthreads();
    for (int s = 128; s; s >>= 1) {
        if (tid < s) { r1[tid] += r1[tid + s]; r2[tid] += r2[tid + s]; }
        __syncthreads();
    }
    if (tid == 0) { ss[i] = r1[0]; sd[i] = r2[0]; }
}

// ---------------- GAT aggregate: block per dst node ----------------
#define MAXE 256
__global__ __launch_bounds__(256) void gat_agg_k(
    const float* __restrict__ hmat, const int* __restrict__ esrc,
    const int* __restrict__ edst, int nedges, const float* __restrict__ ss,
    const float* __restrict__ sd, const float* __restrict__ bias, float* __restrict__ outp)
{
    int i = blockIdx.x, tid = threadIdx.x;
    __shared__ int cnt;
    __shared__ int msrc[MAXE];
    __shared__ float mw[MAXE];
    __shared__ float inv_s;
    if (tid == 0) {
        cnt = 1; msrc[0] = i;
        float e = ss[i] + sd[i];
        mw[0] = e > 0.f ? e : 0.2f * e;
    }
    __syncthreads();
    for (int e = tid; e < nedges; e += 256) {
        if (edst[e] == i) {
            int p = atomicAdd(&cnt, 1);
            if (p < MAXE) {
                int s = esrc[e];
                msrc[p] = s;
                float v = ss[s] + sd[i];
                mw[p] = v > 0.f ? v : 0.2f * v;
            }
        }
    }
    __syncthreads();
    int m = min(cnt, MAXE);
    if (tid == 0) {
        float mx = -1e30f;
        for (int p = 0; p < m; p++) mx = fmaxf(mx, mw[p]);
        float s = 0.f;
        for (int p = 0; p < m; p++) { float e = expf(mw[p] - mx); mw[p] = e; s += e; }
        inv_s = 1.0f / s;
    }
    __syncthreads();
    for (int d = tid; d < HH; d += 256) {
        float a = 0.f;
        for (int p = 0; p < m; p++) a += mw[p] * hmat[(size_t)msrc[p] * HH + d];
        outp[(size_t)i * HH + d] = a * inv_s + bias[d];
    }
}

// ---------------- concat [wav3, cat, inner] ----------------
__global__ void concat_k(const float* __restrict__ wav, const float* __restrict__ gc,
                         const float* __restrict__ gi, float* __restrict__ cc)
{
    int row = blockIdx.x;
    int c = row / 20;
    for (int k = threadIdx.x; k < H3; k += 256) {
        float v;
        if (k < HH) v = wav[(size_t)row * HH + k];
        else if (k < 2 * HH) v = gc[(size_t)c * HH + (k - HH)];
        else v = gi[(size_t)row * HH + (k - 2 * HH)];
        cc[(size_t)row * H3 + k] = v;
    }
}

// ---------------- reg/cls heads ----------------
__global__ void heads_k(const float* __restrict__ f, const float* __restrict__ regW,
                        const float* __restrict__ regb, const float* __restrict__ clsW,
                        const float* __restrict__ clsb, float* __restrict__ outp)
{
    int i = blockIdx.x, tid = threadIdx.x;
    float s1 = 0.f, s2 = 0.f;
    for (int k = tid; k < HH; k += 256) {
        float v = f[(size_t)i * HH + k];
        s1 += v * regW[k]; s2 += v * clsW[k];
    }
    __shared__ float r1[256], r2[256];
    r1[tid] = s1; r2[tid] = s2; __syncthreads();
    for (int s = 128; s; s >>= 1) {
        if (tid < s) { r1[tid] += r1[tid + s]; r2[tid] += r2[tid + s]; }
        __syncthreads();
    }
    if (tid == 0) {
        outp[i] = r1[0] + regb[0];
        outp[100 + i] = sigf(r2[0] + clsb[0]);
    }
}

extern "C" void kernel_launch(void* const* d_in, const int* in_sizes, int n_in,
                              void* d_out, int out_size, void* d_ws, size_t ws_size,
                              hipStream_t stream)
{
    (void)in_sizes; (void)n_in; (void)out_size; (void)ws_size;
    const float* x0 = (const float*)d_in[0];
    const float* x1 = (const float*)d_in[1];
    const float* x2 = (const float*)d_in[2];
    const float* x3 = (const float*)d_in[3];
    const int*   ie = (const int*)d_in[4];
    const int*   oe = (const int*)d_in[5];
    const float* enc_Wih = (const float*)d_in[6];
    const float* enc_Whh = (const float*)d_in[7];
    const float* enc_bih = (const float*)d_in[8];
    const float* enc_bhh = (const float*)d_in[9];
    const float* enc_attW = (const float*)d_in[10];
    const float* enc_attb = (const float*)d_in[11];
    const float* wk_Wih = (const float*)d_in[12];
    const float* wk_Whh = (const float*)d_in[13];
    const float* wk_bih = (const float*)d_in[14];
    const float* wk_bhh = (const float*)d_in[15];
    const float* wkatt_W = (const float*)d_in[16];
    const float* wkatt_b = (const float*)d_in[17];
    const float* pool_W = (const float*)d_in[18];
    const float* pool_b = (const float*)d_in[19];
    const float* ig_W = (const float*)d_in[20];
    const float* ig_as = (const float*)d_in[21];
    const float* ig_ad = (const float*)d_in[22];
    const float* ig_b = (const float*)d_in[23];
    const float* cg_W = (const float*)d_in[24];
    const float* cg_as = (const float*)d_in[25];
    const float* cg_ad = (const float*)d_in[26];
    const float* cg_b = (const float*)d_in[27];
    const float* fus_W = (const float*)d_in[28];
    const float* fus_b = (const float*)d_in[29];
    const float* reg_W = (const float*)d_in[30];
    const float* reg_b = (const float*)d_in[31];
    const float* cls_W = (const float*)d_in[32];
    const float* cls_b = (const float*)d_in[33];
    float* outp = (float*)d_out;

    // workspace carve-up
    char* p = (char*)d_ws;
    auto alloc = [&](size_t bytes) { char* r = p; p += (bytes + 255) & ~(size_t)255; return (void*)r; };
    unsigned* flags = (unsigned*)alloc(2 * 256 * 16 * 4);  // [0..255]=enc (4 weeks x 64), [256..511]=wk
    _Float16* Wcat = (_Float16*)alloc((size_t)NW * H3 * 1280 * 2);
    float* bc = (float*)alloc((size_t)NW * 4 * HH * 4);
    _Float16* wkW = (_Float16*)alloc((size_t)H3 * HH * 2);
    _Float16* xT = (_Float16*)alloc((size_t)NW * TT * 128 * II * 2);
    _Float16* hhA = (_Float16*)alloc((size_t)NW * 128 * HH * 2);
    _Float16* hhB = (_Float16*)alloc((size_t)NW * 128 * HH * 2);
    _Float16* seq = (_Float16*)alloc((size_t)NW * NST * TT * HH * 2);
    float* wex = (float*)alloc((size_t)NW * NST * HH * 4);
    float* gxw = (float*)alloc((size_t)NW * NST * H3 * 4);
    float* hwA = (float*)alloc(4 * HH * 4);
    float* hwB = (float*)alloc(4 * HH * 4);
    float* we2 = (float*)alloc((size_t)NST * 4 * HH * 4);
    float* wav = (float*)alloc((size_t)NST * HH * 4);
    float* hi  = (float*)alloc((size_t)NST * HH * 4);
    float* si_s = (float*)alloc(128 * 4);
    float* si_d = (float*)alloc(128 * 4);
    float* gi  = (float*)alloc((size_t)NST * HH * 4);
    float* cat1 = (float*)alloc(5 * HH * 4);
    float* hc  = (float*)alloc(5 * HH * 4);
    float* sc_s = (float*)alloc(64 * 4);
    float* sc_d = (float*)alloc(64 * 4);
    float* gc  = (float*)alloc(5 * HH * 4);
    float* cc  = (float*)alloc((size_t)NST * H3 * 4);
    float* fbuf = (float*)alloc((size_t)NST * HH * 4);

    // allow >64KB dynamic LDS for the fused encoder (once)
    static bool attr_done = false;
    if (!attr_done) {
        hipFuncSetAttribute((const void*)enc_fused_k,
                            hipFuncAttributeMaxDynamicSharedMemorySize, ENC_LDS_BYTES);
        attr_done = true;
    }

    // one-time conversions + zero-init (flag state re-zeroed every replay)
    zero_k<<<32, 256, 0, stream>>>((float*)flags, 2 * 256 * 16);
    convW_k<<<dim3(5, H3, NW), 256, 0, stream>>>(enc_Whh, enc_Wih, Wcat);
    convB_k<<<dim3(4, NW), 256, 0, stream>>>(enc_bih, enc_bhh, bc);
    convWk_k<<<dim3(4, H3), 256, 0, stream>>>(wk_Whh, wkW);
    xcvt_k<<<8192, 256, 0, stream>>>(x0, x1, x2, x3, xT);
    zero_k<<<(NW * 128 * HH / 2 + 255) / 256, 256, 0, stream>>>((float*)hhA, NW * 128 * HH / 2);
    zero_k<<<(4 * HH + 255) / 256, 256, 0, stream>>>(hwA, 4 * HH);

    // 4-week encoder GRU: single kernel, 128 internal steps, flag-array barrier
    enc_fused_k<<<dim3(64, NW), 256, ENC_LDS_BYTES, stream>>>(
        Wcat, bc, xT, hhA, hhB, seq, flags);

    // per-week time attention -> wex[w][n][d]
    att1_k<<<dim3(8, NST, NW), 256, 0, stream>>>(seq, enc_attW, enc_attb, wex);

    // weekly GRU input projection (bias folded in)
    gemm_tn_k<0><<<dim3(48, 7), 256, 0, stream>>>(wex, wk_Wih, wk_bih, gxw, 400, H3, HH);

    // weekly GRU recurrence: single kernel, 100 internal steps, flag-array barrier
    wk_fused_k<<<256, 256, 0, stream>>>(gxw, wkW, wk_bhh, hwA, hwB, we2, flags + 256 * 16);

    // weekly attention -> wav (100,1024)
    wkatt_k<<<NST, 256, 0, stream>>>(we2, wkatt_W, wkatt_b, wav);

    // inner GAT
    gemm_tn_k<0><<<dim3(16, 2), 256, 0, stream>>>(wav, ig_W, nullptr, hi, NST, HH, HH);
    gat_dots_k<<<NST, 256, 0, stream>>>(hi, ig_as, ig_ad, si_s, si_d);
    gat_agg_k<<<NST, 256, 0, stream>>>(hi, ie, ie + 2000, 2000, si_s, si_d, ig_b, gi);

    // category pooling attention + outer GAT
    poolatt_k<<<5, 256, 0, stream>>>(wav, pool_W, pool_b, cat1);
    gemm_tn_k<0><<<dim3(16, 1), 256, 0, stream>>>(cat1, cg_W, nullptr, hc, 5, HH, HH);
    gat_dots_k<<<5, 256, 0, stream>>>(hc, cg_as, cg_ad, sc_s, sc_d);
    gat_agg_k<<<5, 256, 0, stream>>>(hc, oe, oe + 25, 25, sc_s, sc_d, cg_b, gc);

    // fusion + heads
    concat_k<<<NST, 256, 0, stream>>>(wav, gc, gi, cc);
    gemm_tn_k<1><<<dim3(16, 2), 256, 0, stream>>>(cc, fus_W, fus_b, fbuf, NST, HH, H3);
    heads_k<<<NST, 256, 0, stream>>>(fbuf, reg_W, reg_b, cls_W, cls_b, outp);
}

// Round 5
// 6633.362 us; speedup vs baseline: 1.6014x; 1.3197x over previous
//
#include <hip/hip_runtime.h>
#include <hip/hip_bf16.h>

#define NW 4
#define NST 100
#define TT 128
#define II 256
#define HH 1024
#define H3 3072

typedef _Float16 h8 __attribute__((ext_vector_type(8)));
typedef float f4 __attribute__((ext_vector_type(4)));

__device__ __forceinline__ float sigf(float x) { return 1.0f / (1.0f + expf(-x)); }

// ---- coherent (L3-direct, sc1) loads: bypass L1/L2 so no acquire fence needed ----
__device__ __forceinline__ h8 ld_h8_sc1(const _Float16* p) {
    union { unsigned long long u[2]; h8 v; } r;
    r.u[0] = __hip_atomic_load((unsigned long long*)p, __ATOMIC_RELAXED, __HIP_MEMORY_SCOPE_AGENT);
    r.u[1] = __hip_atomic_load((unsigned long long*)p + 1, __ATOMIC_RELAXED, __HIP_MEMORY_SCOPE_AGENT);
    return r.v;
}
__device__ __forceinline__ float4 ld_f4_sc1(const float* p) {
    union { unsigned long long u[2]; float4 v; } r;
    r.u[0] = __hip_atomic_load((unsigned long long*)p, __ATOMIC_RELAXED, __HIP_MEMORY_SCOPE_AGENT);
    r.u[1] = __hip_atomic_load((unsigned long long*)p + 1, __ATOMIC_RELAXED, __HIP_MEMORY_SCOPE_AGENT);
    return r.v;
}
__device__ __forceinline__ float ld_f_sc1(const float* p) {
    return __hip_atomic_load((float*)p, __ATOMIC_RELAXED, __HIP_MEMORY_SCOPE_AGENT);
}

// ---- bounded spin: never hang the queue; a sync failure becomes a clean mismatch ----
__device__ __forceinline__ void spin_wait(unsigned* f, unsigned t) {
    int guard = 0;
    while (__hip_atomic_load(f, __ATOMIC_RELAXED, __HIP_MEMORY_SCOPE_AGENT) <= t) {
        __builtin_amdgcn_s_sleep(2);
        if (++guard > (1 << 20)) break;
    }
}

// ---------------- zero init ----------------
__global__ void zero_k(float* a, int n) {
    int i = blockIdx.x * 256 + threadIdx.x;
    if (i < n) a[i] = 0.0f;
}

// ---------------- weight concat + fp16 convert: Wc[w][3072][1280] = [Whh | Wih] ----
__global__ void convW_k(const float* __restrict__ Whh, const float* __restrict__ Wih,
                        _Float16* __restrict__ Wc) {
    int col = blockIdx.x * 256 + threadIdx.x;  // 0..1279
    int r = blockIdx.y;                        // 0..3071
    int w = blockIdx.z;
    float v = (col < HH) ? Whh[((size_t)w * H3 + r) * HH + col]
                         : Wih[((size_t)w * H3 + r) * II + (col - HH)];
    Wc[((size_t)w * H3 + r) * 1280 + col] = (_Float16)v;
}

// ---------------- weekly weights fp16 ----------------
__global__ void convWk_k(const float* __restrict__ src, _Float16* __restrict__ dst) {
    int col = blockIdx.x * 256 + threadIdx.x;  // 0..1023
    int r = blockIdx.y;                        // 0..3071
    dst[(size_t)r * HH + col] = (_Float16)src[(size_t)r * HH + col];
}

// ---------------- x -> fp16 padded transpose: xT[w][t][128][256] ----------------
__global__ void xcvt_k(const float* __restrict__ x0, const float* __restrict__ x1,
                       const float* __restrict__ x2, const float* __restrict__ x3,
                       _Float16* __restrict__ xT) {
    int idx = blockIdx.x * 256 + threadIdx.x;   // 2^21 total
    int k8 = idx & 31;
    int m  = (idx >> 5) & 127;
    int t  = (idx >> 12) & 127;
    int w  = idx >> 19;
    const float* xw = (w == 0) ? x0 : (w == 1) ? x1 : (w == 2) ? x2 : x3;
    h8 hv = {};
    if (m < NST) {
        const float* s = xw + ((size_t)m * TT + t) * II + k8 * 8;
        float4 fa = *(const float4*)s;
        float4 fb = *(const float4*)(s + 4);
        hv[0] = (_Float16)fa.x; hv[1] = (_Float16)fa.y;
        hv[2] = (_Float16)fa.z; hv[3] = (_Float16)fa.w;
        hv[4] = (_Float16)fb.x; hv[5] = (_Float16)fb.y;
        hv[6] = (_Float16)fb.z; hv[7] = (_Float16)fb.w;
    }
    *(h8*)&xT[(((size_t)w * TT + t) * 128 + m) * II + k8 * 8] = hv;
}

// ---------------- attW transpose: wT[w][t][tp] = attW[w][tp][t] ----------------
__global__ void wTcvt_k(const float* __restrict__ attW, float* __restrict__ wT) {
    int tp = threadIdx.x;        // 0..127
    int t  = blockIdx.x;         // 0..127
    int w  = blockIdx.y;
    wT[((size_t)w * TT + t) * TT + tp] = attW[((size_t)w * TT + tp) * TT + t];
}

// ---------------- combined bias precompute: bc[w][{r,z,ni,nh}][1024] fp32 ----
__global__ void convB_k(const float* __restrict__ bih, const float* __restrict__ bhh,
                        float* __restrict__ bc) {
    int j = blockIdx.x * 256 + threadIdx.x;
    int w = blockIdx.y;
    const float* bi = bih + w * H3;
    const float* bh = bhh + w * H3;
    float* o = bc + w * 4096;
    o[j] = bi[j] + bh[j];
    o[1024 + j] = bi[1024 + j] + bh[1024 + j];
    o[2048 + j] = bi[2048 + j];
    o[3072 + j] = bh[2048 + j];
}

// ---------------- fused encoder GRU: entire 128-step recurrence in ONE kernel.
// Weights in LDS, fp32 h master in registers, 8-deep A-prefetch ring,
// flag barrier with sc1 h-exchange (NO per-step L2 invalidate). ----------------
#define ENC_LDS_HALFS (40 * 48 * 40)
#define ENC_LDS_BYTES (ENC_LDS_HALFS * 2)

__global__ __launch_bounds__(256) void enc_fused_k(
    const _Float16* __restrict__ Wc, const float* __restrict__ bc,
    const _Float16* __restrict__ xT,
    _Float16* __restrict__ hhA, _Float16* __restrict__ hhB,
    _Float16* __restrict__ seq, unsigned* flags)
{
    extern __shared__ _Float16 Bs[];   // [40 chunks][48 rows][40 halfs] stride-40 pad

    int j0 = blockIdx.x * 16;
    int w  = blockIdx.y;
    const _Float16* Wcw = Wc + (size_t)w * H3 * 1280;
    const float* bcw = bc + w * 4096;
    _Float16* hA = hhA + (size_t)w * 128 * HH;
    _Float16* hB = hhB + (size_t)w * 128 * HH;
    unsigned* fw = flags + (size_t)w * 64 * 16;   // per-week flag group, 64B stride

    int tid = threadIdx.x;
    int lane = tid & 63, wi = tid >> 6, quad = lane >> 4, l15 = lane & 15;

    // one-time weight staging: 192 threads, 16B each, 40 chunks
    if (tid < 192) {
        int brow = tid >> 2, bseg = tid & 3;
        const _Float16* bsrc =
            Wcw + (size_t)((brow >> 4) * 1024 + j0 + (brow & 15)) * 1280 + bseg * 8;
        #pragma unroll 8
        for (int c = 0; c < 40; c++) {
            uint4 v = *(const uint4*)(bsrc + c * 32);
            *(uint4*)&Bs[((size_t)c * 48 + brow) * 40 + bseg * 8] = v;
        }
    }
    __syncthreads();

    int j = j0 + l15;
    float br = bcw[j], bz = bcw[1024 + j], bni = bcw[2048 + j], bnh = bcw[3072 + j];
    int r0 = wi * 32 + l15, r1 = wi * 32 + 16 + l15;
    float hreg[2][4] = {};   // fp32 h master, block-private -> registers

    for (int t = 0; t < TT; t++) {
        const _Float16* hin = (t & 1) ? hB : hA;
        _Float16* hout = (t & 1) ? hA : hB;
        const _Float16* xt = xT + ((size_t)w * TT + t) * 128 * II;
        const _Float16* pA0h = hin + (size_t)r0 * HH + quad * 8;
        const _Float16* pA1h = hin + (size_t)r1 * HH + quad * 8;
        const _Float16* pA0x = xt + (size_t)r0 * II + quad * 8;
        const _Float16* pA1x = xt + (size_t)r1 * II + quad * 8;

        f4 aR[2] = {}, aZ[2] = {}, aNH[2] = {}, aNX[2] = {};

        // 8-deep prefetch ring: chunks 0..7 (h, coherent sc1 loads)
        h8 rb0[8], rb1[8];
        #pragma unroll
        for (int u = 0; u < 8; u++) {
            rb0[u] = ld_h8_sc1(pA0h + u * 32);
            rb1[u] = ld_h8_sc1(pA1h + u * 32);
        }

        #pragma unroll 8
        for (int c = 0; c < 40; c++) {
            int u = c & 7;
            h8 a0 = rb0[u], a1 = rb1[u];
            int cn = c + 8;
            if (cn < 32) {               // h chunks: coherent
                rb0[u] = ld_h8_sc1(pA0h + cn * 32);
                rb1[u] = ld_h8_sc1(pA1h + cn * 32);
            } else if (cn < 40) {        // x chunks: normal cached (read-only)
                rb0[u] = *(const h8*)(pA0x + (cn - 32) * 32);
                rb1[u] = *(const h8*)(pA1x + (cn - 32) * 32);
            }
            const _Float16* bb = &Bs[(size_t)(c * 48) * 40];
            h8 bf0 = *(const h8*)&bb[l15 * 40 + quad * 8];
            h8 bf1 = *(const h8*)&bb[(16 + l15) * 40 + quad * 8];
            h8 bf2 = *(const h8*)&bb[(32 + l15) * 40 + quad * 8];
            aR[0] = __builtin_amdgcn_mfma_f32_16x16x32_f16(a0, bf0, aR[0], 0, 0, 0);
            aR[1] = __builtin_amdgcn_mfma_f32_16x16x32_f16(a1, bf0, aR[1], 0, 0, 0);
            aZ[0] = __builtin_amdgcn_mfma_f32_16x16x32_f16(a0, bf1, aZ[0], 0, 0, 0);
            aZ[1] = __builtin_amdgcn_mfma_f32_16x16x32_f16(a1, bf1, aZ[1], 0, 0, 0);
            if (c < 32) {
                aNH[0] = __builtin_amdgcn_mfma_f32_16x16x32_f16(a0, bf2, aNH[0], 0, 0, 0);
                aNH[1] = __builtin_amdgcn_mfma_f32_16x16x32_f16(a1, bf2, aNH[1], 0, 0, 0);
            } else {
                aNX[0] = __builtin_amdgcn_mfma_f32_16x16x32_f16(a0, bf2, aNX[0], 0, 0, 0);
                aNX[1] = __builtin_amdgcn_mfma_f32_16x16x32_f16(a1, bf2, aNX[1], 0, 0, 0);
            }
        }

        // ---- gate epilogue: C/D mapping col=lane&15, row=quad*4+reg ----
        #pragma unroll
        for (int mi = 0; mi < 2; mi++) {
            #pragma unroll
            for (int p = 0; p < 4; p++) {
                int row = wi * 32 + mi * 16 + quad * 4 + p;
                float r = sigf(aR[mi][p] + br);
                float z = sigf(aZ[mi][p] + bz);
                float n = tanhf(aNX[mi][p] + bni + r * (aNH[mi][p] + bnh));
                float hv = (1.f - z) * n + z * hreg[mi][p];
                hreg[mi][p] = hv;
                hout[(size_t)row * HH + j] = (_Float16)hv;
                if (row < NST)
                    seq[(((size_t)w * NST + row) * TT + t) * HH + j] = (_Float16)hv;
            }
        }
        // ---- flag barrier (64 blocks of this week); release store publishes h
        // (wbl2 before flag). Readers use sc1 loads -> NO acquire fence needed. ----
        if (t < TT - 1) {
            __syncthreads();   // all waves' stores issued & drained
            if (tid == 0)
                __hip_atomic_store(&fw[blockIdx.x * 16], (unsigned)(t + 1),
                                   __ATOMIC_RELEASE, __HIP_MEMORY_SCOPE_AGENT);
            if (tid < 64) spin_wait(&fw[tid * 16], (unsigned)t);
            __syncthreads();
        }
    }
}

// ---------------- encoder time-attention (fp16 seq, wT pre-transposed) ----------------
__global__ __launch_bounds__(256) void att1_k(
    const _Float16* __restrict__ seq, const float* __restrict__ wT,
    const float* __restrict__ attb, float* __restrict__ wex)
{
    int d0 = blockIdx.x * 128;
    int n  = blockIdx.y;
    int w  = blockIdx.z;
    __shared__ _Float16 S[128][128];  // [t][d]
    __shared__ float PM[16][136];
    int tid = threadIdx.x;
    const _Float16* sp = seq + ((size_t)(w * NST + n) * TT) * HH + d0;
    for (int q = tid; q < 2048; q += 256) {
        int t = q >> 4, seg = q & 15;
        *(h8*)&S[t][seg * 8] = *(const h8*)(sp + (size_t)t * HH + seg * 8);
    }
    __syncthreads();
    int tx = tid & 15, ty = tid >> 4;
    const float* Wg = wT + (size_t)w * TT * TT;   // [t][tp]
    float acc[8][8];
    #pragma unroll
    for (int i = 0; i < 8; i++) {
        float b = attb[w * TT + ty * 8 + i];
        for (int j = 0; j < 8; j++) acc[i][j] = b;
    }
    for (int t = 0; t < 128; t++) {
        float wv[8], sv[8];
        float4 wa = *(const float4*)&Wg[(size_t)t * TT + ty * 8];
        float4 wb = *(const float4*)&Wg[(size_t)t * TT + ty * 8 + 4];
        wv[0] = wa.x; wv[1] = wa.y; wv[2] = wa.z; wv[3] = wa.w;
        wv[4] = wb.x; wv[5] = wb.y; wv[6] = wb.z; wv[7] = wb.w;
        h8 s8 = *(const h8*)&S[t][tx * 8];
        #pragma unroll
        for (int j = 0; j < 8; j++) sv[j] = (float)s8[j];
        #pragma unroll
        for (int i = 0; i < 8; i++)
            #pragma unroll
            for (int j = 0; j < 8; j++) acc[i][j] += wv[i] * sv[j];
    }
    float cmax[8], csum[8];
    #pragma unroll
    for (int j = 0; j < 8; j++) {
        float m = acc[0][j];
        for (int i = 1; i < 8; i++) m = fmaxf(m, acc[i][j]);
        PM[ty][tx * 8 + j] = m;
    }
    __syncthreads();
    #pragma unroll
    for (int j = 0; j < 8; j++) {
        float m = -1e30f;
        for (int yy = 0; yy < 16; yy++) m = fmaxf(m, PM[yy][tx * 8 + j]);
        cmax[j] = m;
    }
    __syncthreads();
    #pragma unroll
    for (int j = 0; j < 8; j++) {
        float s = 0.f;
        for (int i = 0; i < 8; i++) { acc[i][j] = expf(acc[i][j] - cmax[j]); s += acc[i][j]; }
        PM[ty][tx * 8 + j] = s;
    }
    __syncthreads();
    #pragma unroll
    for (int j = 0; j < 8; j++) {
        float s = 0.f;
        for (int yy = 0; yy < 16; yy++) s += PM[yy][tx * 8 + j];
        csum[j] = s;
    }
    __syncthreads();
    #pragma unroll
    for (int i = 0; i < 8; i++) {
        h8 s8 = *(const h8*)&S[ty * 8 + i][tx * 8];
        #pragma unroll
        for (int j = 0; j < 8; j++) {
            if (i == 0) PM[ty][tx * 8 + j] = 0.f;
            PM[ty][tx * 8 + j] += acc[i][j] * (float)s8[j];
        }
    }
    __syncthreads();
    if (ty == 0) {
        #pragma unroll
        for (int j = 0; j < 8; j++) {
            float o = 0.f;
            for (int yy = 0; yy < 16; yy++) o += PM[yy][tx * 8 + j];
            wex[((size_t)w * NST + n) * HH + d0 + tx * 8 + j] = o / csum[j];
        }
    }
}

// ---------------- generic fp32 GEMM: C[m][n] = sum_k A[m][k]*B[n][k] (+bias, relu) ----
template <int RELU>
__global__ __launch_bounds__(256) void gemm_tn_k(
    const float* __restrict__ A, const float* __restrict__ B,
    const float* __restrict__ bias, float* __restrict__ C, int M, int N, int K)
{
    int n0 = blockIdx.x * 64, m0 = blockIdx.y * 64;
    __shared__ float As[16][64], Bs[16][64];
    int tid = threadIdx.x, tx = tid & 15, ty = tid >> 4;
    float acc[4][4] = {{0.f}};
    for (int k0 = 0; k0 < K; k0 += 16) {
        __syncthreads();
        for (int q = tid; q < 1024; q += 256) {
            int kk = q & 15, r = q >> 4;
            int m = m0 + r, nn = n0 + r;
            As[kk][r] = (m < M) ? A[(size_t)m * K + k0 + kk] : 0.f;
            Bs[kk][r] = (nn < N) ? B[(size_t)nn * K + k0 + kk] : 0.f;
        }
        __syncthreads();
        #pragma unroll
        for (int kk = 0; kk < 16; kk++) {
            float4 av = *(const float4*)&As[kk][ty * 4];
            float4 bv = *(const float4*)&Bs[kk][tx * 4];
            float a[4] = {av.x, av.y, av.z, av.w};
            float b[4] = {bv.x, bv.y, bv.z, bv.w};
            #pragma unroll
            for (int r = 0; r < 4; r++)
                #pragma unroll
                for (int c = 0; c < 4; c++) acc[r][c] += a[r] * b[c];
        }
    }
    #pragma unroll
    for (int r = 0; r < 4; r++) {
        int m = m0 + ty * 4 + r;
        if (m >= M) continue;
        #pragma unroll
        for (int c = 0; c < 4; c++) {
            int nn = n0 + tx * 4 + c;
            if (nn >= N) continue;
            float v = acc[r][c] + (bias ? bias[nn] : 0.f);
            if (RELU) v = fmaxf(v, 0.f);
            C[(size_t)m * N + nn] = v;
        }
    }
}

// ---------------- fused weekly GRU: 100-step recurrence in ONE kernel,
// weights register-resident, sc1 h-exchange, no per-step fences ----------------
__global__ __launch_bounds__(256) void wk_fused_k(
    const float* __restrict__ gxw, const _Float16* __restrict__ wkW,
    const float* __restrict__ bhh, float* __restrict__ hA,
    float* __restrict__ hB, float* __restrict__ we2, unsigned* flags)
{
    int tid = threadIdx.x;
    int wi = tid >> 6, lane = tid & 63;
    int j = blockIdx.x * 4 + wi;
    int k0 = lane * 16;
    float wf[3][16];
    #pragma unroll
    for (int g = 0; g < 3; g++) {
        h8 wa = *(const h8*)&wkW[(size_t)(g * HH + j) * HH + k0];
        h8 wb = *(const h8*)&wkW[(size_t)(g * HH + j) * HH + k0 + 8];
        #pragma unroll
        for (int i = 0; i < 8; i++) { wf[g][i] = (float)wa[i]; wf[g][8 + i] = (float)wb[i]; }
    }
    float b0 = bhh[j], b1 = bhh[HH + j], b2 = bhh[2 * HH + j];

    for (int t = 0; t < NST; t++) {
        const float* hin = (t & 1) ? hB : hA;
        float* hout = (t & 1) ? hA : hB;
        float acc[4][3] = {};
        #pragma unroll
        for (int b = 0; b < 4; b++) {
            float hv[16];
            #pragma unroll
            for (int s = 0; s < 4; s++) {
                float4 hq = ld_f4_sc1(&hin[b * HH + k0 + s * 4]);
                hv[s * 4] = hq.x; hv[s * 4 + 1] = hq.y;
                hv[s * 4 + 2] = hq.z; hv[s * 4 + 3] = hq.w;
            }
            #pragma unroll
            for (int g = 0; g < 3; g++)
                #pragma unroll
                for (int i = 0; i < 16; i++) acc[b][g] += wf[g][i] * hv[i];
        }
        #pragma unroll
        for (int b = 0; b < 4; b++)
            #pragma unroll
            for (int g = 0; g < 3; g++)
                for (int o = 32; o; o >>= 1) acc[b][g] += __shfl_down(acc[b][g], o);
        if (lane == 0) {
            for (int b = 0; b < 4; b++) {
                const float* gx = gxw + ((size_t)b * NST + t) * H3;
                float hr = acc[b][0] + b0;
                float hz = acc[b][1] + b1;
                float hn = acc[b][2] + b2;
                float r = sigf(gx[j] + hr);
                float z = sigf(gx[HH + j] + hz);
                float n = tanhf(gx[2 * HH + j] + r * hn);
                float hv = (1.f - z) * n + z * ld_f_sc1(&hin[b * HH + j]);
                hout[b * HH + j] = hv;
                we2[((size_t)t * 4 + b) * HH + j] = hv;
            }
        }
        // ---- flag barrier across 256 blocks, no acquire fence ----
        if (t < NST - 1) {
            __syncthreads();
            if (tid == 0)
                __hip_atomic_store(&flags[blockIdx.x * 16], (unsigned)(t + 1),
                                   __ATOMIC_RELEASE, __HIP_MEMORY_SCOPE_AGENT);
            spin_wait(&flags[tid * 16], (unsigned)t);
            __syncthreads();
        }
    }
}

// ---------------- weekly attention (T=4) ----------------
__global__ void wkatt_k(const float* __restrict__ we2, const float* __restrict__ W,
                        const float* __restrict__ bv, float* __restrict__ wav)
{
    int n = blockIdx.x;
    for (int d = threadIdx.x; d < HH; d += 256) {
        float v[4], l[4];
        #pragma unroll
        for (int tp = 0; tp < 4; tp++) v[tp] = we2[((size_t)n * 4 + tp) * HH + d];
        float mx = -1e30f;
        #pragma unroll
        for (int tp = 0; tp < 4; tp++) {
            float s = bv[tp];
            for (int t2 = 0; t2 < 4; t2++) s += v[t2] * W[tp * 4 + t2];
            l[tp] = s; mx = fmaxf(mx, s);
        }
        float se = 0.f, o = 0.f;
        #pragma unroll
        for (int tp = 0; tp < 4; tp++) {
            float e = expf(l[tp] - mx);
            se += e; o += e * v[tp];
        }
        wav[(size_t)n * HH + d] = o / se;
    }
}

// ---------------- pool attention (C=5, T=20) ----------------
__global__ void poolatt_k(const float* __restrict__ wav, const float* __restrict__ W,
                          const float* __restrict__ bv, float* __restrict__ cat1)
{
    int c = blockIdx.x;
    for (int d = threadIdx.x; d < HH; d += 256) {
        float v[20], l[20];
        for (int t2 = 0; t2 < 20; t2++) v[t2] = wav[((size_t)c * 20 + t2) * HH + d];
        float mx = -1e30f;
        for (int tp = 0; tp < 20; tp++) {
            float s = bv[tp];
            for (int t2 = 0; t2 < 20; t2++) s += v[t2] * W[tp * 20 + t2];
            l[tp] = s; mx = fmaxf(mx, s);
        }
        float se = 0.f, o = 0.f;
        for (int tp = 0; tp < 20; tp++) {
            float e = expf(l[tp] - mx);
            se += e; o += e * v[tp];
        }
        cat1[(size_t)c * HH + d] = o / se;
    }
}

// ---------------- GAT: per-node alpha dots ----------------
__global__ void gat_dots_k(const float* __restrict__ h, const float* __restrict__ as_,
                           const float* __restrict__ ad_, float* __restrict__ ss,
                           float* __restrict__ sd)
{
    int i = blockIdx.x, tid = threadIdx.x;
    float s1 = 0.f, s2 = 0.f;
    for (int k = tid; k < HH; k += 256) {
        float v = h[(size_t)i * HH + k];
        s1 += v * as_[k]; s2 += v * ad_[k];
    }
    __shared__ float r1[256], r2[256];
    r1[tid] = s1; r2[tid] = s2; __syncthreads();
    for (int s = 128; s; s >>= 1) {
        if (tid < s) { r1[tid] += r1[tid + s]; r2[tid] += r2[tid + s]; }
        __syncthreads();
    }
    if (tid == 0) { ss[i] = r1[0]; sd[i] = r2[0]; }
}

// ---------------- GAT aggregate: block per dst node ----------------
#define MAXE 256
__global__ __launch_bounds__(256) void gat_agg_k(
    const float* __restrict__ hmat, const int* __restrict__ esrc,
    const int* __restrict__ edst, int nedges, const float* __restrict__ ss,
    const float* __restrict__ sd, const float* __restrict__ bias, float* __restrict__ outp)
{
    int i = blockIdx.x, tid = threadIdx.x;
    __shared__ int cnt;
    __shared__ int msrc[MAXE];
    __shared__ float mw[MAXE];
    __shared__ float inv_s;
    if (tid == 0) {
        cnt = 1; msrc[0] = i;
        float e = ss[i] + sd[i];
        mw[0] = e > 0.f ? e : 0.2f * e;
    }
    __syncthreads();
    for (int e = tid; e < nedges; e += 256) {
        if (edst[e] == i) {
            int p = atomicAdd(&cnt, 1);
            if (p < MAXE) {
                int s = esrc[e];
                msrc[p] = s;
                float v = ss[s] + sd[i];
                mw[p] = v > 0.f ? v : 0.2f * v;
            }
        }
    }
    __syncthreads();
    int m = min(cnt, MAXE);
    if (tid == 0) {
        float mx = -1e30f;
        for (int p = 0; p < m; p++) mx = fmaxf(mx, mw[p]);
        float s = 0.f;
        for (int p = 0; p < m; p++) { float e = expf(mw[p] - mx); mw[p] = e; s += e; }
        inv_s = 1.0f / s;
    }
    __syncthreads();
    for (int d = tid; d < HH; d += 256) {
        float a = 0.f;
        for (int p = 0; p < m; p++) a += mw[p] * hmat[(size_t)msrc[p] * HH + d];
        outp[(size_t)i * HH + d] = a * inv_s + bias[d];
    }
}

// ---------------- concat [wav3, cat, inner] ----------------
__global__ void concat_k(const float* __restrict__ wav, const float* __restrict__ gc,
                         const float* __restrict__ gi, float* __restrict__ cc)
{
    int row = blockIdx.x;
    int c = row / 20;
    for (int k = threadIdx.x; k < H3; k += 256) {
        float v;
        if (k < HH) v = wav[(size_t)row * HH + k];
        else if (k < 2 * HH) v = gc[(size_t)c * HH + (k - HH)];
        else v = gi[(size_t)row * HH + (k - 2 * HH)];
        cc[(size_t)row * H3 + k] = v;
    }
}

// ---------------- reg/cls heads ----------------
__global__ void heads_k(const float* __restrict__ f, const float* __restrict__ regW,
                        const float* __restrict__ regb, const float* __restrict__ clsW,
                        const float* __restrict__ clsb, float* __restrict__ outp)
{
    int i = blockIdx.x, tid = threadIdx.x;
    float s1 = 0.f, s2 = 0.f;
    for (int k = tid; k < HH; k += 256) {
        float v = f[(size_t)i * HH + k];
        s1 += v * regW[k]; s2 += v * clsW[k];
    }
    __shared__ float r1[256], r2[256];
    r1[tid] = s1; r2[tid] = s2; __syncthreads();
    for (int s = 128; s; s >>= 1) {
        if (tid < s) { r1[tid] += r1[tid + s]; r2[tid] += r2[tid + s]; }
        __syncthreads();
    }
    if (tid == 0) {
        outp[i] = r1[0] + regb[0];
        outp[100 + i] = sigf(r2[0] + clsb[0]);
    }
}

extern "C" void kernel_launch(void* const* d_in, const int* in_sizes, int n_in,
                              void* d_out, int out_size, void* d_ws, size_t ws_size,
                              hipStream_t stream)
{
    (void)in_sizes; (void)n_in; (void)out_size; (void)ws_size;
    const float* x0 = (const float*)d_in[0];
    const float* x1 = (const float*)d_in[1];
    const float* x2 = (const float*)d_in[2];
    const float* x3 = (const float*)d_in[3];
    const int*   ie = (const int*)d_in[4];
    const int*   oe = (const int*)d_in[5];
    const float* enc_Wih = (const float*)d_in[6];
    const float* enc_Whh = (const float*)d_in[7];
    const float* enc_bih = (const float*)d_in[8];
    const float* enc_bhh = (const float*)d_in[9];
    const float* enc_attW = (const float*)d_in[10];
    const float* enc_attb = (const float*)d_in[11];
    const float* wk_Wih = (const float*)d_in[12];
    const float* wk_Whh = (const float*)d_in[13];
    const float* wk_bih = (const float*)d_in[14];
    const float* wk_bhh = (const float*)d_in[15];
    const float* wkatt_W = (const float*)d_in[16];
    const float* wkatt_b = (const float*)d_in[17];
    const float* pool_W = (const float*)d_in[18];
    const float* pool_b = (const float*)d_in[19];
    const float* ig_W = (const float*)d_in[20];
    const float* ig_as = (const float*)d_in[21];
    const float* ig_ad = (const float*)d_in[22];
    const float* ig_b = (const float*)d_in[23];
    const float* cg_W = (const float*)d_in[24];
    const float* cg_as = (const float*)d_in[25];
    const float* cg_ad = (const float*)d_in[26];
    const float* cg_b = (const float*)d_in[27];
    const float* fus_W = (const float*)d_in[28];
    const float* fus_b = (const float*)d_in[29];
    const float* reg_W = (const float*)d_in[30];
    const float* reg_b = (const float*)d_in[31];
    const float* cls_W = (const float*)d_in[32];
    const float* cls_b = (const float*)d_in[33];
    float* outp = (float*)d_out;

    // workspace carve-up
    char* p = (char*)d_ws;
    auto alloc = [&](size_t bytes) { char* r = p; p += (bytes + 255) & ~(size_t)255; return (void*)r; };
    unsigned* flags = (unsigned*)alloc(2 * 256 * 16 * 4);  // [0..255]=enc (4w x 64), [256..511]=wk
    _Float16* Wcat = (_Float16*)alloc((size_t)NW * H3 * 1280 * 2);
    float* bc = (float*)alloc((size_t)NW * 4 * HH * 4);
    _Float16* wkW = (_Float16*)alloc((size_t)H3 * HH * 2);
    _Float16* xT = (_Float16*)alloc((size_t)NW * TT * 128 * II * 2);
    float* wT = (float*)alloc((size_t)NW * TT * TT * 4);
    _Float16* hhA = (_Float16*)alloc((size_t)NW * 128 * HH * 2);
    _Float16* hhB = (_Float16*)alloc((size_t)NW * 128 * HH * 2);
    _Float16* seq = (_Float16*)alloc((size_t)NW * NST * TT * HH * 2);
    float* wex = (float*)alloc((size_t)NW * NST * HH * 4);
    float* gxw = (float*)alloc((size_t)NW * NST * H3 * 4);
    float* hwA = (float*)alloc(4 * HH * 4);
    float* hwB = (float*)alloc(4 * HH * 4);
    float* we2 = (float*)alloc((size_t)NST * 4 * HH * 4);
    float* wav = (float*)alloc((size_t)NST * HH * 4);
    float* hi  = (float*)alloc((size_t)NST * HH * 4);
    float* si_s = (float*)alloc(128 * 4);
    float* si_d = (float*)alloc(128 * 4);
    float* gi  = (float*)alloc((size_t)NST * HH * 4);
    float* cat1 = (float*)alloc(5 * HH * 4);
    float* hc  = (float*)alloc(5 * HH * 4);
    float* sc_s = (float*)alloc(64 * 4);
    float* sc_d = (float*)alloc(64 * 4);
    float* gc  = (float*)alloc(5 * HH * 4);
    float* cc  = (float*)alloc((size_t)NST * H3 * 4);
    float* fbuf = (float*)alloc((size_t)NST * HH * 4);

    // allow >64KB dynamic LDS for the fused encoder (once)
    static bool attr_done = false;
    if (!attr_done) {
        hipFuncSetAttribute((const void*)enc_fused_k,
                            hipFuncAttributeMaxDynamicSharedMemorySize, ENC_LDS_BYTES);
        attr_done = true;
    }

    // one-time conversions + zero-init (flag state re-zeroed every replay)
    zero_k<<<32, 256, 0, stream>>>((float*)flags, 2 * 256 * 16);
    convW_k<<<dim3(5, H3, NW), 256, 0, stream>>>(enc_Whh, enc_Wih, Wcat);
    convB_k<<<dim3(4, NW), 256, 0, stream>>>(enc_bih, enc_bhh, bc);
    convWk_k<<<dim3(4, H3), 256, 0, stream>>>(wk_Whh, wkW);
    xcvt_k<<<8192, 256, 0, stream>>>(x0, x1, x2, x3, xT);
    wTcvt_k<<<dim3(TT, NW), 128, 0, stream>>>(enc_attW, wT);
    zero_k<<<(NW * 128 * HH / 2 + 255) / 256, 256, 0, stream>>>((float*)hhA, NW * 128 * HH / 2);
    zero_k<<<(4 * HH + 255) / 256, 256, 0, stream>>>(hwA, 4 * HH);

    // 4-week encoder GRU: single kernel, 128 internal steps, sc1-coherent h exchange
    enc_fused_k<<<dim3(64, NW), 256, ENC_LDS_BYTES, stream>>>(
        Wcat, bc, xT, hhA, hhB, seq, flags);

    // per-week time attention -> wex[w][n][d]
    att1_k<<<dim3(8, NST, NW), 256, 0, stream>>>(seq, wT, enc_attb, wex);

    // weekly GRU input projection (bias folded in)
    gemm_tn_k<0><<<dim3(48, 7), 256, 0, stream>>>(wex, wk_Wih, wk_bih, gxw, 400, H3, HH);

    // weekly GRU recurrence: single kernel, 100 internal steps
    wk_fused_k<<<256, 256, 0, stream>>>(gxw, wkW, wk_bhh, hwA, hwB, we2, flags + 256 * 16);

    // weekly attention -> wav (100,1024)
    wkatt_k<<<NST, 256, 0, stream>>>(we2, wkatt_W, wkatt_b, wav);

    // inner GAT
    gemm_tn_k<0><<<dim3(16, 2), 256, 0, stream>>>(wav, ig_W, nullptr, hi, NST, HH, HH);
    gat_dots_k<<<NST, 256, 0, stream>>>(hi, ig_as, ig_ad, si_s, si_d);
    gat_agg_k<<<NST, 256, 0, stream>>>(hi, ie, ie + 2000, 2000, si_s, si_d, ig_b, gi);

    // category pooling attention + outer GAT
    poolatt_k<<<5, 256, 0, stream>>>(wav, pool_W, pool_b, cat1);
    gemm_tn_k<0><<<dim3(16, 1), 256, 0, stream>>>(cat1, cg_W, nullptr, hc, 5, HH, HH);
    gat_dots_k<<<5, 256, 0, stream>>>(hc, cg_as, cg_ad, sc_s, sc_d);
    gat_agg_k<<<5, 256, 0, stream>>>(hc, oe, oe + 25, 25, sc_s, sc_d, cg_b, gc);

    // fusion + heads
    concat_k<<<NST, 256, 0, stream>>>(wav, gc, gi, cc);
    gemm_tn_k<1><<<dim3(16, 2), 256, 0, stream>>>(cc, fus_W, fus_b, fbuf, NST, HH, H3);
    heads_k<<<NST, 256, 0, stream>>>(fbuf, reg_W, reg_b, cls_W, cls_b, outp);
}

// Round 6
// 5226.543 us; speedup vs baseline: 2.0324x; 1.2692x over previous
//
#include <hip/hip_runtime.h>
#include <hip/hip_bf16.h>

#define NW 4
#define NST 100
#define TT 128
#define II 256
#define HH 1024
#define H3 3072

typedef _Float16 h8 __attribute__((ext_vector_type(8)));
typedef float f4 __attribute__((ext_vector_type(4)));

__device__ __forceinline__ float sigf(float x) { return 1.0f / (1.0f + expf(-x)); }

// ---- coherent (L3-direct, sc1) loads for the small weekly-GRU h exchange ----
__device__ __forceinline__ float4 ld_f4_sc1(const float* p) {
    union { unsigned long long u[2]; float4 v; } r;
    r.u[0] = __hip_atomic_load((unsigned long long*)p, __ATOMIC_RELAXED, __HIP_MEMORY_SCOPE_AGENT);
    r.u[1] = __hip_atomic_load((unsigned long long*)p + 1, __ATOMIC_RELAXED, __HIP_MEMORY_SCOPE_AGENT);
    return r.v;
}
__device__ __forceinline__ float ld_f_sc1(const float* p) {
    return __hip_atomic_load((float*)p, __ATOMIC_RELAXED, __HIP_MEMORY_SCOPE_AGENT);
}

// ---- bounded spin: never hang the queue; a sync failure becomes a clean mismatch ----
__device__ __forceinline__ void spin_wait(unsigned* f, unsigned t) {
    int guard = 0;
    while (__hip_atomic_load(f, __ATOMIC_RELAXED, __HIP_MEMORY_SCOPE_AGENT) <= t) {
        __builtin_amdgcn_s_sleep(2);
        if (++guard > (1 << 20)) break;
    }
}

// ---------------- zero init ----------------
__global__ void zero_k(float* a, int n) {
    int i = blockIdx.x * 256 + threadIdx.x;
    if (i < n) a[i] = 0.0f;
}

// ---------------- weight concat + fp16 convert: Wc[w][3072][1280] = [Whh | Wih] ----
__global__ void convW_k(const float* __restrict__ Whh, const float* __restrict__ Wih,
                        _Float16* __restrict__ Wc) {
    int col = blockIdx.x * 256 + threadIdx.x;  // 0..1279
    int r = blockIdx.y;                        // 0..3071
    int w = blockIdx.z;
    float v = (col < HH) ? Whh[((size_t)w * H3 + r) * HH + col]
                         : Wih[((size_t)w * H3 + r) * II + (col - HH)];
    Wc[((size_t)w * H3 + r) * 1280 + col] = (_Float16)v;
}

// ---------------- weekly weights fp16 ----------------
__global__ void convWk_k(const float* __restrict__ src, _Float16* __restrict__ dst) {
    int col = blockIdx.x * 256 + threadIdx.x;  // 0..1023
    int r = blockIdx.y;                        // 0..3071
    dst[(size_t)r * HH + col] = (_Float16)src[(size_t)r * HH + col];
}

// ---------------- x -> fp16 padded transpose: xT[w][t][128][256] ----------------
__global__ void xcvt_k(const float* __restrict__ x0, const float* __restrict__ x1,
                       const float* __restrict__ x2, const float* __restrict__ x3,
                       _Float16* __restrict__ xT) {
    int idx = blockIdx.x * 256 + threadIdx.x;   // 2^21 total
    int k8 = idx & 31;
    int m  = (idx >> 5) & 127;
    int t  = (idx >> 12) & 127;
    int w  = idx >> 19;
    const float* xw = (w == 0) ? x0 : (w == 1) ? x1 : (w == 2) ? x2 : x3;
    h8 hv = {};
    if (m < NST) {
        const float* s = xw + ((size_t)m * TT + t) * II + k8 * 8;
        float4 fa = *(const float4*)s;
        float4 fb = *(const float4*)(s + 4);
        hv[0] = (_Float16)fa.x; hv[1] = (_Float16)fa.y;
        hv[2] = (_Float16)fa.z; hv[3] = (_Float16)fa.w;
        hv[4] = (_Float16)fb.x; hv[5] = (_Float16)fb.y;
        hv[6] = (_Float16)fb.z; hv[7] = (_Float16)fb.w;
    }
    *(h8*)&xT[(((size_t)w * TT + t) * 128 + m) * II + k8 * 8] = hv;
}

// ---------------- attW transpose: wT[w][t][tp] = attW[w][tp][t] ----------------
__global__ void wTcvt_k(const float* __restrict__ attW, float* __restrict__ wT) {
    int tp = threadIdx.x;        // 0..127
    int t  = blockIdx.x;         // 0..127
    int w  = blockIdx.y;
    wT[((size_t)w * TT + t) * TT + tp] = attW[((size_t)w * TT + tp) * TT + t];
}

// ---------------- combined bias precompute: bc[w][{r,z,ni,nh}][1024] fp32 ----
__global__ void convB_k(const float* __restrict__ bih, const float* __restrict__ bhh,
                        float* __restrict__ bc) {
    int j = blockIdx.x * 256 + threadIdx.x;
    int w = blockIdx.y;
    const float* bi = bih + w * H3;
    const float* bh = bhh + w * H3;
    float* o = bc + w * 4096;
    o[j] = bi[j] + bh[j];
    o[1024 + j] = bi[1024 + j] + bh[1024 + j];
    o[2048 + j] = bi[2048 + j];
    o[3072 + j] = bh[2048 + j];
}

// ---------------- fused encoder GRU: entire 128-step recurrence in ONE kernel.
// Weights in LDS; fp32 h master in registers; h/seq published via PACKED 4B
// write-through sc1 stores (no dirty L2 -> flag store can be RELAXED, no wbl2);
// h read via NORMAL CACHED loads (L2 dedups the all-to-all) preceded by a single
// acquire-only fence (buffer_inv) per step; week confined to one XCD pair. ------
#define ENC_LDS_HALFS (40 * 48 * 40)
#define ENC_LDS_BYTES (ENC_LDS_HALFS * 2)

__global__ __launch_bounds__(256) void enc_fused_k(
    const _Float16* __restrict__ Wc, const float* __restrict__ bc,
    const _Float16* __restrict__ xT,
    _Float16* __restrict__ hhA, _Float16* __restrict__ hhB,
    _Float16* __restrict__ seq, unsigned* flags)
{
    extern __shared__ _Float16 Bs[];   // [40 chunks][48 rows][40 halfs] stride-40 pad

    // XCD-confinement swizzle: round-robin dispatch puts linear id%8 on XCD id%8.
    // week w = (id&7)>>1  ->  week w's 64 blocks land on XCD pair {2w, 2w+1}.
    int id = blockIdx.x;
    int rr = id & 7, qq = id >> 3;
    int w  = rr >> 1;
    int bx = qq * 2 + (rr & 1);        // 0..63 within week
    int j0 = bx * 16;

    const _Float16* Wcw = Wc + (size_t)w * H3 * 1280;
    const float* bcw = bc + w * 4096;
    _Float16* hA = hhA + (size_t)w * 128 * HH;
    _Float16* hB = hhB + (size_t)w * 128 * HH;
    unsigned* fw = flags + (size_t)w * 64 * 16;   // per-week flag group, 64B stride

    int tid = threadIdx.x;
    int lane = tid & 63, wi = tid >> 6, quad = lane >> 4, l15 = lane & 15;

    // one-time weight staging: 192 threads, 16B each, 40 chunks
    if (tid < 192) {
        int brow = tid >> 2, bseg = tid & 3;
        const _Float16* bsrc =
            Wcw + (size_t)((brow >> 4) * 1024 + j0 + (brow & 15)) * 1280 + bseg * 8;
        #pragma unroll 8
        for (int c = 0; c < 40; c++) {
            uint4 v = *(const uint4*)(bsrc + c * 32);
            *(uint4*)&Bs[((size_t)c * 48 + brow) * 40 + bseg * 8] = v;
        }
    }
    __syncthreads();

    int j = j0 + l15;
    float br = bcw[j], bz = bcw[1024 + j], bni = bcw[2048 + j], bnh = bcw[3072 + j];
    int r0 = wi * 32 + l15, r1 = wi * 32 + 16 + l15;
    float hreg[2][4] = {};   // fp32 h master, block-private -> registers

    for (int t = 0; t < TT; t++) {
        const _Float16* hin = (t & 1) ? hB : hA;
        _Float16* hout = (t & 1) ? hA : hB;
        const _Float16* xt = xT + ((size_t)w * TT + t) * 128 * II;
        const _Float16* pA0h = hin + (size_t)r0 * HH + quad * 8;
        const _Float16* pA1h = hin + (size_t)r1 * HH + quad * 8;
        const _Float16* pA0x = xt + (size_t)r0 * II + quad * 8;
        const _Float16* pA1x = xt + (size_t)r1 * II + quad * 8;

        f4 aR[2] = {}, aZ[2] = {}, aNH[2] = {}, aNX[2] = {};

        // 8-deep prefetch ring (normal cached loads; post-inv misses overlap)
        h8 rb0[8], rb1[8];
        #pragma unroll
        for (int u = 0; u < 8; u++) {
            rb0[u] = *(const h8*)(pA0h + u * 32);
            rb1[u] = *(const h8*)(pA1h + u * 32);
        }

        #pragma unroll 8
        for (int c = 0; c < 40; c++) {
            int u = c & 7;
            h8 a0 = rb0[u], a1 = rb1[u];
            int cn = c + 8;
            if (cn < 32) {               // h chunks
                rb0[u] = *(const h8*)(pA0h + cn * 32);
                rb1[u] = *(const h8*)(pA1h + cn * 32);
            } else if (cn < 40) {        // x chunks
                rb0[u] = *(const h8*)(pA0x + (cn - 32) * 32);
                rb1[u] = *(const h8*)(pA1x + (cn - 32) * 32);
            }
            const _Float16* bb = &Bs[(size_t)(c * 48) * 40];
            h8 bf0 = *(const h8*)&bb[l15 * 40 + quad * 8];
            h8 bf1 = *(const h8*)&bb[(16 + l15) * 40 + quad * 8];
            h8 bf2 = *(const h8*)&bb[(32 + l15) * 40 + quad * 8];
            aR[0] = __builtin_amdgcn_mfma_f32_16x16x32_f16(a0, bf0, aR[0], 0, 0, 0);
            aR[1] = __builtin_amdgcn_mfma_f32_16x16x32_f16(a1, bf0, aR[1], 0, 0, 0);
            aZ[0] = __builtin_amdgcn_mfma_f32_16x16x32_f16(a0, bf1, aZ[0], 0, 0, 0);
            aZ[1] = __builtin_amdgcn_mfma_f32_16x16x32_f16(a1, bf1, aZ[1], 0, 0, 0);
            if (c < 32) {
                aNH[0] = __builtin_amdgcn_mfma_f32_16x16x32_f16(a0, bf2, aNH[0], 0, 0, 0);
                aNH[1] = __builtin_amdgcn_mfma_f32_16x16x32_f16(a1, bf2, aNH[1], 0, 0, 0);
            } else {
                aNX[0] = __builtin_amdgcn_mfma_f32_16x16x32_f16(a0, bf2, aNX[0], 0, 0, 0);
                aNX[1] = __builtin_amdgcn_mfma_f32_16x16x32_f16(a1, bf2, aNX[1], 0, 0, 0);
            }
        }

        // ---- gate epilogue: C/D mapping col=lane&15, row=quad*4+reg.
        // Pack cols (j, j+1) via shfl_xor -> 4B write-through sc1 stores. ----
        #pragma unroll
        for (int mi = 0; mi < 2; mi++) {
            #pragma unroll
            for (int p = 0; p < 4; p++) {
                int row = wi * 32 + mi * 16 + quad * 4 + p;
                float r = sigf(aR[mi][p] + br);
                float z = sigf(aZ[mi][p] + bz);
                float n = tanhf(aNX[mi][p] + bni + r * (aNH[mi][p] + bnh));
                float hv = (1.f - z) * n + z * hreg[mi][p];
                hreg[mi][p] = hv;
                unsigned short hb = __builtin_bit_cast(unsigned short, (_Float16)hv);
                unsigned ob = __shfl_xor((unsigned)hb, 1);
                unsigned pk = (unsigned)hb | (ob << 16);
                if (!(l15 & 1)) {   // even col stores the pair (4B aligned)
                    if (t < TT - 1)
                        __hip_atomic_store((unsigned*)&hout[(size_t)row * HH + j], pk,
                                           __ATOMIC_RELAXED, __HIP_MEMORY_SCOPE_AGENT);
                    if (row < NST)
                        __hip_atomic_store(
                            (unsigned*)&seq[(((size_t)w * NST + row) * TT + t) * HH + j], pk,
                            __ATOMIC_RELAXED, __HIP_MEMORY_SCOPE_AGENT);
                }
            }
        }
        // ---- flag barrier (64 blocks of this week).  syncthreads drains vmcnt
        // (WT stores ACKed at coherence point) -> relaxed flag store suffices.
        // Acquire-only fence (buffer_inv, no wbl2) drops stale cached h lines. ----
        if (t < TT - 1) {
            __syncthreads();
            if (tid == 0)
                __hip_atomic_store(&fw[bx * 16], (unsigned)(t + 1),
                                   __ATOMIC_RELAXED, __HIP_MEMORY_SCOPE_AGENT);
            if (tid < 64) spin_wait(&fw[tid * 16], (unsigned)t);
            __syncthreads();
            __builtin_amdgcn_fence(__ATOMIC_ACQUIRE, "agent");
        }
    }
}

// ---------------- encoder time-attention (fp16 seq, wT pre-transposed) ----------------
__global__ __launch_bounds__(256) void att1_k(
    const _Float16* __restrict__ seq, const float* __restrict__ wT,
    const float* __restrict__ attb, float* __restrict__ wex)
{
    int d0 = blockIdx.x * 128;
    int n  = blockIdx.y;
    int w  = blockIdx.z;
    __shared__ _Float16 S[128][128];  // [t][d]
    __shared__ float PM[16][136];
    int tid = threadIdx.x;
    const _Float16* sp = seq + ((size_t)(w * NST + n) * TT) * HH + d0;
    for (int q = tid; q < 2048; q += 256) {
        int t = q >> 4, seg = q & 15;
        *(h8*)&S[t][seg * 8] = *(const h8*)(sp + (size_t)t * HH + seg * 8);
    }
    __syncthreads();
    int tx = tid & 15, ty = tid >> 4;
    const float* Wg = wT + (size_t)w * TT * TT;   // [t][tp]
    float acc[8][8];
    #pragma unroll
    for (int i = 0; i < 8; i++) {
        float b = attb[w * TT + ty * 8 + i];
        for (int j = 0; j < 8; j++) acc[i][j] = b;
    }
    for (int t = 0; t < 128; t++) {
        float wv[8], sv[8];
        float4 wa = *(const float4*)&Wg[(size_t)t * TT + ty * 8];
        float4 wb = *(const float4*)&Wg[(size_t)t * TT + ty * 8 + 4];
        wv[0] = wa.x; wv[1] = wa.y; wv[2] = wa.z; wv[3] = wa.w;
        wv[4] = wb.x; wv[5] = wb.y; wv[6] = wb.z; wv[7] = wb.w;
        h8 s8 = *(const h8*)&S[t][tx * 8];
        #pragma unroll
        for (int j = 0; j < 8; j++) sv[j] = (float)s8[j];
        #pragma unroll
        for (int i = 0; i < 8; i++)
            #pragma unroll
            for (int j = 0; j < 8; j++) acc[i][j] += wv[i] * sv[j];
    }
    float cmax[8], csum[8];
    #pragma unroll
    for (int j = 0; j < 8; j++) {
        float m = acc[0][j];
        for (int i = 1; i < 8; i++) m = fmaxf(m, acc[i][j]);
        PM[ty][tx * 8 + j] = m;
    }
    __syncthreads();
    #pragma unroll
    for (int j = 0; j < 8; j++) {
        float m = -1e30f;
        for (int yy = 0; yy < 16; yy++) m = fmaxf(m, PM[yy][tx * 8 + j]);
        cmax[j] = m;
    }
    __syncthreads();
    #pragma unroll
    for (int j = 0; j < 8; j++) {
        float s = 0.f;
        for (int i = 0; i < 8; i++) { acc[i][j] = expf(acc[i][j] - cmax[j]); s += acc[i][j]; }
        PM[ty][tx * 8 + j] = s;
    }
    __syncthreads();
    #pragma unroll
    for (int j = 0; j < 8; j++) {
        float s = 0.f;
        for (int yy = 0; yy < 16; yy++) s += PM[yy][tx * 8 + j];
        csum[j] = s;
    }
    __syncthreads();
    #pragma unroll
    for (int i = 0; i < 8; i++) {
        h8 s8 = *(const h8*)&S[ty * 8 + i][tx * 8];
        #pragma unroll
        for (int j = 0; j < 8; j++) {
            if (i == 0) PM[ty][tx * 8 + j] = 0.f;
            PM[ty][tx * 8 + j] += acc[i][j] * (float)s8[j];
        }
    }
    __syncthreads();
    if (ty == 0) {
        #pragma unroll
        for (int j = 0; j < 8; j++) {
            float o = 0.f;
            for (int yy = 0; yy < 16; yy++) o += PM[yy][tx * 8 + j];
            wex[((size_t)w * NST + n) * HH + d0 + tx * 8 + j] = o / csum[j];
        }
    }
}

// ---------------- generic fp32 GEMM: C[m][n] = sum_k A[m][k]*B[n][k] (+bias, relu) ----
template <int RELU>
__global__ __launch_bounds__(256) void gemm_tn_k(
    const float* __restrict__ A, const float* __restrict__ B,
    const float* __restrict__ bias, float* __restrict__ C, int M, int N, int K)
{
    int n0 = blockIdx.x * 64, m0 = blockIdx.y * 64;
    __shared__ float As[16][64], Bs[16][64];
    int tid = threadIdx.x, tx = tid & 15, ty = tid >> 4;
    float acc[4][4] = {{0.f}};
    for (int k0 = 0; k0 < K; k0 += 16) {
        __syncthreads();
        for (int q = tid; q < 1024; q += 256) {
            int kk = q & 15, r = q >> 4;
            int m = m0 + r, nn = n0 + r;
            As[kk][r] = (m < M) ? A[(size_t)m * K + k0 + kk] : 0.f;
            Bs[kk][r] = (nn < N) ? B[(size_t)nn * K + k0 + kk] : 0.f;
        }
        __syncthreads();
        #pragma unroll
        for (int kk = 0; kk < 16; kk++) {
            float4 av = *(const float4*)&As[kk][ty * 4];
            float4 bv = *(const float4*)&Bs[kk][tx * 4];
            float a[4] = {av.x, av.y, av.z, av.w};
            float b[4] = {bv.x, bv.y, bv.z, bv.w};
            #pragma unroll
            for (int r = 0; r < 4; r++)
                #pragma unroll
                for (int c = 0; c < 4; c++) acc[r][c] += a[r] * b[c];
        }
    }
    #pragma unroll
    for (int r = 0; r < 4; r++) {
        int m = m0 + ty * 4 + r;
        if (m >= M) continue;
        #pragma unroll
        for (int c = 0; c < 4; c++) {
            int nn = n0 + tx * 4 + c;
            if (nn >= N) continue;
            float v = acc[r][c] + (bias ? bias[nn] : 0.f);
            if (RELU) v = fmaxf(v, 0.f);
            C[(size_t)m * N + nn] = v;
        }
    }
}

// ---------------- fused weekly GRU: 100-step recurrence in ONE kernel.
// h stores write-through sc1, flag relaxed, reads sc1 -> ZERO cache-maintenance. --
__global__ __launch_bounds__(256) void wk_fused_k(
    const float* __restrict__ gxw, const _Float16* __restrict__ wkW,
    const float* __restrict__ bhh, float* __restrict__ hA,
    float* __restrict__ hB, float* __restrict__ we2, unsigned* flags)
{
    int tid = threadIdx.x;
    int wi = tid >> 6, lane = tid & 63;
    int j = blockIdx.x * 4 + wi;
    int k0 = lane * 16;
    float wf[3][16];
    #pragma unroll
    for (int g = 0; g < 3; g++) {
        h8 wa = *(const h8*)&wkW[(size_t)(g * HH + j) * HH + k0];
        h8 wb = *(const h8*)&wkW[(size_t)(g * HH + j) * HH + k0 + 8];
        #pragma unroll
        for (int i = 0; i < 8; i++) { wf[g][i] = (float)wa[i]; wf[g][8 + i] = (float)wb[i]; }
    }
    float b0 = bhh[j], b1 = bhh[HH + j], b2 = bhh[2 * HH + j];

    for (int t = 0; t < NST; t++) {
        const float* hin = (t & 1) ? hB : hA;
        float* hout = (t & 1) ? hA : hB;
        float acc[4][3] = {};
        #pragma unroll
        for (int b = 0; b < 4; b++) {
            float hv[16];
            #pragma unroll
            for (int s = 0; s < 4; s++) {
                float4 hq = ld_f4_sc1(&hin[b * HH + k0 + s * 4]);
                hv[s * 4] = hq.x; hv[s * 4 + 1] = hq.y;
                hv[s * 4 + 2] = hq.z; hv[s * 4 + 3] = hq.w;
            }
            #pragma unroll
            for (int g = 0; g < 3; g++)
                #pragma unroll
                for (int i = 0; i < 16; i++) acc[b][g] += wf[g][i] * hv[i];
        }
        #pragma unroll
        for (int b = 0; b < 4; b++)
            #pragma unroll
            for (int g = 0; g < 3; g++)
                for (int o = 32; o; o >>= 1) acc[b][g] += __shfl_down(acc[b][g], o);
        if (lane == 0) {
            for (int b = 0; b < 4; b++) {
                const float* gx = gxw + ((size_t)b * NST + t) * H3;
                float hr = acc[b][0] + b0;
                float hz = acc[b][1] + b1;
                float hn = acc[b][2] + b2;
                float r = sigf(gx[j] + hr);
                float z = sigf(gx[HH + j] + hz);
                float n = tanhf(gx[2 * HH + j] + r * hn);
                float hv = (1.f - z) * n + z * ld_f_sc1(&hin[b * HH + j]);
                __hip_atomic_store(&hout[b * HH + j], hv,
                                   __ATOMIC_RELAXED, __HIP_MEMORY_SCOPE_AGENT);
                we2[((size_t)t * 4 + b) * HH + j] = hv;
            }
        }
        // ---- flag barrier across 256 blocks: relaxed store (vmcnt anchor), no fences ----
        if (t < NST - 1) {
            __syncthreads();
            if (tid == 0)
                __hip_atomic_store(&flags[blockIdx.x * 16], (unsigned)(t + 1),
                                   __ATOMIC_RELAXED, __HIP_MEMORY_SCOPE_AGENT);
            spin_wait(&flags[tid * 16], (unsigned)t);
            __syncthreads();
        }
    }
}

// ---------------- weekly attention (T=4) ----------------
__global__ void wkatt_k(const float* __restrict__ we2, const float* __restrict__ W,
                        const float* __restrict__ bv, float* __restrict__ wav)
{
    int n = blockIdx.x;
    for (int d = threadIdx.x; d < HH; d += 256) {
        float v[4], l[4];
        #pragma unroll
        for (int tp = 0; tp < 4; tp++) v[tp] = we2[((size_t)n * 4 + tp) * HH + d];
        float mx = -1e30f;
        #pragma unroll
        for (int tp = 0; tp < 4; tp++) {
            float s = bv[tp];
            for (int t2 = 0; t2 < 4; t2++) s += v[t2] * W[tp * 4 + t2];
            l[tp] = s; mx = fmaxf(mx, s);
        }
        float se = 0.f, o = 0.f;
        #pragma unroll
        for (int tp = 0; tp < 4; tp++) {
            float e = expf(l[tp] - mx);
            se += e; o += e * v[tp];
        }
        wav[(size_t)n * HH + d] = o / se;
    }
}

// ---------------- pool attention (C=5, T=20) ----------------
__global__ void poolatt_k(const float* __restrict__ wav, const float* __restrict__ W,
                          const float* __restrict__ bv, float* __restrict__ cat1)
{
    int c = blockIdx.x;
    for (int d = threadIdx.x; d < HH; d += 256) {
        float v[20], l[20];
        for (int t2 = 0; t2 < 20; t2++) v[t2] = wav[((size_t)c * 20 + t2) * HH + d];
        float mx = -1e30f;
        for (int tp = 0; tp < 20; tp++) {
            float s = bv[tp];
            for (int t2 = 0; t2 < 20; t2++) s += v[t2] * W[tp * 20 + t2];
            l[tp] = s; mx = fmaxf(mx, s);
        }
        float se = 0.f, o = 0.f;
        for (int tp = 0; tp < 20; tp++) {
            float e = expf(l[tp] - mx);
            se += e; o += e * v[tp];
        }
        cat1[(size_t)c * HH + d] = o / se;
    }
}

// ---------------- GAT: per-node alpha dots ----------------
__global__ void gat_dots_k(const float* __restrict__ h, const float* __restrict__ as_,
                           const float* __restrict__ ad_, float* __restrict__ ss,
                           float* __restrict__ sd)
{
    int i = blockIdx.x, tid = threadIdx.x;
    float s1 = 0.f, s2 = 0.f;
    for (int k = tid; k < HH; k += 256) {
        float v = h[(size_t)i * HH + k];
        s1 += v * as_[k]; s2 += v * ad_[k];
    }
    __shared__ float r1[256], r2[256];
    r1[tid] = s1; r2[tid] = s2; __syncthreads();
    for (int s = 128; s; s >>= 1) {
        if (tid < s) { r1[tid] += r1[tid + s]; r2[tid] += r2[tid + s]; }
        __syncthreads();
    }
    if (tid == 0) { ss[i] = r1[0]; sd[i] = r2[0]; }
}

// ---------------- GAT aggregate: block per dst node ----------------
#define MAXE 256
__global__ __launch_bounds__(256) void gat_agg_k(
    const float* __restrict__ hmat, const int* __restrict__ esrc,
    const int* __restrict__ edst, int nedges, const float* __restrict__ ss,
    const float* __restrict__ sd, const float* __restrict__ bias, float* __restrict__ outp)
{
    int i = blockIdx.x, tid = threadIdx.x;
    __shared__ int cnt;
    __shared__ int msrc[MAXE];
    __shared__ float mw[MAXE];
    __shared__ float inv_s;
    if (tid == 0) {
        cnt = 1; msrc[0] = i;
        float e = ss[i] + sd[i];
        mw[0] = e > 0.f ? e : 0.2f * e;
    }
    __syncthreads();
    for (int e = tid; e < nedges; e += 256) {
        if (edst[e] == i) {
            int p = atomicAdd(&cnt, 1);
            if (p < MAXE) {
                int s = esrc[e];
                msrc[p] = s;
                float v = ss[s] + sd[i];
                mw[p] = v > 0.f ? v : 0.2f * v;
            }
        }
    }
    __syncthreads();
    int m = min(cnt, MAXE);
    if (tid == 0) {
        float mx = -1e30f;
        for (int p = 0; p < m; p++) mx = fmaxf(mx, mw[p]);
        float s = 0.f;
        for (int p = 0; p < m; p++) { float e = expf(mw[p] - mx); mw[p] = e; s += e; }
        inv_s = 1.0f / s;
    }
    __syncthreads();
    for (int d = tid; d < HH; d += 256) {
        float a = 0.f;
        for (int p = 0; p < m; p++) a += mw[p] * hmat[(size_t)msrc[p] * HH + d];
        outp[(size_t)i * HH + d] = a * inv_s + bias[d];
    }
}

// ---------------- concat [wav3, cat, inner] ----------------
__global__ void concat_k(const float* __restrict__ wav, const float* __restrict__ gc,
                         const float* __restrict__ gi, float* __restrict__ cc)
{
    int row = blockIdx.x;
    int c = row / 20;
    for (int k = threadIdx.x; k < H3; k += 256) {
        float v;
        if (k < HH) v = wav[(size_t)row * HH + k];
        else if (k < 2 * HH) v = gc[(size_t)c * HH + (k - HH)];
        else v = gi[(size_t)row * HH + (k - 2 * HH)];
        cc[(size_t)row * H3 + k] = v;
    }
}

// ---------------- reg/cls heads ----------------
__global__ void heads_k(const float* __restrict__ f, const float* __restrict__ regW,
                        const float* __restrict__ regb, const float* __restrict__ clsW,
                        const float* __restrict__ clsb, float* __restrict__ outp)
{
    int i = blockIdx.x, tid = threadIdx.x;
    float s1 = 0.f, s2 = 0.f;
    for (int k = tid; k < HH; k += 256) {
        float v = f[(size_t)i * HH + k];
        s1 += v * regW[k]; s2 += v * clsW[k];
    }
    __shared__ float r1[256], r2[256];
    r1[tid] = s1; r2[tid] = s2; __syncthreads();
    for (int s = 128; s; s >>= 1) {
        if (tid < s) { r1[tid] += r1[tid + s]; r2[tid] += r2[tid + s]; }
        __syncthreads();
    }
    if (tid == 0) {
        outp[i] = r1[0] + regb[0];
        outp[100 + i] = sigf(r2[0] + clsb[0]);
    }
}

extern "C" void kernel_launch(void* const* d_in, const int* in_sizes, int n_in,
                              void* d_out, int out_size, void* d_ws, size_t ws_size,
                              hipStream_t stream)
{
    (void)in_sizes; (void)n_in; (void)out_size; (void)ws_size;
    const float* x0 = (const float*)d_in[0];
    const float* x1 = (const float*)d_in[1];
    const float* x2 = (const float*)d_in[2];
    const float* x3 = (const float*)d_in[3];
    const int*   ie = (const int*)d_in[4];
    const int*   oe = (const int*)d_in[5];
    const float* enc_Wih = (const float*)d_in[6];
    const float* enc_Whh = (const float*)d_in[7];
    const float* enc_bih = (const float*)d_in[8];
    const float* enc_bhh = (const float*)d_in[9];
    const float* enc_attW = (const float*)d_in[10];
    const float* enc_attb = (const float*)d_in[11];
    const float* wk_Wih = (const float*)d_in[12];
    const float* wk_Whh = (const float*)d_in[13];
    const float* wk_bih = (const float*)d_in[14];
    const float* wk_bhh = (const float*)d_in[15];
    const float* wkatt_W = (const float*)d_in[16];
    const float* wkatt_b = (const float*)d_in[17];
    const float* pool_W = (const float*)d_in[18];
    const float* pool_b = (const float*)d_in[19];
    const float* ig_W = (const float*)d_in[20];
    const float* ig_as = (const float*)d_in[21];
    const float* ig_ad = (const float*)d_in[22];
    const float* ig_b = (const float*)d_in[23];
    const float* cg_W = (const float*)d_in[24];
    const float* cg_as = (const float*)d_in[25];
    const float* cg_ad = (const float*)d_in[26];
    const float* cg_b = (const float*)d_in[27];
    const float* fus_W = (const float*)d_in[28];
    const float* fus_b = (const float*)d_in[29];
    const float* reg_W = (const float*)d_in[30];
    const float* reg_b = (const float*)d_in[31];
    const float* cls_W = (const float*)d_in[32];
    const float* cls_b = (const float*)d_in[33];
    float* outp = (float*)d_out;

    // workspace carve-up
    char* p = (char*)d_ws;
    auto alloc = [&](size_t bytes) { char* r = p; p += (bytes + 255) & ~(size_t)255; return (void*)r; };
    unsigned* flags = (unsigned*)alloc(2 * 256 * 16 * 4);  // [0..255]=enc (4w x 64), [256..511]=wk
    _Float16* Wcat = (_Float16*)alloc((size_t)NW * H3 * 1280 * 2);
    float* bc = (float*)alloc((size_t)NW * 4 * HH * 4);
    _Float16* wkW = (_Float16*)alloc((size_t)H3 * HH * 2);
    _Float16* xT = (_Float16*)alloc((size_t)NW * TT * 128 * II * 2);
    float* wT = (float*)alloc((size_t)NW * TT * TT * 4);
    _Float16* hhA = (_Float16*)alloc((size_t)NW * 128 * HH * 2);
    _Float16* hhB = (_Float16*)alloc((size_t)NW * 128 * HH * 2);
    _Float16* seq = (_Float16*)alloc((size_t)NW * NST * TT * HH * 2);
    float* wex = (float*)alloc((size_t)NW * NST * HH * 4);
    float* gxw = (float*)alloc((size_t)NW * NST * H3 * 4);
    float* hwA = (float*)alloc(4 * HH * 4);
    float* hwB = (float*)alloc(4 * HH * 4);
    float* we2 = (float*)alloc((size_t)NST * 4 * HH * 4);
    float* wav = (float*)alloc((size_t)NST * HH * 4);
    float* hi  = (float*)alloc((size_t)NST * HH * 4);
    float* si_s = (float*)alloc(128 * 4);
    float* si_d = (float*)alloc(128 * 4);
    float* gi  = (float*)alloc((size_t)NST * HH * 4);
    float* cat1 = (float*)alloc(5 * HH * 4);
    float* hc  = (float*)alloc(5 * HH * 4);
    float* sc_s = (float*)alloc(64 * 4);
    float* sc_d = (float*)alloc(64 * 4);
    float* gc  = (float*)alloc(5 * HH * 4);
    float* cc  = (float*)alloc((size_t)NST * H3 * 4);
    float* fbuf = (float*)alloc((size_t)NST * HH * 4);

    // allow >64KB dynamic LDS for the fused encoder (once)
    static bool attr_done = false;
    if (!attr_done) {
        hipFuncSetAttribute((const void*)enc_fused_k,
                            hipFuncAttributeMaxDynamicSharedMemorySize, ENC_LDS_BYTES);
        attr_done = true;
    }

    // one-time conversions + zero-init (flag state re-zeroed every replay)
    zero_k<<<32, 256, 0, stream>>>((float*)flags, 2 * 256 * 16);
    convW_k<<<dim3(5, H3, NW), 256, 0, stream>>>(enc_Whh, enc_Wih, Wcat);
    convB_k<<<dim3(4, NW), 256, 0, stream>>>(enc_bih, enc_bhh, bc);
    convWk_k<<<dim3(4, H3), 256, 0, stream>>>(wk_Whh, wkW);
    xcvt_k<<<8192, 256, 0, stream>>>(x0, x1, x2, x3, xT);
    wTcvt_k<<<dim3(TT, NW), 128, 0, stream>>>(enc_attW, wT);
    zero_k<<<(NW * 128 * HH / 2 + 255) / 256, 256, 0, stream>>>((float*)hhA, NW * 128 * HH / 2);
    zero_k<<<(4 * HH + 255) / 256, 256, 0, stream>>>(hwA, 4 * HH);

    // 4-week encoder GRU: single kernel, 128 internal steps, XCD-confined weeks
    enc_fused_k<<<256, 256, ENC_LDS_BYTES, stream>>>(
        Wcat, bc, xT, hhA, hhB, seq, flags);

    // per-week time attention -> wex[w][n][d]
    att1_k<<<dim3(8, NST, NW), 256, 0, stream>>>(seq, wT, enc_attb, wex);

    // weekly GRU input projection (bias folded in)
    gemm_tn_k<0><<<dim3(48, 7), 256, 0, stream>>>(wex, wk_Wih, wk_bih, gxw, 400, H3, HH);

    // weekly GRU recurrence: single kernel, 100 internal steps
    wk_fused_k<<<256, 256, 0, stream>>>(gxw, wkW, wk_bhh, hwA, hwB, we2, flags + 256 * 16);

    // weekly attention -> wav (100,1024)
    wkatt_k<<<NST, 256, 0, stream>>>(we2, wkatt_W, wkatt_b, wav);

    // inner GAT
    gemm_tn_k<0><<<dim3(16, 2), 256, 0, stream>>>(wav, ig_W, nullptr, hi, NST, HH, HH);
    gat_dots_k<<<NST, 256, 0, stream>>>(hi, ig_as, ig_ad, si_s, si_d);
    gat_agg_k<<<NST, 256, 0, stream>>>(hi, ie, ie + 2000, 2000, si_s, si_d, ig_b, gi);

    // category pooling attention + outer GAT
    poolatt_k<<<5, 256, 0, stream>>>(wav, pool_W, pool_b, cat1);
    gemm_tn_k<0><<<dim3(16, 1), 256, 0, stream>>>(cat1, cg_W, nullptr, hc, 5, HH, HH);
    gat_dots_k<<<5, 256, 0, stream>>>(hc, cg_as, cg_ad, sc_s, sc_d);
    gat_agg_k<<<5, 256, 0, stream>>>(hc, oe, oe + 25, 25, sc_s, sc_d, cg_b, gc);

    // fusion + heads
    concat_k<<<NST, 256, 0, stream>>>(wav, gc, gi, cc);
    gemm_tn_k<1><<<dim3(16, 2), 256, 0, stream>>>(cc, fus_W, fus_b, fbuf, NST, HH, H3);
    heads_k<<<NST, 256, 0, stream>>>(fbuf, reg_W, reg_b, cls_W, cls_b, outp);
}

// Round 7
// 5142.465 us; speedup vs baseline: 2.0656x; 1.0163x over previous
//
#include <hip/hip_runtime.h>
#include <hip/hip_bf16.h>

#define NW 4
#define NST 100
#define TT 128
#define II 256
#define HH 1024
#define H3 3072

typedef _Float16 h8 __attribute__((ext_vector_type(8)));
typedef float f4 __attribute__((ext_vector_type(4)));

__device__ __forceinline__ float sigf(float x) { return 1.0f / (1.0f + expf(-x)); }

// ---- coherent (L3-direct, sc1) loads for the small weekly-GRU h exchange ----
__device__ __forceinline__ float4 ld_f4_sc1(const float* p) {
    union { unsigned long long u[2]; float4 v; } r;
    r.u[0] = __hip_atomic_load((unsigned long long*)p, __ATOMIC_RELAXED, __HIP_MEMORY_SCOPE_AGENT);
    r.u[1] = __hip_atomic_load((unsigned long long*)p + 1, __ATOMIC_RELAXED, __HIP_MEMORY_SCOPE_AGENT);
    return r.v;
}
__device__ __forceinline__ float ld_f_sc1(const float* p) {
    return __hip_atomic_load((float*)p, __ATOMIC_RELAXED, __HIP_MEMORY_SCOPE_AGENT);
}

// ---- bounded spin: never hang the queue; a sync failure becomes a clean mismatch ----
__device__ __forceinline__ void spin_wait(unsigned* f, unsigned t) {
    int guard = 0;
    while (__hip_atomic_load(f, __ATOMIC_RELAXED, __HIP_MEMORY_SCOPE_AGENT) <= t) {
        __builtin_amdgcn_s_sleep(1);
        if (++guard > (1 << 21)) break;
    }
}

// ---------------- zero init ----------------
__global__ void zero_k(float* a, int n) {
    int i = blockIdx.x * 256 + threadIdx.x;
    if (i < n) a[i] = 0.0f;
}

// ---------------- weight concat + fp16 convert: Wc[w][3072][1280] = [Whh | Wih] ----
__global__ void convW_k(const float* __restrict__ Whh, const float* __restrict__ Wih,
                        _Float16* __restrict__ Wc) {
    int col = blockIdx.x * 256 + threadIdx.x;  // 0..1279
    int r = blockIdx.y;                        // 0..3071
    int w = blockIdx.z;
    float v = (col < HH) ? Whh[((size_t)w * H3 + r) * HH + col]
                         : Wih[((size_t)w * H3 + r) * II + (col - HH)];
    Wc[((size_t)w * H3 + r) * 1280 + col] = (_Float16)v;
}

// ---------------- weekly weights fp16 ----------------
__global__ void convWk_k(const float* __restrict__ src, _Float16* __restrict__ dst) {
    int col = blockIdx.x * 256 + threadIdx.x;  // 0..1023
    int r = blockIdx.y;                        // 0..3071
    dst[(size_t)r * HH + col] = (_Float16)src[(size_t)r * HH + col];
}

// ---------------- x -> fp16 padded transpose: xT[w][t][128][256] ----------------
__global__ void xcvt_k(const float* __restrict__ x0, const float* __restrict__ x1,
                       const float* __restrict__ x2, const float* __restrict__ x3,
                       _Float16* __restrict__ xT) {
    int idx = blockIdx.x * 256 + threadIdx.x;   // 2^21 total
    int k8 = idx & 31;
    int m  = (idx >> 5) & 127;
    int t  = (idx >> 12) & 127;
    int w  = idx >> 19;
    const float* xw = (w == 0) ? x0 : (w == 1) ? x1 : (w == 2) ? x2 : x3;
    h8 hv = {};
    if (m < NST) {
        const float* s = xw + ((size_t)m * TT + t) * II + k8 * 8;
        float4 fa = *(const float4*)s;
        float4 fb = *(const float4*)(s + 4);
        hv[0] = (_Float16)fa.x; hv[1] = (_Float16)fa.y;
        hv[2] = (_Float16)fa.z; hv[3] = (_Float16)fa.w;
        hv[4] = (_Float16)fb.x; hv[5] = (_Float16)fb.y;
        hv[6] = (_Float16)fb.z; hv[7] = (_Float16)fb.w;
    }
    *(h8*)&xT[(((size_t)w * TT + t) * 128 + m) * II + k8 * 8] = hv;
}

// ---------------- attW transpose: wT[w][t][tp] = attW[w][tp][t] ----------------
__global__ void wTcvt_k(const float* __restrict__ attW, float* __restrict__ wT) {
    int tp = threadIdx.x;        // 0..127
    int t  = blockIdx.x;         // 0..127
    int w  = blockIdx.y;
    wT[((size_t)w * TT + t) * TT + tp] = attW[((size_t)w * TT + tp) * TT + t];
}

// ---------------- combined bias precompute: bc[w][{r,z,ni,nh}][1024] fp32 ----
__global__ void convB_k(const float* __restrict__ bih, const float* __restrict__ bhh,
                        float* __restrict__ bc) {
    int j = blockIdx.x * 256 + threadIdx.x;
    int w = blockIdx.y;
    const float* bi = bih + w * H3;
    const float* bh = bhh + w * H3;
    float* o = bc + w * 4096;
    o[j] = bi[j] + bh[j];
    o[1024 + j] = bi[1024 + j] + bh[1024 + j];
    o[2048 + j] = bi[2048 + j];
    o[3072 + j] = bh[2048 + j];
}

// ---------------- fused encoder GRU: entire 128-step recurrence in ONE kernel.
// Weights in LDS ([chunk][gate][16][32] conflict-free layout); fp32 h master in
// registers; h published via atomicExch (allocates at L3 coherence point);
// h read via normal cached loads + one acquire fence per step (L2 dedup);
// seq via sc1 WT stores placed AFTER the flag so drain overlaps polling. ------
#define ENC_LDS_HALFS (40 * 3 * 16 * 32)
#define ENC_LDS_BYTES (ENC_LDS_HALFS * 2)

__global__ __launch_bounds__(256) void enc_fused_k(
    const _Float16* __restrict__ Wc, const float* __restrict__ bc,
    const _Float16* __restrict__ xT,
    _Float16* __restrict__ hhA, _Float16* __restrict__ hhB,
    _Float16* __restrict__ seq, unsigned* flags)
{
    extern __shared__ _Float16 Bs[];   // [40][3][16][32] fragment-contiguous

    // XCD-confinement swizzle: round-robin dispatch puts linear id%8 on XCD id%8.
    // week w = (id&7)>>1  ->  week w's 64 blocks land on XCD pair {2w, 2w+1}.
    int id = blockIdx.x;
    int rr = id & 7, qq = id >> 3;
    int w  = rr >> 1;
    int bx = qq * 2 + (rr & 1);        // 0..63 within week
    int j0 = bx * 16;

    const _Float16* Wcw = Wc + (size_t)w * H3 * 1280;
    const float* bcw = bc + w * 4096;
    _Float16* hA = hhA + (size_t)w * 128 * HH;
    _Float16* hB = hhB + (size_t)w * 128 * HH;
    unsigned* fw = flags + (size_t)w * 64 * 16;   // per-week flag group, 64B stride

    int tid = threadIdx.x;
    int lane = tid & 63, wi = tid >> 6, quad = lane >> 4, l15 = lane & 15;

    // one-time weight staging: 192 threads, 16B each, 40 chunks
    // dst layout: Bs[c][g][jj][k32]  (fragment-contiguous, conflict-free reads)
    if (tid < 192) {
        int brow = tid >> 2, bseg = tid & 3;
        int g = brow >> 4, jj = brow & 15;
        const _Float16* bsrc =
            Wcw + (size_t)(g * 1024 + j0 + jj) * 1280 + bseg * 8;
        #pragma unroll 8
        for (int c = 0; c < 40; c++) {
            uint4 v = *(const uint4*)(bsrc + c * 32);
            *(uint4*)&Bs[(((size_t)c * 3 + g) * 16 + jj) * 32 + bseg * 8] = v;
        }
    }
    __syncthreads();

    int j = j0 + l15;
    float br = bcw[j], bz = bcw[1024 + j], bni = bcw[2048 + j], bnh = bcw[3072 + j];
    int r0 = wi * 32 + l15, r1 = wi * 32 + 16 + l15;
    float hreg[2][4] = {};   // fp32 h master, block-private -> registers

    for (int t = 0; t < TT; t++) {
        const _Float16* hin = (t & 1) ? hB : hA;
        _Float16* hout = (t & 1) ? hA : hB;
        const _Float16* xt = xT + ((size_t)w * TT + t) * 128 * II;
        const _Float16* pA0h = hin + (size_t)r0 * HH + quad * 8;
        const _Float16* pA1h = hin + (size_t)r1 * HH + quad * 8;
        const _Float16* pA0x = xt + (size_t)r0 * II + quad * 8;
        const _Float16* pA1x = xt + (size_t)r1 * II + quad * 8;

        f4 aR[2] = {}, aZ[2] = {}, aNH[2] = {}, aNX[2] = {};

        // 8-deep prefetch ring (normal cached loads; post-fence refill from L3)
        h8 rb0[8], rb1[8];
        #pragma unroll
        for (int u = 0; u < 8; u++) {
            rb0[u] = *(const h8*)(pA0h + u * 32);
            rb1[u] = *(const h8*)(pA1h + u * 32);
        }

        #pragma unroll 8
        for (int c = 0; c < 40; c++) {
            int u = c & 7;
            h8 a0 = rb0[u], a1 = rb1[u];
            int cn = c + 8;
            if (cn < 32) {               // h chunks
                rb0[u] = *(const h8*)(pA0h + cn * 32);
                rb1[u] = *(const h8*)(pA1h + cn * 32);
            } else if (cn < 40) {        // x chunks
                rb0[u] = *(const h8*)(pA0x + (cn - 32) * 32);
                rb1[u] = *(const h8*)(pA1x + (cn - 32) * 32);
            }
            const _Float16* bb = &Bs[(size_t)c * 1536];   // 3*16*32 halfs per chunk
            h8 bf0 = *(const h8*)&bb[l15 * 32 + quad * 8];
            h8 bf1 = *(const h8*)&bb[512 + l15 * 32 + quad * 8];
            h8 bf2 = *(const h8*)&bb[1024 + l15 * 32 + quad * 8];
            aR[0] = __builtin_amdgcn_mfma_f32_16x16x32_f16(a0, bf0, aR[0], 0, 0, 0);
            aR[1] = __builtin_amdgcn_mfma_f32_16x16x32_f16(a1, bf0, aR[1], 0, 0, 0);
            aZ[0] = __builtin_amdgcn_mfma_f32_16x16x32_f16(a0, bf1, aZ[0], 0, 0, 0);
            aZ[1] = __builtin_amdgcn_mfma_f32_16x16x32_f16(a1, bf1, aZ[1], 0, 0, 0);
            if (c < 32) {
                aNH[0] = __builtin_amdgcn_mfma_f32_16x16x32_f16(a0, bf2, aNH[0], 0, 0, 0);
                aNH[1] = __builtin_amdgcn_mfma_f32_16x16x32_f16(a1, bf2, aNH[1], 0, 0, 0);
            } else {
                aNX[0] = __builtin_amdgcn_mfma_f32_16x16x32_f16(a0, bf2, aNX[0], 0, 0, 0);
                aNX[1] = __builtin_amdgcn_mfma_f32_16x16x32_f16(a1, bf2, aNX[1], 0, 0, 0);
            }
        }

        // ---- gate epilogue: C/D mapping col=lane&15, row=quad*4+reg.
        // Pack cols (j, j+1); h published via atomicExch (L3-allocating). ----
        unsigned pks[2][4];
        #pragma unroll
        for (int mi = 0; mi < 2; mi++) {
            #pragma unroll
            for (int p = 0; p < 4; p++) {
                int row = wi * 32 + mi * 16 + quad * 4 + p;
                float r = sigf(aR[mi][p] + br);
                float z = sigf(aZ[mi][p] + bz);
                float n = tanhf(aNX[mi][p] + bni + r * (aNH[mi][p] + bnh));
                float hv = (1.f - z) * n + z * hreg[mi][p];
                hreg[mi][p] = hv;
                unsigned short hb = __builtin_bit_cast(unsigned short, (_Float16)hv);
                unsigned ob = __shfl_xor((unsigned)hb, 1);
                unsigned pk = (unsigned)hb | (ob << 16);
                pks[mi][p] = pk;
                if (!(l15 & 1) && t < TT - 1)
                    __hip_atomic_exchange((unsigned*)&hout[(size_t)row * HH + j], pk,
                                          __ATOMIC_RELAXED, __HIP_MEMORY_SCOPE_AGENT);
            }
        }
        // ---- arrive: h-atomics drained by syncthreads, then flag (relaxed sc1) ----
        if (t < TT - 1) {
            __syncthreads();
            if (tid == 0)
                __hip_atomic_store(&fw[bx * 16], (unsigned)(t + 1),
                                   __ATOMIC_RELAXED, __HIP_MEMORY_SCOPE_AGENT);
        }
        // ---- seq stores (sc1 WT, not read in-kernel) overlap the poll below ----
        #pragma unroll
        for (int mi = 0; mi < 2; mi++) {
            #pragma unroll
            for (int p = 0; p < 4; p++) {
                int row = wi * 32 + mi * 16 + quad * 4 + p;
                if (!(l15 & 1) && row < NST)
                    __hip_atomic_store(
                        (unsigned*)&seq[(((size_t)w * NST + row) * TT + t) * HH + j],
                        pks[mi][p], __ATOMIC_RELAXED, __HIP_MEMORY_SCOPE_AGENT);
            }
        }
        // ---- wait + acquire (buffer_inv drops stale cached h lines) ----
        if (t < TT - 1) {
            if (tid < 64) spin_wait(&fw[tid * 16], (unsigned)t);
            __syncthreads();
            __builtin_amdgcn_fence(__ATOMIC_ACQUIRE, "agent");
        }
    }
}

// ---------------- encoder time-attention (fp16 seq, wT pre-transposed) ----------------
__global__ __launch_bounds__(256) void att1_k(
    const _Float16* __restrict__ seq, const float* __restrict__ wT,
    const float* __restrict__ attb, float* __restrict__ wex)
{
    int d0 = blockIdx.x * 128;
    int n  = blockIdx.y;
    int w  = blockIdx.z;
    __shared__ _Float16 S[128][128];  // [t][d]
    __shared__ float PM[16][136];
    int tid = threadIdx.x;
    const _Float16* sp = seq + ((size_t)(w * NST + n) * TT) * HH + d0;
    for (int q = tid; q < 2048; q += 256) {
        int t = q >> 4, seg = q & 15;
        *(h8*)&S[t][seg * 8] = *(const h8*)(sp + (size_t)t * HH + seg * 8);
    }
    __syncthreads();
    int tx = tid & 15, ty = tid >> 4;
    const float* Wg = wT + (size_t)w * TT * TT;   // [t][tp]
    float acc[8][8];
    #pragma unroll
    for (int i = 0; i < 8; i++) {
        float b = attb[w * TT + ty * 8 + i];
        for (int j = 0; j < 8; j++) acc[i][j] = b;
    }
    for (int t = 0; t < 128; t++) {
        float wv[8], sv[8];
        float4 wa = *(const float4*)&Wg[(size_t)t * TT + ty * 8];
        float4 wb = *(const float4*)&Wg[(size_t)t * TT + ty * 8 + 4];
        wv[0] = wa.x; wv[1] = wa.y; wv[2] = wa.z; wv[3] = wa.w;
        wv[4] = wb.x; wv[5] = wb.y; wv[6] = wb.z; wv[7] = wb.w;
        h8 s8 = *(const h8*)&S[t][tx * 8];
        #pragma unroll
        for (int j = 0; j < 8; j++) sv[j] = (float)s8[j];
        #pragma unroll
        for (int i = 0; i < 8; i++)
            #pragma unroll
            for (int j = 0; j < 8; j++) acc[i][j] += wv[i] * sv[j];
    }
    float cmax[8], csum[8];
    #pragma unroll
    for (int j = 0; j < 8; j++) {
        float m = acc[0][j];
        for (int i = 1; i < 8; i++) m = fmaxf(m, acc[i][j]);
        PM[ty][tx * 8 + j] = m;
    }
    __syncthreads();
    #pragma unroll
    for (int j = 0; j < 8; j++) {
        float m = -1e30f;
        for (int yy = 0; yy < 16; yy++) m = fmaxf(m, PM[yy][tx * 8 + j]);
        cmax[j] = m;
    }
    __syncthreads();
    #pragma unroll
    for (int j = 0; j < 8; j++) {
        float s = 0.f;
        for (int i = 0; i < 8; i++) { acc[i][j] = expf(acc[i][j] - cmax[j]); s += acc[i][j]; }
        PM[ty][tx * 8 + j] = s;
    }
    __syncthreads();
    #pragma unroll
    for (int j = 0; j < 8; j++) {
        float s = 0.f;
        for (int yy = 0; yy < 16; yy++) s += PM[yy][tx * 8 + j];
        csum[j] = s;
    }
    __syncthreads();
    #pragma unroll
    for (int i = 0; i < 8; i++) {
        h8 s8 = *(const h8*)&S[ty * 8 + i][tx * 8];
        #pragma unroll
        for (int j = 0; j < 8; j++) {
            if (i == 0) PM[ty][tx * 8 + j] = 0.f;
            PM[ty][tx * 8 + j] += acc[i][j] * (float)s8[j];
        }
    }
    __syncthreads();
    if (ty == 0) {
        #pragma unroll
        for (int j = 0; j < 8; j++) {
            float o = 0.f;
            for (int yy = 0; yy < 16; yy++) o += PM[yy][tx * 8 + j];
            wex[((size_t)w * NST + n) * HH + d0 + tx * 8 + j] = o / csum[j];
        }
    }
}

// ---------------- generic fp32 GEMM: C[m][n] = sum_k A[m][k]*B[n][k] (+bias, relu) ----
template <int RELU>
__global__ __launch_bounds__(256) void gemm_tn_k(
    const float* __restrict__ A, const float* __restrict__ B,
    const float* __restrict__ bias, float* __restrict__ C, int M, int N, int K)
{
    int n0 = blockIdx.x * 64, m0 = blockIdx.y * 64;
    __shared__ float As[16][64], Bs[16][64];
    int tid = threadIdx.x, tx = tid & 15, ty = tid >> 4;
    float acc[4][4] = {{0.f}};
    for (int k0 = 0; k0 < K; k0 += 16) {
        __syncthreads();
        for (int q = tid; q < 1024; q += 256) {
            int kk = q & 15, r = q >> 4;
            int m = m0 + r, nn = n0 + r;
            As[kk][r] = (m < M) ? A[(size_t)m * K + k0 + kk] : 0.f;
            Bs[kk][r] = (nn < N) ? B[(size_t)nn * K + k0 + kk] : 0.f;
        }
        __syncthreads();
        #pragma unroll
        for (int kk = 0; kk < 16; kk++) {
            float4 av = *(const float4*)&As[kk][ty * 4];
            float4 bv = *(const float4*)&Bs[kk][tx * 4];
            float a[4] = {av.x, av.y, av.z, av.w};
            float b[4] = {bv.x, bv.y, bv.z, bv.w};
            #pragma unroll
            for (int r = 0; r < 4; r++)
                #pragma unroll
                for (int c = 0; c < 4; c++) acc[r][c] += a[r] * b[c];
        }
    }
    #pragma unroll
    for (int r = 0; r < 4; r++) {
        int m = m0 + ty * 4 + r;
        if (m >= M) continue;
        #pragma unroll
        for (int c = 0; c < 4; c++) {
            int nn = n0 + tx * 4 + c;
            if (nn >= N) continue;
            float v = acc[r][c] + (bias ? bias[nn] : 0.f);
            if (RELU) v = fmaxf(v, 0.f);
            C[(size_t)m * N + nn] = v;
        }
    }
}

// ---------------- fused weekly GRU: 100-step recurrence in ONE kernel.
// h published via atomicExch (L3-allocating), read via sc1 (L3 hit), no fences. --
__global__ __launch_bounds__(256) void wk_fused_k(
    const float* __restrict__ gxw, const _Float16* __restrict__ wkW,
    const float* __restrict__ bhh, float* __restrict__ hA,
    float* __restrict__ hB, float* __restrict__ we2, unsigned* flags)
{
    int tid = threadIdx.x;
    int wi = tid >> 6, lane = tid & 63;
    int j = blockIdx.x * 4 + wi;
    int k0 = lane * 16;
    float wf[3][16];
    #pragma unroll
    for (int g = 0; g < 3; g++) {
        h8 wa = *(const h8*)&wkW[(size_t)(g * HH + j) * HH + k0];
        h8 wb = *(const h8*)&wkW[(size_t)(g * HH + j) * HH + k0 + 8];
        #pragma unroll
        for (int i = 0; i < 8; i++) { wf[g][i] = (float)wa[i]; wf[g][8 + i] = (float)wb[i]; }
    }
    float b0 = bhh[j], b1 = bhh[HH + j], b2 = bhh[2 * HH + j];

    for (int t = 0; t < NST; t++) {
        const float* hin = (t & 1) ? hB : hA;
        float* hout = (t & 1) ? hA : hB;
        float acc[4][3] = {};
        #pragma unroll
        for (int b = 0; b < 4; b++) {
            float hv[16];
            #pragma unroll
            for (int s = 0; s < 4; s++) {
                float4 hq = ld_f4_sc1(&hin[b * HH + k0 + s * 4]);
                hv[s * 4] = hq.x; hv[s * 4 + 1] = hq.y;
                hv[s * 4 + 2] = hq.z; hv[s * 4 + 3] = hq.w;
            }
            #pragma unroll
            for (int g = 0; g < 3; g++)
                #pragma unroll
                for (int i = 0; i < 16; i++) acc[b][g] += wf[g][i] * hv[i];
        }
        #pragma unroll
        for (int b = 0; b < 4; b++)
            #pragma unroll
            for (int g = 0; g < 3; g++)
                for (int o = 32; o; o >>= 1) acc[b][g] += __shfl_down(acc[b][g], o);
        if (lane == 0) {
            for (int b = 0; b < 4; b++) {
                const float* gx = gxw + ((size_t)b * NST + t) * H3;
                float hr = acc[b][0] + b0;
                float hz = acc[b][1] + b1;
                float hn = acc[b][2] + b2;
                float r = sigf(gx[j] + hr);
                float z = sigf(gx[HH + j] + hz);
                float n = tanhf(gx[2 * HH + j] + r * hn);
                float hv = (1.f - z) * n + z * ld_f_sc1(&hin[b * HH + j]);
                __hip_atomic_exchange(&hout[b * HH + j], hv,
                                      __ATOMIC_RELAXED, __HIP_MEMORY_SCOPE_AGENT);
                we2[((size_t)t * 4 + b) * HH + j] = hv;
            }
        }
        // ---- flag barrier across 256 blocks: relaxed store (vmcnt anchor), no fences ----
        if (t < NST - 1) {
            __syncthreads();
            if (tid == 0)
                __hip_atomic_store(&flags[blockIdx.x * 16], (unsigned)(t + 1),
                                   __ATOMIC_RELAXED, __HIP_MEMORY_SCOPE_AGENT);
            spin_wait(&flags[tid * 16], (unsigned)t);
            __syncthreads();
        }
    }
}

// ---------------- weekly attention (T=4) ----------------
__global__ void wkatt_k(const float* __restrict__ we2, const float* __restrict__ W,
                        const float* __restrict__ bv, float* __restrict__ wav)
{
    int n = blockIdx.x;
    for (int d = threadIdx.x; d < HH; d += 256) {
        float v[4], l[4];
        #pragma unroll
        for (int tp = 0; tp < 4; tp++) v[tp] = we2[((size_t)n * 4 + tp) * HH + d];
        float mx = -1e30f;
        #pragma unroll
        for (int tp = 0; tp < 4; tp++) {
            float s = bv[tp];
            for (int t2 = 0; t2 < 4; t2++) s += v[t2] * W[tp * 4 + t2];
            l[tp] = s; mx = fmaxf(mx, s);
        }
        float se = 0.f, o = 0.f;
        #pragma unroll
        for (int tp = 0; tp < 4; tp++) {
            float e = expf(l[tp] - mx);
            se += e; o += e * v[tp];
        }
        wav[(size_t)n * HH + d] = o / se;
    }
}

// ---------------- pool attention (C=5, T=20) ----------------
__global__ void poolatt_k(const float* __restrict__ wav, const float* __restrict__ W,
                          const float* __restrict__ bv, float* __restrict__ cat1)
{
    int c = blockIdx.x;
    for (int d = threadIdx.x; d < HH; d += 256) {
        float v[20], l[20];
        for (int t2 = 0; t2 < 20; t2++) v[t2] = wav[((size_t)c * 20 + t2) * HH + d];
        float mx = -1e30f;
        for (int tp = 0; tp < 20; tp++) {
            float s = bv[tp];
            for (int t2 = 0; t2 < 20; t2++) s += v[t2] * W[tp * 20 + t2];
            l[tp] = s; mx = fmaxf(mx, s);
        }
        float se = 0.f, o = 0.f;
        for (int tp = 0; tp < 20; tp++) {
            float e = expf(l[tp] - mx);
            se += e; o += e * v[tp];
        }
        cat1[(size_t)c * HH + d] = o / se;
    }
}

// ---------------- GAT: per-node alpha dots ----------------
__global__ void gat_dots_k(const float* __restrict__ h, const float* __restrict__ as_,
                           const float* __restrict__ ad_, float* __restrict__ ss,
                           float* __restrict__ sd)
{
    int i = blockIdx.x, tid = threadIdx.x;
    float s1 = 0.f, s2 = 0.f;
    for (int k = tid; k < HH; k += 256) {
        float v = h[(size_t)i * HH + k];
        s1 += v * as_[k]; s2 += v * ad_[k];
    }
    __shared__ float r1[256], r2[256];
    r1[tid] = s1; r2[tid] = s2; __syncthreads();
    for (int s = 128; s; s >>= 1) {
        if (tid < s) { r1[tid] += r1[tid + s]; r2[tid] += r2[tid + s]; }
        __syncthreads();
    }
    if (tid == 0) { ss[i] = r1[0]; sd[i] = r2[0]; }
}

// ---------------- GAT aggregate: block per dst node ----------------
#define MAXE 256
__global__ __launch_bounds__(256) void gat_agg_k(
    const float* __restrict__ hmat, const int* __restrict__ esrc,
    const int* __restrict__ edst, int nedges, const float* __restrict__ ss,
    const float* __restrict__ sd, const float* __restrict__ bias, float* __restrict__ outp)
{
    int i = blockIdx.x, tid = threadIdx.x;
    __shared__ int cnt;
    __shared__ int msrc[MAXE];
    __shared__ float mw[MAXE];
    __shared__ float inv_s;
    if (tid == 0) {
        cnt = 1; msrc[0] = i;
        float e = ss[i] + sd[i];
        mw[0] = e > 0.f ? e : 0.2f * e;
    }
    __syncthreads();
    for (int e = tid; e < nedges; e += 256) {
        if (edst[e] == i) {
            int p = atomicAdd(&cnt, 1);
            if (p < MAXE) {
                int s = esrc[e];
                msrc[p] = s;
                float v = ss[s] + sd[i];
                mw[p] = v > 0.f ? v : 0.2f * v;
            }
        }
    }
    __syncthreads();
    int m = min(cnt, MAXE);
    if (tid == 0) {
        float mx = -1e30f;
        for (int p = 0; p < m; p++) mx = fmaxf(mx, mw[p]);
        float s = 0.f;
        for (int p = 0; p < m; p++) { float e = expf(mw[p] - mx); mw[p] = e; s += e; }
        inv_s = 1.0f / s;
    }
    __syncthreads();
    for (int d = tid; d < HH; d += 256) {
        float a = 0.f;
        for (int p = 0; p < m; p++) a += mw[p] * hmat[(size_t)msrc[p] * HH + d];
        outp[(size_t)i * HH + d] = a * inv_s + bias[d];
    }
}

// ---------------- concat [wav3, cat, inner] ----------------
__global__ void concat_k(const float* __restrict__ wav, const float* __restrict__ gc,
                         const float* __restrict__ gi, float* __restrict__ cc)
{
    int row = blockIdx.x;
    int c = row / 20;
    for (int k = threadIdx.x; k < H3; k += 256) {
        float v;
        if (k < HH) v = wav[(size_t)row * HH + k];
        else if (k < 2 * HH) v = gc[(size_t)c * HH + (k - HH)];
        else v = gi[(size_t)row * HH + (k - 2 * HH)];
        cc[(size_t)row * H3 + k] = v;
    }
}

// ---------------- reg/cls heads ----------------
__global__ void heads_k(const float* __restrict__ f, const float* __restrict__ regW,
                        const float* __restrict__ regb, const float* __restrict__ clsW,
                        const float* __restrict__ clsb, float* __restrict__ outp)
{
    int i = blockIdx.x, tid = threadIdx.x;
    float s1 = 0.f, s2 = 0.f;
    for (int k = tid; k < HH; k += 256) {
        float v = f[(size_t)i * HH + k];
        s1 += v * regW[k]; s2 += v * clsW[k];
    }
    __shared__ float r1[256], r2[256];
    r1[tid] = s1; r2[tid] = s2; __syncthreads();
    for (int s = 128; s; s >>= 1) {
        if (tid < s) { r1[tid] += r1[tid + s]; r2[tid] += r2[tid + s]; }
        __syncthreads();
    }
    if (tid == 0) {
        outp[i] = r1[0] + regb[0];
        outp[100 + i] = sigf(r2[0] + clsb[0]);
    }
}

extern "C" void kernel_launch(void* const* d_in, const int* in_sizes, int n_in,
                              void* d_out, int out_size, void* d_ws, size_t ws_size,
                              hipStream_t stream)
{
    (void)in_sizes; (void)n_in; (void)out_size; (void)ws_size;
    const float* x0 = (const float*)d_in[0];
    const float* x1 = (const float*)d_in[1];
    const float* x2 = (const float*)d_in[2];
    const float* x3 = (const float*)d_in[3];
    const int*   ie = (const int*)d_in[4];
    const int*   oe = (const int*)d_in[5];
    const float* enc_Wih = (const float*)d_in[6];
    const float* enc_Whh = (const float*)d_in[7];
    const float* enc_bih = (const float*)d_in[8];
    const float* enc_bhh = (const float*)d_in[9];
    const float* enc_attW = (const float*)d_in[10];
    const float* enc_attb = (const float*)d_in[11];
    const float* wk_Wih = (const float*)d_in[12];
    const float* wk_Whh = (const float*)d_in[13];
    const float* wk_bih = (const float*)d_in[14];
    const float* wk_bhh = (const float*)d_in[15];
    const float* wkatt_W = (const float*)d_in[16];
    const float* wkatt_b = (const float*)d_in[17];
    const float* pool_W = (const float*)d_in[18];
    const float* pool_b = (const float*)d_in[19];
    const float* ig_W = (const float*)d_in[20];
    const float* ig_as = (const float*)d_in[21];
    const float* ig_ad = (const float*)d_in[22];
    const float* ig_b = (const float*)d_in[23];
    const float* cg_W = (const float*)d_in[24];
    const float* cg_as = (const float*)d_in[25];
    const float* cg_ad = (const float*)d_in[26];
    const float* cg_b = (const float*)d_in[27];
    const float* fus_W = (const float*)d_in[28];
    const float* fus_b = (const float*)d_in[29];
    const float* reg_W = (const float*)d_in[30];
    const float* reg_b = (const float*)d_in[31];
    const float* cls_W = (const float*)d_in[32];
    const float* cls_b = (const float*)d_in[33];
    float* outp = (float*)d_out;

    // workspace carve-up
    char* p = (char*)d_ws;
    auto alloc = [&](size_t bytes) { char* r = p; p += (bytes + 255) & ~(size_t)255; return (void*)r; };
    unsigned* flags = (unsigned*)alloc(2 * 256 * 16 * 4);  // [0..255]=enc (4w x 64), [256..511]=wk
    _Float16* Wcat = (_Float16*)alloc((size_t)NW * H3 * 1280 * 2);
    float* bc = (float*)alloc((size_t)NW * 4 * HH * 4);
    _Float16* wkW = (_Float16*)alloc((size_t)H3 * HH * 2);
    _Float16* xT = (_Float16*)alloc((size_t)NW * TT * 128 * II * 2);
    float* wT = (float*)alloc((size_t)NW * TT * TT * 4);
    _Float16* hhA = (_Float16*)alloc((size_t)NW * 128 * HH * 2);
    _Float16* hhB = (_Float16*)alloc((size_t)NW * 128 * HH * 2);
    _Float16* seq = (_Float16*)alloc((size_t)NW * NST * TT * HH * 2);
    float* wex = (float*)alloc((size_t)NW * NST * HH * 4);
    float* gxw = (float*)alloc((size_t)NW * NST * H3 * 4);
    float* hwA = (float*)alloc(4 * HH * 4);
    float* hwB = (float*)alloc(4 * HH * 4);
    float* we2 = (float*)alloc((size_t)NST * 4 * HH * 4);
    float* wav = (float*)alloc((size_t)NST * HH * 4);
    float* hi  = (float*)alloc((size_t)NST * HH * 4);
    float* si_s = (float*)alloc(128 * 4);
    float* si_d = (float*)alloc(128 * 4);
    float* gi  = (float*)alloc((size_t)NST * HH * 4);
    float* cat1 = (float*)alloc(5 * HH * 4);
    float* hc  = (float*)alloc(5 * HH * 4);
    float* sc_s = (float*)alloc(64 * 4);
    float* sc_d = (float*)alloc(64 * 4);
    float* gc  = (float*)alloc(5 * HH * 4);
    float* cc  = (float*)alloc((size_t)NST * H3 * 4);
    float* fbuf = (float*)alloc((size_t)NST * HH * 4);

    // allow >64KB dynamic LDS for the fused encoder (once)
    static bool attr_done = false;
    if (!attr_done) {
        hipFuncSetAttribute((const void*)enc_fused_k,
                            hipFuncAttributeMaxDynamicSharedMemorySize, ENC_LDS_BYTES);
        attr_done = true;
    }

    // one-time conversions + zero-init (flag state re-zeroed every replay)
    zero_k<<<32, 256, 0, stream>>>((float*)flags, 2 * 256 * 16);
    convW_k<<<dim3(5, H3, NW), 256, 0, stream>>>(enc_Whh, enc_Wih, Wcat);
    convB_k<<<dim3(4, NW), 256, 0, stream>>>(enc_bih, enc_bhh, bc);
    convWk_k<<<dim3(4, H3), 256, 0, stream>>>(wk_Whh, wkW);
    xcvt_k<<<8192, 256, 0, stream>>>(x0, x1, x2, x3, xT);
    wTcvt_k<<<dim3(TT, NW), 128, 0, stream>>>(enc_attW, wT);
    zero_k<<<(NW * 128 * HH / 2 + 255) / 256, 256, 0, stream>>>((float*)hhA, NW * 128 * HH / 2);
    zero_k<<<(4 * HH + 255) / 256, 256, 0, stream>>>(hwA, 4 * HH);

    // 4-week encoder GRU: single kernel, 128 internal steps, XCD-confined weeks
    enc_fused_k<<<256, 256, ENC_LDS_BYTES, stream>>>(
        Wcat, bc, xT, hhA, hhB, seq, flags);

    // per-week time attention -> wex[w][n][d]
    att1_k<<<dim3(8, NST, NW), 256, 0, stream>>>(seq, wT, enc_attb, wex);

    // weekly GRU input projection (bias folded in)
    gemm_tn_k<0><<<dim3(48, 7), 256, 0, stream>>>(wex, wk_Wih, wk_bih, gxw, 400, H3, HH);

    // weekly GRU recurrence: single kernel, 100 internal steps
    wk_fused_k<<<256, 256, 0, stream>>>(gxw, wkW, wk_bhh, hwA, hwB, we2, flags + 256 * 16);

    // weekly attention -> wav (100,1024)
    wkatt_k<<<NST, 256, 0, stream>>>(we2, wkatt_W, wkatt_b, wav);

    // inner GAT
    gemm_tn_k<0><<<dim3(16, 2), 256, 0, stream>>>(wav, ig_W, nullptr, hi, NST, HH, HH);
    gat_dots_k<<<NST, 256, 0, stream>>>(hi, ig_as, ig_ad, si_s, si_d);
    gat_agg_k<<<NST, 256, 0, stream>>>(hi, ie, ie + 2000, 2000, si_s, si_d, ig_b, gi);

    // category pooling attention + outer GAT
    poolatt_k<<<5, 256, 0, stream>>>(wav, pool_W, pool_b, cat1);
    gemm_tn_k<0><<<dim3(16, 1), 256, 0, stream>>>(cat1, cg_W, nullptr, hc, 5, HH, HH);
    gat_dots_k<<<5, 256, 0, stream>>>(hc, cg_as, cg_ad, sc_s, sc_d);
    gat_agg_k<<<5, 256, 0, stream>>>(hc, oe, oe + 25, 25, sc_s, sc_d, cg_b, gc);

    // fusion + heads
    concat_k<<<NST, 256, 0, stream>>>(wav, gc, gi, cc);
    gemm_tn_k<1><<<dim3(16, 2), 256, 0, stream>>>(cc, fus_W, fus_b, fbuf, NST, HH, H3);
    heads_k<<<NST, 256, 0, stream>>>(fbuf, reg_W, reg_b, cls_W, cls_b, outp);
}

// Round 9
// 4598.576 us; speedup vs baseline: 2.3099x; 1.1183x over previous
//
#include <hip/hip_runtime.h>
#include <hip/hip_bf16.h>

#define NW 4
#define NST 100
#define TT 128
#define II 256
#define HH 1024
#define H3 3072

typedef _Float16 h8 __attribute__((ext_vector_type(8)));
typedef float f4 __attribute__((ext_vector_type(4)));

__device__ __forceinline__ float sigf(float x) { return 1.0f / (1.0f + __expf(-x)); }
__device__ __forceinline__ float tanhfast(float x) { return 1.0f - 2.0f / (1.0f + __expf(2.0f * x)); }

// ---- coherent (L3-direct, sc1) loads for the small weekly-GRU h exchange ----
__device__ __forceinline__ float4 ld_f4_sc1(const float* p) {
    union { unsigned long long u[2]; float4 v; } r;
    r.u[0] = __hip_atomic_load((unsigned long long*)p, __ATOMIC_RELAXED, __HIP_MEMORY_SCOPE_AGENT);
    r.u[1] = __hip_atomic_load((unsigned long long*)p + 1, __ATOMIC_RELAXED, __HIP_MEMORY_SCOPE_AGENT);
    return r.v;
}
__device__ __forceinline__ float ld_f_sc1(const float* p) {
    return __hip_atomic_load((float*)p, __ATOMIC_RELAXED, __HIP_MEMORY_SCOPE_AGENT);
}

// ---- bounded spin: never hang the queue; a sync failure becomes a clean mismatch ----
__device__ __forceinline__ void spin_wait(unsigned* f, unsigned t) {
    int guard = 0;
    while (__hip_atomic_load(f, __ATOMIC_RELAXED, __HIP_MEMORY_SCOPE_AGENT) <= t) {
        __builtin_amdgcn_s_sleep(1);
        if (++guard > (1 << 20)) break;
    }
}

// ---------------- zero init ----------------
__global__ void zero_k(float* a, int n) {
    int i = blockIdx.x * 256 + threadIdx.x;
    if (i < n) a[i] = 0.0f;
}

// ---------------- weight concat + fp16 convert: Wc[w][3072][1280] = [Whh | Wih] ----
__global__ void convW_k(const float* __restrict__ Whh, const float* __restrict__ Wih,
                        _Float16* __restrict__ Wc) {
    int col = blockIdx.x * 256 + threadIdx.x;  // 0..1279
    int r = blockIdx.y;                        // 0..3071
    int w = blockIdx.z;
    float v = (col < HH) ? Whh[((size_t)w * H3 + r) * HH + col]
                         : Wih[((size_t)w * H3 + r) * II + (col - HH)];
    Wc[((size_t)w * H3 + r) * 1280 + col] = (_Float16)v;
}

// ---------------- weekly weights fp16 ----------------
__global__ void convWk_k(const float* __restrict__ src, _Float16* __restrict__ dst) {
    int col = blockIdx.x * 256 + threadIdx.x;  // 0..1023
    int r = blockIdx.y;                        // 0..3071
    dst[(size_t)r * HH + col] = (_Float16)src[(size_t)r * HH + col];
}

// ---------------- x -> fp16 padded transpose: xT[w][t][128][256] ----------------
__global__ void xcvt_k(const float* __restrict__ x0, const float* __restrict__ x1,
                       const float* __restrict__ x2, const float* __restrict__ x3,
                       _Float16* __restrict__ xT) {
    int idx = blockIdx.x * 256 + threadIdx.x;   // 2^21 total
    int k8 = idx & 31;
    int m  = (idx >> 5) & 127;
    int t  = (idx >> 12) & 127;
    int w  = idx >> 19;
    const float* xw = (w == 0) ? x0 : (w == 1) ? x1 : (w == 2) ? x2 : x3;
    h8 hv = {};
    if (m < NST) {
        const float* s = xw + ((size_t)m * TT + t) * II + k8 * 8;
        float4 fa = *(const float4*)s;
        float4 fb = *(const float4*)(s + 4);
        hv[0] = (_Float16)fa.x; hv[1] = (_Float16)fa.y;
        hv[2] = (_Float16)fa.z; hv[3] = (_Float16)fa.w;
        hv[4] = (_Float16)fb.x; hv[5] = (_Float16)fb.y;
        hv[6] = (_Float16)fb.z; hv[7] = (_Float16)fb.w;
    }
    *(h8*)&xT[(((size_t)w * TT + t) * 128 + m) * II + k8 * 8] = hv;
}

// ---------------- attW transpose: wT[w][t][tp] = attW[w][tp][t] ----------------
__global__ void wTcvt_k(const float* __restrict__ attW, float* __restrict__ wT) {
    int tp = threadIdx.x;        // 0..127
    int t  = blockIdx.x;         // 0..127
    int w  = blockIdx.y;
    wT[((size_t)w * TT + t) * TT + tp] = attW[((size_t)w * TT + tp) * TT + t];
}

// ---------------- combined bias precompute: bc[w][{r,z,ni,nh}][1024] fp32 ----
__global__ void convB_k(const float* __restrict__ bih, const float* __restrict__ bhh,
                        float* __restrict__ bc) {
    int j = blockIdx.x * 256 + threadIdx.x;
    int w = blockIdx.y;
    const float* bi = bih + w * H3;
    const float* bh = bhh + w * H3;
    float* o = bc + w * 4096;
    o[j] = bi[j] + bh[j];
    o[1024 + j] = bi[1024 + j] + bh[1024 + j];
    o[2048 + j] = bi[2048 + j];
    o[3072 + j] = bh[2048 + j];
}

// ---------------- fused encoder GRU: entire 128-step recurrence in ONE kernel.
// Weights in LDS; fp32 h master in registers; 12-deep h-prefetch ring; x chunks
// prefetched into dedicated regs DURING the barrier spin (read-only =>
// stale-safe across the fence); hierarchical flag barrier (arrive flags ->
// master block -> one generation word). ------
#define ENC_LDS_HALFS (40 * 3 * 16 * 32)
#define ENC_LDS_BYTES (ENC_LDS_HALFS * 2)

__global__ __launch_bounds__(256) void enc_fused_k(
    const _Float16* __restrict__ Wc, const float* __restrict__ bc,
    const _Float16* __restrict__ xT,
    _Float16* __restrict__ hhA, _Float16* __restrict__ hhB,
    _Float16* __restrict__ seq, unsigned* flags)
{
    extern __shared__ _Float16 Bs[];   // [40][3][16][32] fragment-contiguous

    // XCD-confinement swizzle: week w's 64 blocks land on XCD pair {2w, 2w+1}.
    int id = blockIdx.x;
    int rr = id & 7, qq = id >> 3;
    int w  = rr >> 1;
    int bx = qq * 2 + (rr & 1);        // 0..63 within week
    int j0 = bx * 16;

    const _Float16* Wcw = Wc + (size_t)w * H3 * 1280;
    const float* bcw = bc + w * 4096;
    _Float16* hA = hhA + (size_t)w * 128 * HH;
    _Float16* hB = hhB + (size_t)w * 128 * HH;
    unsigned* fw = flags + (size_t)w * 64 * 16;        // per-week arrive flags
    unsigned* genw = flags + (size_t)(256 + w) * 16;   // per-week generation word

    int tid = threadIdx.x;
    int lane = tid & 63, wi = tid >> 6, quad = lane >> 4, l15 = lane & 15;

    // one-time weight staging: dst layout Bs[c][g][jj][k32] (fragment-contiguous)
    if (tid < 192) {
        int brow = tid >> 2, bseg = tid & 3;
        int g = brow >> 4, jj = brow & 15;
        const _Float16* bsrc =
            Wcw + (size_t)(g * 1024 + j0 + jj) * 1280 + bseg * 8;
        #pragma unroll 8
        for (int c = 0; c < 40; c++) {
            uint4 v = *(const uint4*)(bsrc + c * 32);
            *(uint4*)&Bs[(((size_t)c * 3 + g) * 16 + jj) * 32 + bseg * 8] = v;
        }
    }
    __syncthreads();

    int j = j0 + l15;
    float br = bcw[j], bz = bcw[1024 + j], bni = bcw[2048 + j], bnh = bcw[3072 + j];
    int r0 = wi * 32 + l15, r1 = wi * 32 + 16 + l15;
    float hreg[2][4] = {};   // fp32 h master, block-private -> registers

    // x chunks for t=0 preloaded into dedicated regs
    h8 xb0[8], xb1[8];
    {
        const _Float16* x0p = xT + ((size_t)w * TT) * 128 * II;
        #pragma unroll
        for (int u = 0; u < 8; u++) {
            xb0[u] = *(const h8*)(x0p + (size_t)r0 * II + quad * 8 + u * 32);
            xb1[u] = *(const h8*)(x0p + (size_t)r1 * II + quad * 8 + u * 32);
        }
    }

    for (int t = 0; t < TT; t++) {
        const _Float16* hin = (t & 1) ? hB : hA;
        _Float16* hout = (t & 1) ? hA : hB;
        const _Float16* pA0h = hin + (size_t)r0 * HH + quad * 8;
        const _Float16* pA1h = hin + (size_t)r1 * HH + quad * 8;

        f4 aR[2] = {}, aZ[2] = {}, aNH[2] = {}, aNX[2] = {};

        // 12-deep h prefetch ring
        h8 rb0[12], rb1[12];
        #pragma unroll
        for (int u = 0; u < 12; u++) {
            rb0[u] = *(const h8*)(pA0h + u * 32);
            rb1[u] = *(const h8*)(pA1h + u * 32);
        }

        #pragma unroll
        for (int c = 0; c < 40; c++) {
            h8 a0, a1;
            if (c < 32) {
                int u = c % 12;
                a0 = rb0[u]; a1 = rb1[u];
                int cn = c + 12;
                if (cn < 32) {
                    rb0[u] = *(const h8*)(pA0h + cn * 32);
                    rb1[u] = *(const h8*)(pA1h + cn * 32);
                }
            } else {
                a0 = xb0[c - 32]; a1 = xb1[c - 32];
            }
            const _Float16* bb = &Bs[(size_t)c * 1536];   // 3*16*32 halfs per chunk
            h8 bf0 = *(const h8*)&bb[l15 * 32 + quad * 8];
            h8 bf1 = *(const h8*)&bb[512 + l15 * 32 + quad * 8];
            h8 bf2 = *(const h8*)&bb[1024 + l15 * 32 + quad * 8];
            aR[0] = __builtin_amdgcn_mfma_f32_16x16x32_f16(a0, bf0, aR[0], 0, 0, 0);
            aR[1] = __builtin_amdgcn_mfma_f32_16x16x32_f16(a1, bf0, aR[1], 0, 0, 0);
            aZ[0] = __builtin_amdgcn_mfma_f32_16x16x32_f16(a0, bf1, aZ[0], 0, 0, 0);
            aZ[1] = __builtin_amdgcn_mfma_f32_16x16x32_f16(a1, bf1, aZ[1], 0, 0, 0);
            if (c < 32) {
                aNH[0] = __builtin_amdgcn_mfma_f32_16x16x32_f16(a0, bf2, aNH[0], 0, 0, 0);
                aNH[1] = __builtin_amdgcn_mfma_f32_16x16x32_f16(a1, bf2, aNH[1], 0, 0, 0);
            } else {
                aNX[0] = __builtin_amdgcn_mfma_f32_16x16x32_f16(a0, bf2, aNX[0], 0, 0, 0);
                aNX[1] = __builtin_amdgcn_mfma_f32_16x16x32_f16(a1, bf2, aNX[1], 0, 0, 0);
            }
        }

        // ---- gate epilogue (fast transcendentals): pack cols (j, j+1) ----
        unsigned pks[2][4];
        #pragma unroll
        for (int mi = 0; mi < 2; mi++) {
            #pragma unroll
            for (int p = 0; p < 4; p++) {
                int row = wi * 32 + mi * 16 + quad * 4 + p;
                float r = sigf(aR[mi][p] + br);
                float z = sigf(aZ[mi][p] + bz);
                float n = tanhfast(aNX[mi][p] + bni + r * (aNH[mi][p] + bnh));
                float hv = (1.f - z) * n + z * hreg[mi][p];
                hreg[mi][p] = hv;
                unsigned short hb = __builtin_bit_cast(unsigned short, (_Float16)hv);
                unsigned ob = __shfl_xor((unsigned)hb, 1);
                unsigned pk = (unsigned)hb | (ob << 16);
                pks[mi][p] = pk;
                if (!(l15 & 1) && t < TT - 1)
                    __hip_atomic_exchange((unsigned*)&hout[(size_t)row * HH + j], pk,
                                          __ATOMIC_RELAXED, __HIP_MEMORY_SCOPE_AGENT);
            }
        }
        // ---- arrive: h-atomics drained by syncthreads, then flag (relaxed) ----
        if (t < TT - 1) {
            __syncthreads();
            if (tid == 0)
                __hip_atomic_store(&fw[bx * 16], (unsigned)(t + 1),
                                   __ATOMIC_RELAXED, __HIP_MEMORY_SCOPE_AGENT);
        }
        // ---- seq stores (sc1 WT, not read in-kernel) overlap the poll ----
        #pragma unroll
        for (int mi = 0; mi < 2; mi++) {
            #pragma unroll
            for (int p = 0; p < 4; p++) {
                int row = wi * 32 + mi * 16 + quad * 4 + p;
                if (!(l15 & 1) && row < NST)
                    __hip_atomic_store(
                        (unsigned*)&seq[(((size_t)w * NST + row) * TT + t) * HH + j],
                        pks[mi][p], __ATOMIC_RELAXED, __HIP_MEMORY_SCOPE_AGENT);
            }
        }
        if (t < TT - 1) {
            // prefetch x for step t+1 (read-only => safe across the fence);
            // misses overlap the barrier wait below
            const _Float16* xn = xT + ((size_t)w * TT + t + 1) * 128 * II;
            #pragma unroll
            for (int u = 0; u < 8; u++) {
                xb0[u] = *(const h8*)(xn + (size_t)r0 * II + quad * 8 + u * 32);
                xb1[u] = *(const h8*)(xn + (size_t)r1 * II + quad * 8 + u * 32);
            }
            // ---- hierarchical wait: master polls 64 flags, publishes gen ----
            if (bx == 0) {
                if (tid < 64) spin_wait(&fw[tid * 16], (unsigned)t);
                __syncthreads();
                if (tid == 0)
                    __hip_atomic_store(genw, (unsigned)(t + 1),
                                       __ATOMIC_RELAXED, __HIP_MEMORY_SCOPE_AGENT);
            } else {
                if (tid == 0) spin_wait(genw, (unsigned)t);
                __syncthreads();
            }
            __builtin_amdgcn_fence(__ATOMIC_ACQUIRE, "agent");
        }
    }
}

// ---------------- encoder time-attention (fp16 seq, wT pre-transposed) ----------------
__global__ __launch_bounds__(256) void att1_k(
    const _Float16* __restrict__ seq, const float* __restrict__ wT,
    const float* __restrict__ attb, float* __restrict__ wex)
{
    int d0 = blockIdx.x * 128;
    int n  = blockIdx.y;
    int w  = blockIdx.z;
    __shared__ _Float16 S[128][128];  // [t][d]
    __shared__ float PM[16][136];
    int tid = threadIdx.x;
    const _Float16* sp = seq + ((size_t)(w * NST + n) * TT) * HH + d0;
    for (int q = tid; q < 2048; q += 256) {
        int t = q >> 4, seg = q & 15;
        *(h8*)&S[t][seg * 8] = *(const h8*)(sp + (size_t)t * HH + seg * 8);
    }
    __syncthreads();
    int tx = tid & 15, ty = tid >> 4;
    const float* Wg = wT + (size_t)w * TT * TT;   // [t][tp]
    float acc[8][8];
    #pragma unroll
    for (int i = 0; i < 8; i++) {
        float b = attb[w * TT + ty * 8 + i];
        for (int j = 0; j < 8; j++) acc[i][j] = b;
    }
    for (int t = 0; t < 128; t++) {
        float wv[8], sv[8];
        float4 wa = *(const float4*)&Wg[(size_t)t * TT + ty * 8];
        float4 wb = *(const float4*)&Wg[(size_t)t * TT + ty * 8 + 4];
        wv[0] = wa.x; wv[1] = wa.y; wv[2] = wa.z; wv[3] = wa.w;
        wv[4] = wb.x; wv[5] = wb.y; wv[6] = wb.z; wv[7] = wb.w;
        h8 s8 = *(const h8*)&S[t][tx * 8];
        #pragma unroll
        for (int j = 0; j < 8; j++) sv[j] = (float)s8[j];
        #pragma unroll
        for (int i = 0; i < 8; i++)
            #pragma unroll
            for (int j = 0; j < 8; j++) acc[i][j] += wv[i] * sv[j];
    }
    float cmax[8], csum[8];
    #pragma unroll
    for (int j = 0; j < 8; j++) {
        float m = acc[0][j];
        for (int i = 1; i < 8; i++) m = fmaxf(m, acc[i][j]);
        PM[ty][tx * 8 + j] = m;
    }
    __syncthreads();
    #pragma unroll
    for (int j = 0; j < 8; j++) {
        float m = -1e30f;
        for (int yy = 0; yy < 16; yy++) m = fmaxf(m, PM[yy][tx * 8 + j]);
        cmax[j] = m;
    }
    __syncthreads();
    #pragma unroll
    for (int j = 0; j < 8; j++) {
        float s = 0.f;
        for (int i = 0; i < 8; i++) { acc[i][j] = expf(acc[i][j] - cmax[j]); s += acc[i][j]; }
        PM[ty][tx * 8 + j] = s;
    }
    __syncthreads();
    #pragma unroll
    for (int j = 0; j < 8; j++) {
        float s = 0.f;
        for (int yy = 0; yy < 16; yy++) s += PM[yy][tx * 8 + j];
        csum[j] = s;
    }
    __syncthreads();
    #pragma unroll
    for (int i = 0; i < 8; i++) {
        h8 s8 = *(const h8*)&S[ty * 8 + i][tx * 8];
        #pragma unroll
        for (int j = 0; j < 8; j++) {
            if (i == 0) PM[ty][tx * 8 + j] = 0.f;
            PM[ty][tx * 8 + j] += acc[i][j] * (float)s8[j];
        }
    }
    __syncthreads();
    if (ty == 0) {
        #pragma unroll
        for (int j = 0; j < 8; j++) {
            float o = 0.f;
            for (int yy = 0; yy < 16; yy++) o += PM[yy][tx * 8 + j];
            wex[((size_t)w * NST + n) * HH + d0 + tx * 8 + j] = o / csum[j];
        }
    }
}

// ---------------- generic fp32 GEMM: C[m][n] = sum_k A[m][k]*B[n][k] (+bias, relu) ----
template <int RELU>
__global__ __launch_bounds__(256) void gemm_tn_k(
    const float* __restrict__ A, const float* __restrict__ B,
    const float* __restrict__ bias, float* __restrict__ C, int M, int N, int K)
{
    int n0 = blockIdx.x * 64, m0 = blockIdx.y * 64;
    __shared__ float As[16][64], Bs[16][64];
    int tid = threadIdx.x, tx = tid & 15, ty = tid >> 4;
    float acc[4][4] = {{0.f}};
    for (int k0 = 0; k0 < K; k0 += 16) {
        __syncthreads();
        for (int q = tid; q < 1024; q += 256) {
            int kk = q & 15, r = q >> 4;
            int m = m0 + r, nn = n0 + r;
            As[kk][r] = (m < M) ? A[(size_t)m * K + k0 + kk] : 0.f;
            Bs[kk][r] = (nn < N) ? B[(size_t)nn * K + k0 + kk] : 0.f;
        }
        __syncthreads();
        #pragma unroll
        for (int kk = 0; kk < 16; kk++) {
            float4 av = *(const float4*)&As[kk][ty * 4];
            float4 bv = *(const float4*)&Bs[kk][tx * 4];
            float a[4] = {av.x, av.y, av.z, av.w};
            float b[4] = {bv.x, bv.y, bv.z, bv.w};
            #pragma unroll
            for (int r = 0; r < 4; r++)
                #pragma unroll
                for (int c = 0; c < 4; c++) acc[r][c] += a[r] * b[c];
        }
    }
    #pragma unroll
    for (int r = 0; r < 4; r++) {
        int m = m0 + ty * 4 + r;
        if (m >= M) continue;
        #pragma unroll
        for (int c = 0; c < 4; c++) {
            int nn = n0 + tx * 4 + c;
            if (nn >= N) continue;
            float v = acc[r][c] + (bias ? bias[nn] : 0.f);
            if (RELU) v = fmaxf(v, 0.f);
            C[(size_t)m * N + nn] = v;
        }
    }
}

// ---------------- fused weekly GRU: 100-step recurrence, hierarchical barrier ----
__global__ __launch_bounds__(256) void wk_fused_k(
    const float* __restrict__ gxw, const _Float16* __restrict__ wkW,
    const float* __restrict__ bhh, float* __restrict__ hA,
    float* __restrict__ hB, float* __restrict__ we2, unsigned* flags)
{
    int tid = threadIdx.x;
    int wi = tid >> 6, lane = tid & 63;
    int j = blockIdx.x * 4 + wi;
    int k0 = lane * 16;
    unsigned* gen = flags + 256 * 16;   // single generation word
    float wf[3][16];
    #pragma unroll
    for (int g = 0; g < 3; g++) {
        h8 wa = *(const h8*)&wkW[(size_t)(g * HH + j) * HH + k0];
        h8 wb = *(const h8*)&wkW[(size_t)(g * HH + j) * HH + k0 + 8];
        #pragma unroll
        for (int i = 0; i < 8; i++) { wf[g][i] = (float)wa[i]; wf[g][8 + i] = (float)wb[i]; }
    }
    float b0 = bhh[j], b1 = bhh[HH + j], b2 = bhh[2 * HH + j];

    for (int t = 0; t < NST; t++) {
        const float* hin = (t & 1) ? hB : hA;
        float* hout = (t & 1) ? hA : hB;
        float acc[4][3] = {};
        #pragma unroll
        for (int b = 0; b < 4; b++) {
            float hv[16];
            #pragma unroll
            for (int s = 0; s < 4; s++) {
                float4 hq = ld_f4_sc1(&hin[b * HH + k0 + s * 4]);
                hv[s * 4] = hq.x; hv[s * 4 + 1] = hq.y;
                hv[s * 4 + 2] = hq.z; hv[s * 4 + 3] = hq.w;
            }
            #pragma unroll
            for (int g = 0; g < 3; g++)
                #pragma unroll
                for (int i = 0; i < 16; i++) acc[b][g] += wf[g][i] * hv[i];
        }
        #pragma unroll
        for (int b = 0; b < 4; b++)
            #pragma unroll
            for (int g = 0; g < 3; g++)
                for (int o = 32; o; o >>= 1) acc[b][g] += __shfl_down(acc[b][g], o);
        if (lane == 0) {
            for (int b = 0; b < 4; b++) {
                const float* gx = gxw + ((size_t)b * NST + t) * H3;
                float hr = acc[b][0] + b0;
                float hz = acc[b][1] + b1;
                float hn = acc[b][2] + b2;
                float r = sigf(gx[j] + hr);
                float z = sigf(gx[HH + j] + hz);
                float n = tanhfast(gx[2 * HH + j] + r * hn);
                float hv = (1.f - z) * n + z * ld_f_sc1(&hin[b * HH + j]);
                __hip_atomic_exchange(&hout[b * HH + j], hv,
                                      __ATOMIC_RELAXED, __HIP_MEMORY_SCOPE_AGENT);
                we2[((size_t)t * 4 + b) * HH + j] = hv;
            }
        }
        // ---- hierarchical barrier: arrive flags -> master block 0 -> gen word ----
        if (t < NST - 1) {
            __syncthreads();
            if (tid == 0)
                __hip_atomic_store(&flags[blockIdx.x * 16], (unsigned)(t + 1),
                                   __ATOMIC_RELAXED, __HIP_MEMORY_SCOPE_AGENT);
            if (blockIdx.x == 0) {
                spin_wait(&flags[tid * 16], (unsigned)t);   // 256 threads, 1 flag each
                __syncthreads();
                if (tid == 0)
                    __hip_atomic_store(gen, (unsigned)(t + 1),
                                       __ATOMIC_RELAXED, __HIP_MEMORY_SCOPE_AGENT);
            } else {
                if (tid == 0) spin_wait(gen, (unsigned)t);
                __syncthreads();
            }
        }
    }
}

// ---------------- weekly attention (T=4) ----------------
__global__ void wkatt_k(const float* __restrict__ we2, const float* __restrict__ W,
                        const float* __restrict__ bv, float* __restrict__ wav)
{
    int n = blockIdx.x;
    for (int d = threadIdx.x; d < HH; d += 256) {
        float v[4], l[4];
        #pragma unroll
        for (int tp = 0; tp < 4; tp++) v[tp] = we2[((size_t)n * 4 + tp) * HH + d];
        float mx = -1e30f;
        #pragma unroll
        for (int tp = 0; tp < 4; tp++) {
            float s = bv[tp];
            for (int t2 = 0; t2 < 4; t2++) s += v[t2] * W[tp * 4 + t2];
            l[tp] = s; mx = fmaxf(mx, s);
        }
        float se = 0.f, o = 0.f;
        #pragma unroll
        for (int tp = 0; tp < 4; tp++) {
            float e = expf(l[tp] - mx);
            se += e; o += e * v[tp];
        }
        wav[(size_t)n * HH + d] = o / se;
    }
}

// ---------------- pool attention (C=5, T=20) ----------------
__global__ void poolatt_k(const float* __restrict__ wav, const float* __restrict__ W,
                          const float* __restrict__ bv, float* __restrict__ cat1)
{
    int c = blockIdx.x;
    for (int d = threadIdx.x; d < HH; d += 256) {
        float v[20], l[20];
        for (int t2 = 0; t2 < 20; t2++) v[t2] = wav[((size_t)c * 20 + t2) * HH + d];
        float mx = -1e30f;
        for (int tp = 0; tp < 20; tp++) {
            float s = bv[tp];
            for (int t2 = 0; t2 < 20; t2++) s += v[t2] * W[tp * 20 + t2];
            l[tp] = s; mx = fmaxf(mx, s);
        }
        float se = 0.f, o = 0.f;
        for (int tp = 0; tp < 20; tp++) {
            float e = expf(l[tp] - mx);
            se += e; o += e * v[tp];
        }
        cat1[(size_t)c * HH + d] = o / se;
    }
}

// ---------------- GAT: per-node alpha dots ----------------
__global__ void gat_dots_k(const float* __restrict__ h, const float* __restrict__ as_,
                           const float* __restrict__ ad_, float* __restrict__ ss,
                           float* __restrict__ sd)
{
    int i = blockIdx.x, tid = threadIdx.x;
    float s1 = 0.f, s2 = 0.f;
    for (int k = tid; k < HH; k += 256) {
        float v = h[(size_t)i * HH + k];
        s1 += v * as_[k]; s2 += v * ad_[k];
    }
    __shared__ float r1[256], r2[256];
    r1[tid] = s1; r2[tid] = s2; __syncthreads();
    for (int s = 128; s; s >>= 1) {
        if (tid < s) { r1[tid] += r1[tid + s]; r2[tid] += r2[tid + s]; }
        __syncthreads();
    }
    if (tid == 0) { ss[i] = r1[0]; sd[i] = r2[0]; }
}

// ---------------- GAT aggregate: block per dst node ----------------
#define MAXE 256
__global__ __launch_bounds__(256) void gat_agg_k(
    const float* __restrict__ hmat, const int* __restrict__ esrc,
    const int* __restrict__ edst, int nedges, const float* __restrict__ ss,
    const float* __restrict__ sd, const float* __restrict__ bias, float* __restrict__ outp)
{
    int i = blockIdx.x, tid = threadIdx.x;
    __shared__ int cnt;
    __shared__ int msrc[MAXE];
    __shared__ float mw[MAXE];
    __shared__ float inv_s;
    if (tid == 0) {
        cnt = 1; msrc[0] = i;
        float e = ss[i] + sd[i];
        mw[0] = e > 0.f ? e : 0.2f * e;
    }
    __syncthreads();
    for (int e = tid; e < nedges; e += 256) {
        if (edst[e] == i) {
            int p = atomicAdd(&cnt, 1);
            if (p < MAXE) {
                int s = esrc[e];
                msrc[p] = s;
                float v = ss[s] + sd[i];
                mw[p] = v > 0.f ? v : 0.2f * v;
            }
        }
    }
    __syncthreads();
    int m = min(cnt, MAXE);
    if (tid == 0) {
        float mx = -1e30f;
        for (int p = 0; p < m; p++) mx = fmaxf(mx, mw[p]);
        float s = 0.f;
        for (int p = 0; p < m; p++) { float e = expf(mw[p] - mx); mw[p] = e; s += e; }
        inv_s = 1.0f / s;
    }
    __syncthreads();
    for (int d = tid; d < HH; d += 256) {
        float a = 0.f;
        for (int p = 0; p < m; p++) a += mw[p] * hmat[(size_t)msrc[p] * HH + d];
        outp[(size_t)i * HH + d] = a * inv_s + bias[d];
    }
}

// ---------------- concat [wav3, cat, inner] ----------------
__global__ void concat_k(const float* __restrict__ wav, const float* __restrict__ gc,
                         const float* __restrict__ gi, float* __restrict__ cc)
{
    int row = blockIdx.x;
    int c = row / 20;
    for (int k = threadIdx.x; k < H3; k += 256) {
        float v;
        if (k < HH) v = wav[(size_t)row * HH + k];
        else if (k < 2 * HH) v = gc[(size_t)c * HH + (k - HH)];
        else v = gi[(size_t)row * HH + (k - 2 * HH)];
        cc[(size_t)row * H3 + k] = v;
    }
}

// ---------------- reg/cls heads ----------------
__global__ void heads_k(const float* __restrict__ f, const float* __restrict__ regW,
                        const float* __restrict__ regb, const float* __restrict__ clsW,
                        const float* __restrict__ clsb, float* __restrict__ outp)
{
    int i = blockIdx.x, tid = threadIdx.x;
    float s1 = 0.f, s2 = 0.f;
    for (int k = tid; k < HH; k += 256) {
        float v = f[(size_t)i * HH + k];
        s1 += v * regW[k]; s2 += v * clsW[k];
    }
    __shared__ float r1[256], r2[256];
    r1[tid] = s1; r2[tid] = s2; __syncthreads();
    for (int s = 128; s; s >>= 1) {
        if (tid < s) { r1[tid] += r1[tid + s]; r2[tid] += r2[tid + s]; }
        __syncthreads();
    }
    if (tid == 0) {
        outp[i] = r1[0] + regb[0];
        outp[100 + i] = sigf(r2[0] + clsb[0]);
    }
}

extern "C" void kernel_launch(void* const* d_in, const int* in_sizes, int n_in,
                              void* d_out, int out_size, void* d_ws, size_t ws_size,
                              hipStream_t stream)
{
    (void)in_sizes; (void)n_in; (void)out_size; (void)ws_size;
    const float* x0 = (const float*)d_in[0];
    const float* x1 = (const float*)d_in[1];
    const float* x2 = (const float*)d_in[2];
    const float* x3 = (const float*)d_in[3];
    const int*   ie = (const int*)d_in[4];
    const int*   oe = (const int*)d_in[5];
    const float* enc_Wih = (const float*)d_in[6];
    const float* enc_Whh = (const float*)d_in[7];
    const float* enc_bih = (const float*)d_in[8];
    const float* enc_bhh = (const float*)d_in[9];
    const float* enc_attW = (const float*)d_in[10];
    const float* enc_attb = (const float*)d_in[11];
    const float* wk_Wih = (const float*)d_in[12];
    const float* wk_Whh = (const float*)d_in[13];
    const float* wk_bih = (const float*)d_in[14];
    const float* wk_bhh = (const float*)d_in[15];
    const float* wkatt_W = (const float*)d_in[16];
    const float* wkatt_b = (const float*)d_in[17];
    const float* pool_W = (const float*)d_in[18];
    const float* pool_b = (const float*)d_in[19];
    const float* ig_W = (const float*)d_in[20];
    const float* ig_as = (const float*)d_in[21];
    const float* ig_ad = (const float*)d_in[22];
    const float* ig_b = (const float*)d_in[23];
    const float* cg_W = (const float*)d_in[24];
    const float* cg_as = (const float*)d_in[25];
    const float* cg_ad = (const float*)d_in[26];
    const float* cg_b = (const float*)d_in[27];
    const float* fus_W = (const float*)d_in[28];
    const float* fus_b = (const float*)d_in[29];
    const float* reg_W = (const float*)d_in[30];
    const float* reg_b = (const float*)d_in[31];
    const float* cls_W = (const float*)d_in[32];
    const float* cls_b = (const float*)d_in[33];
    float* outp = (float*)d_out;

    // workspace carve-up
    char* p = (char*)d_ws;
    auto alloc = [&](size_t bytes) { char* r = p; p += (bytes + 255) & ~(size_t)255; return (void*)r; };
    unsigned* flags = (unsigned*)alloc(1024 * 16 * 4);  // enc arrive[0..255], enc gen[256..259], wk arrive[512..767], wk gen[768]
    _Float16* Wcat = (_Float16*)alloc((size_t)NW * H3 * 1280 * 2);
    float* bc = (float*)alloc((size_t)NW * 4 * HH * 4);
    _Float16* wkW = (_Float16*)alloc((size_t)H3 * HH * 2);
    _Float16* xT = (_Float16*)alloc((size_t)NW * TT * 128 * II * 2);
    float* wT = (float*)alloc((size_t)NW * TT * TT * 4);
    _Float16* hhA = (_Float16*)alloc((size_t)NW * 128 * HH * 2);
    _Float16* hhB = (_Float16*)alloc((size_t)NW * 128 * HH * 2);
    _Float16* seq = (_Float16*)alloc((size_t)NW * NST * TT * HH * 2);
    float* wex = (float*)alloc((size_t)NW * NST * HH * 4);
    float* gxw = (float*)alloc((size_t)NW * NST * H3 * 4);
    float* hwA = (float*)alloc(4 * HH * 4);
    float* hwB = (float*)alloc(4 * HH * 4);
    float* we2 = (float*)alloc((size_t)NST * 4 * HH * 4);
    float* wav = (float*)alloc((size_t)NST * HH * 4);
    float* hi  = (float*)alloc((size_t)NST * HH * 4);
    float* si_s = (float*)alloc(128 * 4);
    float* si_d = (float*)alloc(128 * 4);
    float* gi  = (float*)alloc((size_t)NST * HH * 4);
    float* cat1 = (float*)alloc(5 * HH * 4);
    float* hc  = (float*)alloc(5 * HH * 4);
    float* sc_s = (float*)alloc(64 * 4);
    float* sc_d = (float*)alloc(64 * 4);
    float* gc  = (float*)alloc(5 * HH * 4);
    float* cc  = (float*)alloc((size_t)NST * H3 * 4);
    float* fbuf = (float*)alloc((size_t)NST * HH * 4);

    // allow >64KB dynamic LDS for the fused encoder (once)
    static bool attr_done = false;
    if (!attr_done) {
        hipFuncSetAttribute((const void*)enc_fused_k,
                            hipFuncAttributeMaxDynamicSharedMemorySize, ENC_LDS_BYTES);
        attr_done = true;
    }

    // one-time conversions + zero-init (flag state re-zeroed every replay)
    zero_k<<<64, 256, 0, stream>>>((float*)flags, 1024 * 16);
    convW_k<<<dim3(5, H3, NW), 256, 0, stream>>>(enc_Whh, enc_Wih, Wcat);
    convB_k<<<dim3(4, NW), 256, 0, stream>>>(enc_bih, enc_bhh, bc);
    convWk_k<<<dim3(4, H3), 256, 0, stream>>>(wk_Whh, wkW);
    xcvt_k<<<8192, 256, 0, stream>>>(x0, x1, x2, x3, xT);
    wTcvt_k<<<dim3(TT, NW), 128, 0, stream>>>(enc_attW, wT);
    zero_k<<<(NW * 128 * HH / 2 + 255) / 256, 256, 0, stream>>>((float*)hhA, NW * 128 * HH / 2);
    zero_k<<<(4 * HH + 255) / 256, 256, 0, stream>>>(hwA, 4 * HH);

    // 4-week encoder GRU: single kernel, 128 internal steps, XCD-confined weeks
    enc_fused_k<<<256, 256, ENC_LDS_BYTES, stream>>>(
        Wcat, bc, xT, hhA, hhB, seq, flags);

    // per-week time attention -> wex[w][n][d]
    att1_k<<<dim3(8, NST, NW), 256, 0, stream>>>(seq, wT, enc_attb, wex);

    // weekly GRU input projection (bias folded in)
    gemm_tn_k<0><<<dim3(48, 7), 256, 0, stream>>>(wex, wk_Wih, wk_bih, gxw, 400, H3, HH);

    // weekly GRU recurrence: single kernel, 100 internal steps
    wk_fused_k<<<256, 256, 0, stream>>>(gxw, wkW, wk_bhh, hwA, hwB, we2, flags + 512 * 16);

    // weekly attention -> wav (100,1024)
    wkatt_k<<<NST, 256, 0, stream>>>(we2, wkatt_W, wkatt_b, wav);

    // inner GAT
    gemm_tn_k<0><<<dim3(16, 2), 256, 0, stream>>>(wav, ig_W, nullptr, hi, NST, HH, HH);
    gat_dots_k<<<NST, 256, 0, stream>>>(hi, ig_as, ig_ad, si_s, si_d);
    gat_agg_k<<<NST, 256, 0, stream>>>(hi, ie, ie + 2000, 2000, si_s, si_d, ig_b, gi);

    // category pooling attention + outer GAT
    poolatt_k<<<5, 256, 0, stream>>>(wav, pool_W, pool_b, cat1);
    gemm_tn_k<0><<<dim3(16, 1), 256, 0, stream>>>(cat1, cg_W, nullptr, hc, 5, HH, HH);
    gat_dots_k<<<5, 256, 0, stream>>>(hc, cg_as, cg_ad, sc_s, sc_d);
    gat_agg_k<<<5, 256, 0, stream>>>(hc, oe, oe + 25, 25, sc_s, sc_d, cg_b, gc);

    // fusion + heads
    concat_k<<<NST, 256, 0, stream>>>(wav, gc, gi, cc);
    gemm_tn_k<1><<<dim3(16, 2), 256, 0, stream>>>(cc, fus_W, fus_b, fbuf, NST, HH, H3);
    heads_k<<<NST, 256, 0, stream>>>(fbuf, reg_W, reg_b, cls_W, cls_b, outp);
}

// Round 10
// 4384.958 us; speedup vs baseline: 2.4225x; 1.0487x over previous
//
#include <hip/hip_runtime.h>
#include <hip/hip_bf16.h>

#define NW 4
#define NST 100
#define TT 128
#define II 256
#define HH 1024
#define H3 3072

typedef _Float16 h8 __attribute__((ext_vector_type(8)));
typedef float f4 __attribute__((ext_vector_type(4)));

__device__ __forceinline__ float sigf(float x) { return 1.0f / (1.0f + __expf(-x)); }
__device__ __forceinline__ float tanhfast(float x) { return 1.0f - 2.0f / (1.0f + __expf(2.0f * x)); }

// ---- coherent (L3-direct, sc1) loads for the small weekly-GRU h exchange ----
__device__ __forceinline__ float4 ld_f4_sc1(const float* p) {
    union { unsigned long long u[2]; float4 v; } r;
    r.u[0] = __hip_atomic_load((unsigned long long*)p, __ATOMIC_RELAXED, __HIP_MEMORY_SCOPE_AGENT);
    r.u[1] = __hip_atomic_load((unsigned long long*)p + 1, __ATOMIC_RELAXED, __HIP_MEMORY_SCOPE_AGENT);
    return r.v;
}
__device__ __forceinline__ float ld_f_sc1(const float* p) {
    return __hip_atomic_load((float*)p, __ATOMIC_RELAXED, __HIP_MEMORY_SCOPE_AGENT);
}

// ---- bounded spin: never hang the queue; a sync failure becomes a clean mismatch ----
__device__ __forceinline__ void spin_wait(unsigned* f, unsigned t) {
    int guard = 0;
    while (__hip_atomic_load(f, __ATOMIC_RELAXED, __HIP_MEMORY_SCOPE_AGENT) <= t) {
        __builtin_amdgcn_s_sleep(1);
        if (++guard > (1 << 20)) break;
    }
}

// ---------------- zero init ----------------
__global__ void zero_k(float* a, int n) {
    int i = blockIdx.x * 256 + threadIdx.x;
    if (i < n) a[i] = 0.0f;
}

// ---------------- weight concat + fp16 convert: Wc[w][3072][1280] = [Whh | Wih] ----
__global__ void convW_k(const float* __restrict__ Whh, const float* __restrict__ Wih,
                        _Float16* __restrict__ Wc) {
    int col = blockIdx.x * 256 + threadIdx.x;  // 0..1279
    int r = blockIdx.y;                        // 0..3071
    int w = blockIdx.z;
    float v = (col < HH) ? Whh[((size_t)w * H3 + r) * HH + col]
                         : Wih[((size_t)w * H3 + r) * II + (col - HH)];
    Wc[((size_t)w * H3 + r) * 1280 + col] = (_Float16)v;
}

// ---------------- weekly weights fp16 ----------------
__global__ void convWk_k(const float* __restrict__ src, _Float16* __restrict__ dst) {
    int col = blockIdx.x * 256 + threadIdx.x;  // 0..1023
    int r = blockIdx.y;                        // 0..3071
    dst[(size_t)r * HH + col] = (_Float16)src[(size_t)r * HH + col];
}

// ---------------- x -> fp16 padded transpose: xT[w][t][128][256] ----------------
__global__ void xcvt_k(const float* __restrict__ x0, const float* __restrict__ x1,
                       const float* __restrict__ x2, const float* __restrict__ x3,
                       _Float16* __restrict__ xT) {
    int idx = blockIdx.x * 256 + threadIdx.x;   // 2^21 total
    int k8 = idx & 31;
    int m  = (idx >> 5) & 127;
    int t  = (idx >> 12) & 127;
    int w  = idx >> 19;
    const float* xw = (w == 0) ? x0 : (w == 1) ? x1 : (w == 2) ? x2 : x3;
    h8 hv = {};
    if (m < NST) {
        const float* s = xw + ((size_t)m * TT + t) * II + k8 * 8;
        float4 fa = *(const float4*)s;
        float4 fb = *(const float4*)(s + 4);
        hv[0] = (_Float16)fa.x; hv[1] = (_Float16)fa.y;
        hv[2] = (_Float16)fa.z; hv[3] = (_Float16)fa.w;
        hv[4] = (_Float16)fb.x; hv[5] = (_Float16)fb.y;
        hv[6] = (_Float16)fb.z; hv[7] = (_Float16)fb.w;
    }
    *(h8*)&xT[(((size_t)w * TT + t) * 128 + m) * II + k8 * 8] = hv;
}

// ---------------- combined bias precompute: bc[w][{r,z,ni,nh}][1024] fp32 ----
__global__ void convB_k(const float* __restrict__ bih, const float* __restrict__ bhh,
                        float* __restrict__ bc) {
    int j = blockIdx.x * 256 + threadIdx.x;
    int w = blockIdx.y;
    const float* bi = bih + w * H3;
    const float* bh = bhh + w * H3;
    float* o = bc + w * 4096;
    o[j] = bi[j] + bh[j];
    o[1024 + j] = bi[1024 + j] + bh[1024 + j];
    o[2048 + j] = bi[2048 + j];
    o[3072 + j] = bh[2048 + j];
}

// ---------------- fused encoder GRU: entire 128-step recurrence in ONE kernel.
// Weights in LDS; fp32 h master in registers; 12-deep h-prefetch ring; x chunks
// (prefetched during the barrier spin) consumed FIRST so the post-fence h ring
// gets extra latency cover; hierarchical flag barrier. ------
#define ENC_LDS_HALFS (40 * 3 * 16 * 32)
#define ENC_LDS_BYTES (ENC_LDS_HALFS * 2)

__global__ __launch_bounds__(256) void enc_fused_k(
    const _Float16* __restrict__ Wc, const float* __restrict__ bc,
    const _Float16* __restrict__ xT,
    _Float16* __restrict__ hhA, _Float16* __restrict__ hhB,
    _Float16* __restrict__ seq, unsigned* flags)
{
    extern __shared__ _Float16 Bs[];   // [40][3][16][32] fragment-contiguous

    // XCD-confinement swizzle: week w's 64 blocks land on XCD pair {2w, 2w+1}.
    int id = blockIdx.x;
    int rr = id & 7, qq = id >> 3;
    int w  = rr >> 1;
    int bx = qq * 2 + (rr & 1);        // 0..63 within week
    int j0 = bx * 16;

    const _Float16* Wcw = Wc + (size_t)w * H3 * 1280;
    const float* bcw = bc + w * 4096;
    _Float16* hA = hhA + (size_t)w * 128 * HH;
    _Float16* hB = hhB + (size_t)w * 128 * HH;
    unsigned* fw = flags + (size_t)w * 64 * 16;        // per-week arrive flags
    unsigned* genw = flags + (size_t)(256 + w) * 16;   // per-week generation word

    int tid = threadIdx.x;
    int lane = tid & 63, wi = tid >> 6, quad = lane >> 4, l15 = lane & 15;

    // one-time weight staging: dst layout Bs[c][g][jj][k32] (fragment-contiguous)
    if (tid < 192) {
        int brow = tid >> 2, bseg = tid & 3;
        int g = brow >> 4, jj = brow & 15;
        const _Float16* bsrc =
            Wcw + (size_t)(g * 1024 + j0 + jj) * 1280 + bseg * 8;
        #pragma unroll 8
        for (int c = 0; c < 40; c++) {
            uint4 v = *(const uint4*)(bsrc + c * 32);
            *(uint4*)&Bs[(((size_t)c * 3 + g) * 16 + jj) * 32 + bseg * 8] = v;
        }
    }
    __syncthreads();

    int j = j0 + l15;
    float br = bcw[j], bz = bcw[1024 + j], bni = bcw[2048 + j], bnh = bcw[3072 + j];
    int r0 = wi * 32 + l15, r1 = wi * 32 + 16 + l15;
    float hreg[2][4] = {};   // fp32 h master, block-private -> registers

    // x chunks for t=0 preloaded into dedicated regs
    h8 xb0[8], xb1[8];
    {
        const _Float16* x0p = xT + ((size_t)w * TT) * 128 * II;
        #pragma unroll
        for (int u = 0; u < 8; u++) {
            xb0[u] = *(const h8*)(x0p + (size_t)r0 * II + quad * 8 + u * 32);
            xb1[u] = *(const h8*)(x0p + (size_t)r1 * II + quad * 8 + u * 32);
        }
    }

    for (int t = 0; t < TT; t++) {
        const _Float16* hin = (t & 1) ? hB : hA;
        _Float16* hout = (t & 1) ? hA : hB;
        const _Float16* pA0h = hin + (size_t)r0 * HH + quad * 8;
        const _Float16* pA1h = hin + (size_t)r1 * HH + quad * 8;

        f4 aR[2] = {}, aZ[2] = {}, aNH[2] = {}, aNX[2] = {};

        // 12-deep h prefetch ring (issued first; x MFMAs below cover latency)
        h8 rb0[12], rb1[12];
        #pragma unroll
        for (int u = 0; u < 12; u++) {
            rb0[u] = *(const h8*)(pA0h + u * 32);
            rb1[u] = *(const h8*)(pA1h + u * 32);
        }

        // x chunks first (32..39), then h chunks (0..31)
        #pragma unroll
        for (int cc = 0; cc < 40; cc++) {
            int c = (cc < 8) ? (32 + cc) : (cc - 8);
            h8 a0, a1;
            if (c >= 32) {
                a0 = xb0[c - 32]; a1 = xb1[c - 32];
            } else {
                int u = c % 12;
                a0 = rb0[u]; a1 = rb1[u];
                int cn = c + 12;
                if (cn < 32) {
                    rb0[u] = *(const h8*)(pA0h + cn * 32);
                    rb1[u] = *(const h8*)(pA1h + cn * 32);
                }
            }
            const _Float16* bb = &Bs[(size_t)c * 1536];   // 3*16*32 halfs per chunk
            h8 bf0 = *(const h8*)&bb[l15 * 32 + quad * 8];
            h8 bf1 = *(const h8*)&bb[512 + l15 * 32 + quad * 8];
            h8 bf2 = *(const h8*)&bb[1024 + l15 * 32 + quad * 8];
            aR[0] = __builtin_amdgcn_mfma_f32_16x16x32_f16(a0, bf0, aR[0], 0, 0, 0);
            aR[1] = __builtin_amdgcn_mfma_f32_16x16x32_f16(a1, bf0, aR[1], 0, 0, 0);
            aZ[0] = __builtin_amdgcn_mfma_f32_16x16x32_f16(a0, bf1, aZ[0], 0, 0, 0);
            aZ[1] = __builtin_amdgcn_mfma_f32_16x16x32_f16(a1, bf1, aZ[1], 0, 0, 0);
            if (c < 32) {
                aNH[0] = __builtin_amdgcn_mfma_f32_16x16x32_f16(a0, bf2, aNH[0], 0, 0, 0);
                aNH[1] = __builtin_amdgcn_mfma_f32_16x16x32_f16(a1, bf2, aNH[1], 0, 0, 0);
            } else {
                aNX[0] = __builtin_amdgcn_mfma_f32_16x16x32_f16(a0, bf2, aNX[0], 0, 0, 0);
                aNX[1] = __builtin_amdgcn_mfma_f32_16x16x32_f16(a1, bf2, aNX[1], 0, 0, 0);
            }
        }

        // ---- gate epilogue (fast transcendentals): pack cols (j, j+1) ----
        unsigned pks[2][4];
        #pragma unroll
        for (int mi = 0; mi < 2; mi++) {
            #pragma unroll
            for (int p = 0; p < 4; p++) {
                int row = wi * 32 + mi * 16 + quad * 4 + p;
                float r = sigf(aR[mi][p] + br);
                float z = sigf(aZ[mi][p] + bz);
                float n = tanhfast(aNX[mi][p] + bni + r * (aNH[mi][p] + bnh));
                float hv = (1.f - z) * n + z * hreg[mi][p];
                hreg[mi][p] = hv;
                unsigned short hb = __builtin_bit_cast(unsigned short, (_Float16)hv);
                unsigned ob = __shfl_xor((unsigned)hb, 1);
                unsigned pk = (unsigned)hb | (ob << 16);
                pks[mi][p] = pk;
                if (!(l15 & 1) && t < TT - 1)
                    __hip_atomic_exchange((unsigned*)&hout[(size_t)row * HH + j], pk,
                                          __ATOMIC_RELAXED, __HIP_MEMORY_SCOPE_AGENT);
            }
        }
        // ---- arrive: h-atomics drained by syncthreads, then flag (relaxed) ----
        if (t < TT - 1) {
            __syncthreads();
            if (tid == 0)
                __hip_atomic_store(&fw[bx * 16], (unsigned)(t + 1),
                                   __ATOMIC_RELAXED, __HIP_MEMORY_SCOPE_AGENT);
        }
        // ---- seq stores (sc1 WT, not read in-kernel) overlap the poll ----
        #pragma unroll
        for (int mi = 0; mi < 2; mi++) {
            #pragma unroll
            for (int p = 0; p < 4; p++) {
                int row = wi * 32 + mi * 16 + quad * 4 + p;
                if (!(l15 & 1) && row < NST)
                    __hip_atomic_store(
                        (unsigned*)&seq[(((size_t)w * NST + row) * TT + t) * HH + j],
                        pks[mi][p], __ATOMIC_RELAXED, __HIP_MEMORY_SCOPE_AGENT);
            }
        }
        if (t < TT - 1) {
            // prefetch x for step t+1 (read-only => safe across the fence);
            // misses overlap the barrier wait below
            const _Float16* xn = xT + ((size_t)w * TT + t + 1) * 128 * II;
            #pragma unroll
            for (int u = 0; u < 8; u++) {
                xb0[u] = *(const h8*)(xn + (size_t)r0 * II + quad * 8 + u * 32);
                xb1[u] = *(const h8*)(xn + (size_t)r1 * II + quad * 8 + u * 32);
            }
            // ---- hierarchical wait: master polls 64 flags, publishes gen ----
            if (bx == 0) {
                if (tid < 64) spin_wait(&fw[tid * 16], (unsigned)t);
                __syncthreads();
                if (tid == 0)
                    __hip_atomic_store(genw, (unsigned)(t + 1),
                                       __ATOMIC_RELAXED, __HIP_MEMORY_SCOPE_AGENT);
            } else {
                if (tid == 0) spin_wait(genw, (unsigned)t);
                __syncthreads();
            }
            __builtin_amdgcn_fence(__ATOMIC_ACQUIRE, "agent");
        }
    }
}

// ---------------- encoder time-attention via MFMA ----------------
// scores[d][tp] = sum_t S[t][d]*W[tp][t]  (A = S^T, B = attW rows)
// softmax over tp (in-register ni-reduce + width-16 shfl), PV in VALU.
__global__ __launch_bounds__(256) void att1_k(
    const _Float16* __restrict__ seq, const float* __restrict__ attW,
    const float* __restrict__ attb, float* __restrict__ wex)
{
    int d0 = blockIdx.x * 128;
    int n  = blockIdx.y;
    int w  = blockIdx.z;
    __shared__ _Float16 S[128][128];   // [t][d]
    __shared__ _Float16 Wh[128][128];  // [tp][t]
    int tid = threadIdx.x;
    const _Float16* sp = seq + ((size_t)(w * NST + n) * TT) * HH + d0;
    for (int q = tid; q < 2048; q += 256) {
        int t = q >> 4, seg = q & 15;
        *(h8*)&S[t][seg * 8] = *(const h8*)(sp + (size_t)t * HH + seg * 8);
    }
    const float* Wsrc = attW + (size_t)w * TT * TT;
    for (int q = tid; q < 2048; q += 256) {
        int tp = q >> 4, seg = q & 15;
        const float* s = Wsrc + (size_t)tp * TT + seg * 8;
        float4 fa = *(const float4*)s;
        float4 fb = *(const float4*)(s + 4);
        h8 hv;
        hv[0] = (_Float16)fa.x; hv[1] = (_Float16)fa.y;
        hv[2] = (_Float16)fa.z; hv[3] = (_Float16)fa.w;
        hv[4] = (_Float16)fb.x; hv[5] = (_Float16)fb.y;
        hv[6] = (_Float16)fb.z; hv[7] = (_Float16)fb.w;
        *(h8*)&Wh[tp][seg * 8] = hv;
    }
    __syncthreads();

    int lane = tid & 63, wi = tid >> 6, quad = lane >> 4, l15 = lane & 15;

    // A frags: lane m = wi*32 + mi*16 + l15, k = kc*32 + quad*8 + i
    h8 af[2][4];
    #pragma unroll
    for (int mi = 0; mi < 2; mi++) {
        int dl = wi * 32 + mi * 16 + l15;
        #pragma unroll
        for (int kc = 0; kc < 4; kc++) {
            h8 v;
            #pragma unroll
            for (int i = 0; i < 8; i++)
                v[i] = S[kc * 32 + quad * 8 + i][dl];
            af[mi][kc] = v;
        }
    }
    f4 zero4 = {0.f, 0.f, 0.f, 0.f};
    f4 acc[2][8];
    #pragma unroll
    for (int mi = 0; mi < 2; mi++)
        #pragma unroll
        for (int ni = 0; ni < 8; ni++) acc[mi][ni] = zero4;
    #pragma unroll
    for (int ni = 0; ni < 8; ni++) {
        #pragma unroll
        for (int kc = 0; kc < 4; kc++) {
            h8 bf = *(const h8*)&Wh[ni * 16 + l15][kc * 32 + quad * 8];
            acc[0][ni] = __builtin_amdgcn_mfma_f32_16x16x32_f16(af[0][kc], bf, acc[0][ni], 0, 0, 0);
            acc[1][ni] = __builtin_amdgcn_mfma_f32_16x16x32_f16(af[1][kc], bf, acc[1][ni], 0, 0, 0);
        }
    }
    float bias_[8];
    #pragma unroll
    for (int ni = 0; ni < 8; ni++) bias_[ni] = attb[w * TT + ni * 16 + l15];

    #pragma unroll
    for (int mi = 0; mi < 2; mi++) {
        #pragma unroll
        for (int p = 0; p < 4; p++) {
            float vle[8];
            float mx = -1e30f;
            #pragma unroll
            for (int ni = 0; ni < 8; ni++) {
                vle[ni] = acc[mi][ni][p] + bias_[ni];
                mx = fmaxf(mx, vle[ni]);
            }
            #pragma unroll
            for (int o = 8; o; o >>= 1) mx = fmaxf(mx, __shfl_xor(mx, o, 16));
            float sm = 0.f;
            #pragma unroll
            for (int ni = 0; ni < 8; ni++) { vle[ni] = __expf(vle[ni] - mx); sm += vle[ni]; }
            #pragma unroll
            for (int o = 8; o; o >>= 1) sm += __shfl_xor(sm, o, 16);
            int dl = wi * 32 + mi * 16 + quad * 4 + p;
            float ps = 0.f;
            #pragma unroll
            for (int ni = 0; ni < 8; ni++)
                ps += vle[ni] * (float)S[ni * 16 + l15][dl];
            #pragma unroll
            for (int o = 8; o; o >>= 1) ps += __shfl_xor(ps, o, 16);
            if (l15 == 0)
                wex[((size_t)w * NST + n) * HH + d0 + dl] = ps / sm;
        }
    }
}

// ---------------- generic fp32 GEMM: C[m][n] = sum_k A[m][k]*B[n][k] (+bias, relu) ----
template <int RELU>
__global__ __launch_bounds__(256) void gemm_tn_k(
    const float* __restrict__ A, const float* __restrict__ B,
    const float* __restrict__ bias, float* __restrict__ C, int M, int N, int K)
{
    int n0 = blockIdx.x * 64, m0 = blockIdx.y * 64;
    __shared__ float As[16][64], Bs[16][64];
    int tid = threadIdx.x, tx = tid & 15, ty = tid >> 4;
    float acc[4][4] = {{0.f}};
    for (int k0 = 0; k0 < K; k0 += 16) {
        __syncthreads();
        for (int q = tid; q < 1024; q += 256) {
            int kk = q & 15, r = q >> 4;
            int m = m0 + r, nn = n0 + r;
            As[kk][r] = (m < M) ? A[(size_t)m * K + k0 + kk] : 0.f;
            Bs[kk][r] = (nn < N) ? B[(size_t)nn * K + k0 + kk] : 0.f;
        }
        __syncthreads();
        #pragma unroll
        for (int kk = 0; kk < 16; kk++) {
            float4 av = *(const float4*)&As[kk][ty * 4];
            float4 bv = *(const float4*)&Bs[kk][tx * 4];
            float a[4] = {av.x, av.y, av.z, av.w};
            float b[4] = {bv.x, bv.y, bv.z, bv.w};
            #pragma unroll
            for (int r = 0; r < 4; r++)
                #pragma unroll
                for (int c = 0; c < 4; c++) acc[r][c] += a[r] * b[c];
        }
    }
    #pragma unroll
    for (int r = 0; r < 4; r++) {
        int m = m0 + ty * 4 + r;
        if (m >= M) continue;
        #pragma unroll
        for (int c = 0; c < 4; c++) {
            int nn = n0 + tx * 4 + c;
            if (nn >= N) continue;
            float v = acc[r][c] + (bias ? bias[nn] : 0.f);
            if (RELU) v = fmaxf(v, 0.f);
            C[(size_t)m * N + nn] = v;
        }
    }
}

// ---------------- fused weekly GRU: 100-step recurrence, hierarchical barrier,
// gx/h scalar loads hoisted to step top (latency hidden under the reduce) -------
__global__ __launch_bounds__(256) void wk_fused_k(
    const float* __restrict__ gxw, const _Float16* __restrict__ wkW,
    const float* __restrict__ bhh, float* __restrict__ hA,
    float* __restrict__ hB, float* __restrict__ we2, unsigned* flags)
{
    int tid = threadIdx.x;
    int wi = tid >> 6, lane = tid & 63;
    int j = blockIdx.x * 4 + wi;
    int k0 = lane * 16;
    unsigned* gen = flags + 256 * 16;   // single generation word
    float wf[3][16];
    #pragma unroll
    for (int g = 0; g < 3; g++) {
        h8 wa = *(const h8*)&wkW[(size_t)(g * HH + j) * HH + k0];
        h8 wb = *(const h8*)&wkW[(size_t)(g * HH + j) * HH + k0 + 8];
        #pragma unroll
        for (int i = 0; i < 8; i++) { wf[g][i] = (float)wa[i]; wf[g][8 + i] = (float)wb[i]; }
    }
    float b0 = bhh[j], b1 = bhh[HH + j], b2 = bhh[2 * HH + j];

    for (int t = 0; t < NST; t++) {
        const float* hin = (t & 1) ? hB : hA;
        float* hout = (t & 1) ? hA : hB;
        // early prefetch of epilogue scalars (all lanes; hides L2/L3 latency)
        float hj[4], gxv[4][3];
        #pragma unroll
        for (int b = 0; b < 4; b++) {
            hj[b] = ld_f_sc1(&hin[b * HH + j]);
            const float* gx = gxw + ((size_t)b * NST + t) * H3;
            gxv[b][0] = gx[j]; gxv[b][1] = gx[HH + j]; gxv[b][2] = gx[2 * HH + j];
        }
        float acc[4][3] = {};
        #pragma unroll
        for (int b = 0; b < 4; b++) {
            float hv[16];
            #pragma unroll
            for (int s = 0; s < 4; s++) {
                float4 hq = ld_f4_sc1(&hin[b * HH + k0 + s * 4]);
                hv[s * 4] = hq.x; hv[s * 4 + 1] = hq.y;
                hv[s * 4 + 2] = hq.z; hv[s * 4 + 3] = hq.w;
            }
            #pragma unroll
            for (int g = 0; g < 3; g++)
                #pragma unroll
                for (int i = 0; i < 16; i++) acc[b][g] += wf[g][i] * hv[i];
        }
        #pragma unroll
        for (int b = 0; b < 4; b++)
            #pragma unroll
            for (int g = 0; g < 3; g++)
                for (int o = 32; o; o >>= 1) acc[b][g] += __shfl_down(acc[b][g], o);
        if (lane == 0) {
            for (int b = 0; b < 4; b++) {
                float hr = acc[b][0] + b0;
                float hz = acc[b][1] + b1;
                float hn = acc[b][2] + b2;
                float r = sigf(gxv[b][0] + hr);
                float z = sigf(gxv[b][1] + hz);
                float n = tanhfast(gxv[b][2] + r * hn);
                float hv = (1.f - z) * n + z * hj[b];
                __hip_atomic_exchange(&hout[b * HH + j], hv,
                                      __ATOMIC_RELAXED, __HIP_MEMORY_SCOPE_AGENT);
                we2[((size_t)t * 4 + b) * HH + j] = hv;
            }
        }
        // ---- hierarchical barrier: arrive flags -> master block 0 -> gen word ----
        if (t < NST - 1) {
            __syncthreads();
            if (tid == 0)
                __hip_atomic_store(&flags[blockIdx.x * 16], (unsigned)(t + 1),
                                   __ATOMIC_RELAXED, __HIP_MEMORY_SCOPE_AGENT);
            if (blockIdx.x == 0) {
                spin_wait(&flags[tid * 16], (unsigned)t);   // 256 threads, 1 flag each
                __syncthreads();
                if (tid == 0)
                    __hip_atomic_store(gen, (unsigned)(t + 1),
                                       __ATOMIC_RELAXED, __HIP_MEMORY_SCOPE_AGENT);
            } else {
                if (tid == 0) spin_wait(gen, (unsigned)t);
                __syncthreads();
            }
        }
    }
}

// ---------------- weekly attention (T=4) ----------------
__global__ void wkatt_k(const float* __restrict__ we2, const float* __restrict__ W,
                        const float* __restrict__ bv, float* __restrict__ wav)
{
    int n = blockIdx.x;
    for (int d = threadIdx.x; d < HH; d += 256) {
        float v[4], l[4];
        #pragma unroll
        for (int tp = 0; tp < 4; tp++) v[tp] = we2[((size_t)n * 4 + tp) * HH + d];
        float mx = -1e30f;
        #pragma unroll
        for (int tp = 0; tp < 4; tp++) {
            float s = bv[tp];
            for (int t2 = 0; t2 < 4; t2++) s += v[t2] * W[tp * 4 + t2];
            l[tp] = s; mx = fmaxf(mx, s);
        }
        float se = 0.f, o = 0.f;
        #pragma unroll
        for (int tp = 0; tp < 4; tp++) {
            float e = expf(l[tp] - mx);
            se += e; o += e * v[tp];
        }
        wav[(size_t)n * HH + d] = o / se;
    }
}

// ---------------- pool attention (C=5, T=20) ----------------
__global__ void poolatt_k(const float* __restrict__ wav, const float* __restrict__ W,
                          const float* __restrict__ bv, float* __restrict__ cat1)
{
    int c = blockIdx.x;
    for (int d = threadIdx.x; d < HH; d += 256) {
        float v[20], l[20];
        for (int t2 = 0; t2 < 20; t2++) v[t2] = wav[((size_t)c * 20 + t2) * HH + d];
        float mx = -1e30f;
        for (int tp = 0; tp < 20; tp++) {
            float s = bv[tp];
            for (int t2 = 0; t2 < 20; t2++) s += v[t2] * W[tp * 20 + t2];
            l[tp] = s; mx = fmaxf(mx, s);
        }
        float se = 0.f, o = 0.f;
        for (int tp = 0; tp < 20; tp++) {
            float e = expf(l[tp] - mx);
            se += e; o += e * v[tp];
        }
        cat1[(size_t)c * HH + d] = o / se;
    }
}

// ---------------- GAT: per-node alpha dots ----------------
__global__ void gat_dots_k(const float* __restrict__ h, const float* __restrict__ as_,
                           const float* __restrict__ ad_, float* __restrict__ ss,
                           float* __restrict__ sd)
{
    int i = blockIdx.x, tid = threadIdx.x;
    float s1 = 0.f, s2 = 0.f;
    for (int k = tid; k < HH; k += 256) {
        float v = h[(size_t)i * HH + k];
        s1 += v * as_[k]; s2 += v * ad_[k];
    }
    __shared__ float r1[256], r2[256];
    r1[tid] = s1; r2[tid] = s2; __syncthreads();
    for (int s = 128; s; s >>= 1) {
        if (tid < s) { r1[tid] += r1[tid + s]; r2[tid] += r2[tid + s]; }
        __syncthreads();
    }
    if (tid == 0) { ss[i] = r1[0]; sd[i] = r2[0]; }
}

// ---------------- GAT aggregate: block per dst node ----------------
#define MAXE 256
__global__ __launch_bounds__(256) void gat_agg_k(
    const float* __restrict__ hmat, const int* __restrict__ esrc,
    const int* __restrict__ edst, int nedges, const float* __restrict__ ss,
    const float* __restrict__ sd, const float* __restrict__ bias, float* __restrict__ outp)
{
    int i = blockIdx.x, tid = threadIdx.x;
    __shared__ int cnt;
    __shared__ int msrc[MAXE];
    __shared__ float mw[MAXE];
    __shared__ float inv_s;
    if (tid == 0) {
        cnt = 1; msrc[0] = i;
        float e = ss[i] + sd[i];
        mw[0] = e > 0.f ? e : 0.2f * e;
    }
    __syncthreads();
    for (int e = tid; e < nedges; e += 256) {
        if (edst[e] == i) {
            int p = atomicAdd(&cnt, 1);
            if (p < MAXE) {
                int s = esrc[e];
                msrc[p] = s;
                float v = ss[s] + sd[i];
                mw[p] = v > 0.f ? v : 0.2f * v;
            }
        }
    }
    __syncthreads();
    int m = min(cnt, MAXE);
    if (tid == 0) {
        float mx = -1e30f;
        for (int p = 0; p < m; p++) mx = fmaxf(mx, mw[p]);
        float s = 0.f;
        for (int p = 0; p < m; p++) { float e = expf(mw[p] - mx); mw[p] = e; s += e; }
        inv_s = 1.0f / s;
    }
    __syncthreads();
    for (int d = tid; d < HH; d += 256) {
        float a = 0.f;
        for (int p = 0; p < m; p++) a += mw[p] * hmat[(size_t)msrc[p] * HH + d];
        outp[(size_t)i * HH + d] = a * inv_s + bias[d];
    }
}

// ---------------- concat [wav3, cat, inner] ----------------
__global__ void concat_k(const float* __restrict__ wav, const float* __restrict__ gc,
                         const float* __restrict__ gi, float* __restrict__ cc)
{
    int row = blockIdx.x;
    int c = row / 20;
    for (int k = threadIdx.x; k < H3; k += 256) {
        float v;
        if (k < HH) v = wav[(size_t)row * HH + k];
        else if (k < 2 * HH) v = gc[(size_t)c * HH + (k - HH)];
        else v = gi[(size_t)row * HH + (k - 2 * HH)];
        cc[(size_t)row * H3 + k] = v;
    }
}

// ---------------- reg/cls heads ----------------
__global__ void heads_k(const float* __restrict__ f, const float* __restrict__ regW,
                        const float* __restrict__ regb, const float* __restrict__ clsW,
                        const float* __restrict__ clsb, float* __restrict__ outp)
{
    int i = blockIdx.x, tid = threadIdx.x;
    float s1 = 0.f, s2 = 0.f;
    for (int k = tid; k < HH; k += 256) {
        float v = f[(size_t)i * HH + k];
        s1 += v * regW[k]; s2 += v * clsW[k];
    }
    __shared__ float r1[256], r2[256];
    r1[tid] = s1; r2[tid] = s2; __syncthreads();
    for (int s = 128; s; s >>= 1) {
        if (tid < s) { r1[tid] += r1[tid + s]; r2[tid] += r2[tid + s]; }
        __syncthreads();
    }
    if (tid == 0) {
        outp[i] = r1[0] + regb[0];
        outp[100 + i] = sigf(r2[0] + clsb[0]);
    }
}

extern "C" void kernel_launch(void* const* d_in, const int* in_sizes, int n_in,
                              void* d_out, int out_size, void* d_ws, size_t ws_size,
                              hipStream_t stream)
{
    (void)in_sizes; (void)n_in; (void)out_size; (void)ws_size;
    const float* x0 = (const float*)d_in[0];
    const float* x1 = (const float*)d_in[1];
    const float* x2 = (const float*)d_in[2];
    const float* x3 = (const float*)d_in[3];
    const int*   ie = (const int*)d_in[4];
    const int*   oe = (const int*)d_in[5];
    const float* enc_Wih = (const float*)d_in[6];
    const float* enc_Whh = (const float*)d_in[7];
    const float* enc_bih = (const float*)d_in[8];
    const float* enc_bhh = (const float*)d_in[9];
    const float* enc_attW = (const float*)d_in[10];
    const float* enc_attb = (const float*)d_in[11];
    const float* wk_Wih = (const float*)d_in[12];
    const float* wk_Whh = (const float*)d_in[13];
    const float* wk_bih = (const float*)d_in[14];
    const float* wk_bhh = (const float*)d_in[15];
    const float* wkatt_W = (const float*)d_in[16];
    const float* wkatt_b = (const float*)d_in[17];
    const float* pool_W = (const float*)d_in[18];
    const float* pool_b = (const float*)d_in[19];
    const float* ig_W = (const float*)d_in[20];
    const float* ig_as = (const float*)d_in[21];
    const float* ig_ad = (const float*)d_in[22];
    const float* ig_b = (const float*)d_in[23];
    const float* cg_W = (const float*)d_in[24];
    const float* cg_as = (const float*)d_in[25];
    const float* cg_ad = (const float*)d_in[26];
    const float* cg_b = (const float*)d_in[27];
    const float* fus_W = (const float*)d_in[28];
    const float* fus_b = (const float*)d_in[29];
    const float* reg_W = (const float*)d_in[30];
    const float* reg_b = (const float*)d_in[31];
    const float* cls_W = (const float*)d_in[32];
    const float* cls_b = (const float*)d_in[33];
    float* outp = (float*)d_out;

    // workspace carve-up
    char* p = (char*)d_ws;
    auto alloc = [&](size_t bytes) { char* r = p; p += (bytes + 255) & ~(size_t)255; return (void*)r; };
    unsigned* flags = (unsigned*)alloc(1024 * 16 * 4);  // enc arrive[0..255], enc gen[256..259], wk arrive[512..767], wk gen[768]
    _Float16* Wcat = (_Float16*)alloc((size_t)NW * H3 * 1280 * 2);
    float* bc = (float*)alloc((size_t)NW * 4 * HH * 4);
    _Float16* wkW = (_Float16*)alloc((size_t)H3 * HH * 2);
    _Float16* xT = (_Float16*)alloc((size_t)NW * TT * 128 * II * 2);
    _Float16* hhA = (_Float16*)alloc((size_t)NW * 128 * HH * 2);
    _Float16* hhB = (_Float16*)alloc((size_t)NW * 128 * HH * 2);
    _Float16* seq = (_Float16*)alloc((size_t)NW * NST * TT * HH * 2);
    float* wex = (float*)alloc((size_t)NW * NST * HH * 4);
    float* gxw = (float*)alloc((size_t)NW * NST * H3 * 4);
    float* hwA = (float*)alloc(4 * HH * 4);
    float* hwB = (float*)alloc(4 * HH * 4);
    float* we2 = (float*)alloc((size_t)NST * 4 * HH * 4);
    float* wav = (float*)alloc((size_t)NST * HH * 4);
    float* hi  = (float*)alloc((size_t)NST * HH * 4);
    float* si_s = (float*)alloc(128 * 4);
    float* si_d = (float*)alloc(128 * 4);
    float* gi  = (float*)alloc((size_t)NST * HH * 4);
    float* cat1 = (float*)alloc(5 * HH * 4);
    float* hc  = (float*)alloc(5 * HH * 4);
    float* sc_s = (float*)alloc(64 * 4);
    float* sc_d = (float*)alloc(64 * 4);
    float* gc  = (float*)alloc(5 * HH * 4);
    float* cc  = (float*)alloc((size_t)NST * H3 * 4);
    float* fbuf = (float*)alloc((size_t)NST * HH * 4);

    // allow >64KB dynamic LDS for the fused encoder (once)
    static bool attr_done = false;
    if (!attr_done) {
        hipFuncSetAttribute((const void*)enc_fused_k,
                            hipFuncAttributeMaxDynamicSharedMemorySize, ENC_LDS_BYTES);
        attr_done = true;
    }

    // one-time conversions + zero-init (flag state re-zeroed every replay)
    zero_k<<<64, 256, 0, stream>>>((float*)flags, 1024 * 16);
    convW_k<<<dim3(5, H3, NW), 256, 0, stream>>>(enc_Whh, enc_Wih, Wcat);
    convB_k<<<dim3(4, NW), 256, 0, stream>>>(enc_bih, enc_bhh, bc);
    convWk_k<<<dim3(4, H3), 256, 0, stream>>>(wk_Whh, wkW);
    xcvt_k<<<8192, 256, 0, stream>>>(x0, x1, x2, x3, xT);
    zero_k<<<(NW * 128 * HH / 2 + 255) / 256, 256, 0, stream>>>((float*)hhA, NW * 128 * HH / 2);
    zero_k<<<(4 * HH + 255) / 256, 256, 0, stream>>>(hwA, 4 * HH);

    // 4-week encoder GRU: single kernel, 128 internal steps, XCD-confined weeks
    enc_fused_k<<<256, 256, ENC_LDS_BYTES, stream>>>(
        Wcat, bc, xT, hhA, hhB, seq, flags);

    // per-week time attention -> wex[w][n][d]  (MFMA version)
    att1_k<<<dim3(8, NST, NW), 256, 0, stream>>>(seq, enc_attW, enc_attb, wex);

    // weekly GRU input projection (bias folded in)
    gemm_tn_k<0><<<dim3(48, 7), 256, 0, stream>>>(wex, wk_Wih, wk_bih, gxw, 400, H3, HH);

    // weekly GRU recurrence: single kernel, 100 internal steps
    wk_fused_k<<<256, 256, 0, stream>>>(gxw, wkW, wk_bhh, hwA, hwB, we2, flags + 512 * 16);

    // weekly attention -> wav (100,1024)
    wkatt_k<<<NST, 256, 0, stream>>>(we2, wkatt_W, wkatt_b, wav);

    // inner GAT
    gemm_tn_k<0><<<dim3(16, 2), 256, 0, stream>>>(wav, ig_W, nullptr, hi, NST, HH, HH);
    gat_dots_k<<<NST, 256, 0, stream>>>(hi, ig_as, ig_ad, si_s, si_d);
    gat_agg_k<<<NST, 256, 0, stream>>>(hi, ie, ie + 2000, 2000, si_s, si_d, ig_b, gi);

    // category pooling attention + outer GAT
    poolatt_k<<<5, 256, 0, stream>>>(wav, pool_W, pool_b, cat1);
    gemm_tn_k<0><<<dim3(16, 1), 256, 0, stream>>>(cat1, cg_W, nullptr, hc, 5, HH, HH);
    gat_dots_k<<<5, 256, 0, stream>>>(hc, cg_as, cg_ad, sc_s, sc_d);
    gat_agg_k<<<5, 256, 0, stream>>>(hc, oe, oe + 25, 25, sc_s, sc_d, cg_b, gc);

    // fusion + heads
    concat_k<<<NST, 256, 0, stream>>>(wav, gc, gi, cc);
    gemm_tn_k<1><<<dim3(16, 2), 256, 0, stream>>>(cc, fus_W, fus_b, fbuf, NST, HH, H3);
    heads_k<<<NST, 256, 0, stream>>>(fbuf, reg_W, reg_b, cls_W, cls_b, outp);
}